// Round 1
// baseline (3722.190 us; speedup 1.0000x reference)
//
#include <hip/hip_runtime.h>
#include <math.h>

#define E 768
#define S 1024
#define BATCH 4
#define NH 12
#define HD 64
#define NTOK 4096  /* BATCH*S */

__device__ __forceinline__ float sp_f(float x) {
    // jax.nn.softplus(x) = max(x,0) + log1p(exp(-|x|))
    return fmaxf(x, 0.f) + log1pf(__expf(-fabsf(x)));
}

// ---------------------------------------------------------------- prep ----
__global__ void prep_kernel(const float* __restrict__ wqs, const float* __restrict__ wks,
                            const float* __restrict__ wvs, const float* __restrict__ wos,
                            float* __restrict__ spws, float* __restrict__ kl_out)
{
    int i = blockIdx.x * 256 + threadIdx.x;
    if (i < 4 * E) {
        const float* src;
        int j;
        if (i < E)            { src = wqs; j = i; }
        else if (i < 2 * E)   { src = wks; j = i - E; }
        else if (i < 3 * E)   { src = wvs; j = i - 2 * E; }
        else                  { src = wos; j = i - 3 * E; }
        spws[i] = sp_f(src[j]);
    }
    if (i == 4 * E) {
        // kl = 0.5*(4*C + ...) ; seed with 0.5*4*C, C = ln(0.01) - 1
        *kl_out = 2.f * (logf(0.01f) - 1.f);
    }
}

// ------------------------------------------------------------ row stats ----
__global__ void rowstats_kernel(const float* __restrict__ mu, const float* __restrict__ sg,
                                float* __restrict__ rmu2, float* __restrict__ rsg)
{
    const int n = blockIdx.x;
    const int tid = threadIdx.x;
    const float* mrow = mu + (size_t)n * E;
    const float* srow = sg + (size_t)n * E;
    float s1 = 0.f, s2 = 0.f;
    for (int i = tid; i < E; i += 256) {
        float m = mrow[i];
        s1 += m * m;
        s2 += srow[i];
    }
    for (int off = 32; off; off >>= 1) {
        s1 += __shfl_xor(s1, off);
        s2 += __shfl_xor(s2, off);
    }
    __shared__ float r1[4], r2[4];
    int w = tid >> 6;
    if ((tid & 63) == 0) { r1[w] = s1; r2[w] = s2; }
    __syncthreads();
    if (tid == 0) {
        rmu2[n] = r1[0] + r1[1] + r1[2] + r1[3];
        rsg[n]  = r2[0] + r2[1] + r2[2] + r2[3];
    }
}

// ------------------------------------------------------------ linear_vdp ---
// mu_out = mu_in @ W ; Sigma_out = softplus(Sigma_in @ (W^2/Din) + Sigma2 + Sigma3)
template<bool EXTRA_SP>
__global__ __launch_bounds__(256) void linear_vdp_kernel(
    const float* __restrict__ mu_in, const float* __restrict__ sg_in,
    const float* __restrict__ w_mu,  const float* __restrict__ spws,
    const float* __restrict__ rmu2,  const float* __restrict__ rsg,
    float* __restrict__ mu_out, float* __restrict__ sg_out)
{
    __shared__ float Amu[16][64];
    __shared__ float Asg[16][64];
    __shared__ float Bw [16][64];

    const int tid = threadIdx.x;
    const int tx = tid & 15, ty = tid >> 4;
    const int j0 = blockIdx.x * 64;
    const int n0 = blockIdx.y * 64;

    const int arow = tid >> 2, au = tid & 3;   // A staging: one float4 each
    const int bkk  = tid >> 4, bc = tid & 15;  // B staging: one float4 each

    float acc1[4][4];
    float acc2[4][4];
#pragma unroll
    for (int i = 0; i < 4; ++i)
#pragma unroll
        for (int j = 0; j < 4; ++j) { acc1[i][j] = 0.f; acc2[i][j] = 0.f; }

    const float inv_din = 1.f / (float)E;

    for (int k0 = 0; k0 < E; k0 += 16) {
        float4 va = *(const float4*)(mu_in + (size_t)(n0 + arow) * E + k0 + 4 * au);
        float4 vb = *(const float4*)(sg_in + (size_t)(n0 + arow) * E + k0 + 4 * au);
        float4 vw = *(const float4*)(w_mu + (size_t)(k0 + bkk) * E + j0 + 4 * bc);
        __syncthreads();   // previous iteration's LDS reads done
        Amu[4 * au + 0][arow] = va.x; Amu[4 * au + 1][arow] = va.y;
        Amu[4 * au + 2][arow] = va.z; Amu[4 * au + 3][arow] = va.w;
        Asg[4 * au + 0][arow] = vb.x; Asg[4 * au + 1][arow] = vb.y;
        Asg[4 * au + 2][arow] = vb.z; Asg[4 * au + 3][arow] = vb.w;
        *(float4*)&Bw[bkk][4 * bc] = vw;
        __syncthreads();
#pragma unroll
        for (int kk = 0; kk < 16; ++kk) {
            float4 am = *(const float4*)&Amu[kk][4 * ty];
            float4 as = *(const float4*)&Asg[kk][4 * ty];
            float4 bq = *(const float4*)&Bw[kk][4 * tx];
            float a_m[4] = {am.x, am.y, am.z, am.w};
            float a_s[4] = {as.x, as.y, as.z, as.w};
            float b_q[4] = {bq.x, bq.y, bq.z, bq.w};
            float b_2[4];
#pragma unroll
            for (int j = 0; j < 4; ++j) b_2[j] = b_q[j] * b_q[j] * inv_din;
#pragma unroll
            for (int i = 0; i < 4; ++i)
#pragma unroll
                for (int j = 0; j < 4; ++j) {
                    acc1[i][j] += a_m[i] * b_q[j];
                    acc2[i][j] += a_s[i] * b_2[j];
                }
        }
    }

    const float inv_din2 = 1.f / ((float)E * (float)E);
    const float inv_dout = 1.f / (float)E;
#pragma unroll
    for (int i = 0; i < 4; ++i) {
        int row = n0 + 4 * ty + i;
        float rm = rmu2[row] * inv_din2;
        float rs_ = rsg[row] * inv_dout;
        float mv[4], sv[4];
#pragma unroll
        for (int j = 0; j < 4; ++j) {
            int col = j0 + 4 * tx + j;
            float spw = spws[col];
            float sig = acc2[i][j] + rm * spw + rs_ * spw;
            float o = sp_f(sig);
            if (EXTRA_SP) o = sp_f(o);
            mv[j] = acc1[i][j];
            sv[j] = o;
        }
        *(float4*)(mu_out + (size_t)row * E + j0 + 4 * tx) = make_float4(mv[0], mv[1], mv[2], mv[3]);
        *(float4*)(sg_out + (size_t)row * E + j0 + 4 * tx) = make_float4(sv[0], sv[1], sv[2], sv[3]);
    }
}

// ------------------------------------------------------------- attention ---
// One block = one (b, h, 16 q-rows). Two passes over K (softmax stats, then
// scores + outputs). sigma_score[q,k] = Q1[q]·sg_k[k] + Q2[q]·sg_q[k] with
// Q1=(mu_q^2+sg_q)/d, Q2=mu_k^2/d  (matches ref a+b+c with its transposed b).
__global__ __launch_bounds__(256) void vdp_attn_kernel(
    const float* __restrict__ qm, const float* __restrict__ qs,
    const float* __restrict__ km, const float* __restrict__ ksg,
    const float* __restrict__ vm, const float* __restrict__ vsg,
    float* __restrict__ om, float* __restrict__ osg)
{
    const int qt = blockIdx.x, h = blockIdx.y, b = blockIdx.z;
    const int tid = threadIdx.x;
    const int lane = tid & 63, wv = tid >> 6;
    const size_t base = ((size_t)b * S) * E + (size_t)h * HD;

    __shared__ float Q0[16][64], Q1[16][64], Q2[16][64];
    __shared__ float Kt[64][64], Sk[64][64], Sq[64][64];
    __shared__ float Wp[16][64], Wp2[16][64], Wsw[16][64];
    __shared__ float rowm[16], rowl[16];

    // ---- load Q-side rows
    for (int e = tid; e < 1024; e += 256) {
        int q = e >> 6, dd = e & 63;
        size_t g = base + (size_t)(qt * 16 + q) * E + dd;
        float mq = qm[g], sq_ = qs[g], mk = km[g];
        Q0[q][dd] = mq;
        Q1[q][dd] = (mq * mq + sq_) * (1.f / 64.f);
        Q2[q][dd] = (mk * mk) * (1.f / 64.f);
    }
    __syncthreads();

    // ---- pass 1: online max / sum-exp of mu_score/8 (wave handles q = wv+4i)
    float pm[4], pl[4];
#pragma unroll
    for (int i = 0; i < 4; ++i) { pm[i] = -3.4e38f; pl[i] = 0.f; }

    for (int t = 0; t < 16; ++t) {
        float4 rk[4];
#pragma unroll
        for (int s = 0; s < 4; ++s) {
            int e4 = tid + 256 * s; int k = e4 >> 4, u = e4 & 15;
            rk[s] = *(const float4*)(km + base + (size_t)(t * 64 + k) * E + 4 * u);
        }
        __syncthreads();
#pragma unroll
        for (int s = 0; s < 4; ++s) {
            int e4 = tid + 256 * s; int k = e4 >> 4, u = e4 & 15;
            *(float4*)&Kt[k][4 * (u ^ (k & 7))] = rk[s];
        }
        __syncthreads();
        float s0[4] = {0.f, 0.f, 0.f, 0.f};
#pragma unroll
        for (int u = 0; u < 16; ++u) {
            float4 kv = *(const float4*)&Kt[lane][4 * (u ^ (lane & 7))];
#pragma unroll
            for (int i = 0; i < 4; ++i) {
                float4 qv = *(const float4*)&Q0[wv + 4 * i][4 * u];
                s0[i] += qv.x * kv.x + qv.y * kv.y + qv.z * kv.z + qv.w * kv.w;
            }
        }
#pragma unroll
        for (int i = 0; i < 4; ++i) {
            float z = s0[i] * 0.125f;
            float nm = fmaxf(pm[i], z);
            pl[i] = pl[i] * __expf(pm[i] - nm) + __expf(z - nm);
            pm[i] = nm;
        }
    }
#pragma unroll
    for (int i = 0; i < 4; ++i) {
        float m = pm[i], l = pl[i];
        for (int off = 32; off; off >>= 1) {
            float mo = __shfl_xor(m, off), lo = __shfl_xor(l, off);
            float nm = fmaxf(m, mo);
            l = l * __expf(m - nm) + lo * __expf(mo - nm);
            m = nm;
        }
        if (lane == 0) { rowm[wv + 4 * i] = m; rowl[wv + 4 * i] = 1.f / l; }
    }
    __syncthreads();

    // ---- pass 2
    float a_mu[4] = {0,0,0,0}, a_dt[4] = {0,0,0,0}, a_et[4] = {0,0,0,0}, a_ft[4] = {0,0,0,0};
    const int dB = lane, qg = wv;

    for (int t = 0; t < 16; ++t) {
        float4 rk[4], rs[4], rq[4];
#pragma unroll
        for (int s = 0; s < 4; ++s) {
            int e4 = tid + 256 * s; int k = e4 >> 4, u = e4 & 15;
            size_t g = base + (size_t)(t * 64 + k) * E + 4 * u;
            rk[s] = *(const float4*)(km  + g);
            rs[s] = *(const float4*)(ksg + g);
            rq[s] = *(const float4*)(qs  + g);
        }
        __syncthreads();
#pragma unroll
        for (int s = 0; s < 4; ++s) {
            int e4 = tid + 256 * s; int k = e4 >> 4, u = e4 & 15;
            int uu = 4 * (u ^ (k & 7));
            *(float4*)&Kt[k][uu] = rk[s];
            *(float4*)&Sk[k][uu] = rs[s];
            *(float4*)&Sq[k][uu] = rq[s];
        }
        __syncthreads();

        // phase A: scores for 16q x 64k
        float s0[4] = {0,0,0,0}, s1[4] = {0,0,0,0}, s2[4] = {0,0,0,0};
#pragma unroll
        for (int u = 0; u < 16; ++u) {
            int uu = 4 * (u ^ (lane & 7));
            float4 kv = *(const float4*)&Kt[lane][uu];
            float4 sk = *(const float4*)&Sk[lane][uu];
            float4 sq = *(const float4*)&Sq[lane][uu];
#pragma unroll
            for (int i = 0; i < 4; ++i) {
                int q = wv + 4 * i;
                float4 q0 = *(const float4*)&Q0[q][4 * u];
                float4 q1 = *(const float4*)&Q1[q][4 * u];
                float4 q2 = *(const float4*)&Q2[q][4 * u];
                s0[i] += q0.x * kv.x + q0.y * kv.y + q0.z * kv.z + q0.w * kv.w;
                s1[i] += q1.x * sk.x + q1.y * sk.y + q1.z * sk.z + q1.w * sk.w;
                s2[i] += q2.x * sq.x + q2.y * sq.y + q2.z * sq.z + q2.w * sq.w;
            }
        }
#pragma unroll
        for (int i = 0; i < 4; ++i) {
            int q = wv + 4 * i;
            float z = s0[i] * 0.125f;
            float p = __expf(z - rowm[q]) * rowl[q];
            float g = p - p * p; g = g * g;
            float ss = s1[i] + s2[i];
            Wp [q][lane] = p;
            Wp2[q][lane] = p * p * (1.f / 1024.f);
            Wsw[q][lane] = g * ss * (1.f / 67108864.f);  // /(64*1024*1024)
        }
        __syncthreads();

        // phase B: accumulate outputs (wave = qg, lane = d)
        const size_t vb0 = base + (size_t)(t * 64) * E + dB;
#pragma unroll 8
        for (int k = 0; k < 64; ++k) {
            float vmv = vm [vb0 + (size_t)k * E];
            float vsv = vsg[vb0 + (size_t)k * E];
            float vm2 = vmv * vmv;
#pragma unroll
            for (int i = 0; i < 4; ++i) {
                int q = qg * 4 + i;
                float p  = Wp [q][k];
                float p2 = Wp2[q][k];
                float sw = Wsw[q][k];
                a_mu[i] += p  * vmv;
                a_dt[i] += p2 * vsv;
                a_et[i] += sw * vm2;
                a_ft[i] += sw * vsv;
            }
        }
        __syncthreads();
    }

#pragma unroll
    for (int i = 0; i < 4; ++i) {
        int q = qg * 4 + i;
        size_t g = base + (size_t)(qt * 16 + q) * E + dB;
        om [g] = a_mu[i];
        osg[g] = sp_f(a_dt[i] + a_et[i] + a_ft[i]);
    }
}

// ------------------------------------------------------------------- kl ----
__global__ void kl_kernel(const float* __restrict__ w0, const float* __restrict__ w1,
                          const float* __restrict__ w2, const float* __restrict__ w3,
                          const float* __restrict__ s0, const float* __restrict__ s1,
                          const float* __restrict__ s2, const float* __restrict__ s3,
                          float* __restrict__ kl_out)
{
    const int gid = blockIdx.x * 256 + threadIdx.x;
    const int gsz = gridDim.x * 256;
    float acc = 0.f;
    const float cw = 100.f / ((float)E * (float)E);  // 1/(E*E*PRIOR_VAR)
#pragma unroll
    for (int m = 0; m < 4; ++m) {
        const float* w = (m == 0) ? w0 : (m == 1) ? w1 : (m == 2) ? w2 : w3;
        const float* sv = (m == 0) ? s0 : (m == 1) ? s1 : (m == 2) ? s2 : s3;
        for (int i = gid; i < E * E; i += gsz) { float x = w[i]; acc += x * x * cw; }
        for (int i = gid; i < E; i += gsz) { float x = sv[i]; acc += (-x + sp_f(x) * 100.f) * (1.f / (float)E); }
    }
    for (int off = 32; off; off >>= 1) acc += __shfl_xor(acc, off);
    __shared__ float r[4];
    int tid = threadIdx.x, w_ = tid >> 6;
    if ((tid & 63) == 0) r[w_] = acc;
    __syncthreads();
    if (tid == 0) atomicAdd(kl_out, 0.5f * (r[0] + r[1] + r[2] + r[3]));
}

// --------------------------------------------------------------- launch ----
extern "C" void kernel_launch(void* const* d_in, const int* in_sizes, int n_in,
                              void* d_out, int out_size, void* d_ws, size_t ws_size,
                              hipStream_t stream)
{
    const float* mu_in = (const float*)d_in[0];
    const float* sg_in = (const float*)d_in[1];
    const float* wq  = (const float*)d_in[2];
    const float* wqs = (const float*)d_in[3];
    const float* wk  = (const float*)d_in[4];
    const float* wks = (const float*)d_in[5];
    const float* wvp = (const float*)d_in[6];
    const float* wvs = (const float*)d_in[7];
    const float* wo  = (const float*)d_in[8];
    const float* wos = (const float*)d_in[9];

    float* out_mu = (float*)d_out;
    float* out_sg = out_mu + (size_t)NTOK * E;
    float* kl_out = out_mu + 2 * (size_t)NTOK * E;

    float* ws = (float*)d_ws;
    size_t off = 0;
    auto alloc = [&](size_t n) { float* p = ws + off; off += n; return p; };
    float* q_mu = alloc((size_t)NTOK * E);
    float* q_sg = alloc((size_t)NTOK * E);
    float* k_mu = alloc((size_t)NTOK * E);
    float* k_sg = alloc((size_t)NTOK * E);
    float* v_mu = alloc((size_t)NTOK * E);
    float* v_sg = alloc((size_t)NTOK * E);
    float* a_mu = alloc((size_t)NTOK * E);
    float* a_sg = alloc((size_t)NTOK * E);
    float* rmu2  = alloc(NTOK);
    float* rsgs  = alloc(NTOK);
    float* armu2 = alloc(NTOK);
    float* arsg  = alloc(NTOK);
    float* spws  = alloc(4 * E);
    (void)ws_size; (void)in_sizes; (void)n_in; (void)out_size;

    prep_kernel<<<13, 256, 0, stream>>>(wqs, wks, wvs, wos, spws, kl_out);
    rowstats_kernel<<<NTOK, 256, 0, stream>>>(mu_in, sg_in, rmu2, rsgs);

    dim3 lgrid(E / 64, NTOK / 64);
    linear_vdp_kernel<false><<<lgrid, 256, 0, stream>>>(mu_in, sg_in, wq,  spws + 0 * E, rmu2, rsgs, q_mu, q_sg);
    linear_vdp_kernel<false><<<lgrid, 256, 0, stream>>>(mu_in, sg_in, wk,  spws + 1 * E, rmu2, rsgs, k_mu, k_sg);
    linear_vdp_kernel<false><<<lgrid, 256, 0, stream>>>(mu_in, sg_in, wvp, spws + 2 * E, rmu2, rsgs, v_mu, v_sg);

    dim3 agrid(S / 16, NH, BATCH);
    vdp_attn_kernel<<<agrid, 256, 0, stream>>>(q_mu, q_sg, k_mu, k_sg, v_mu, v_sg, a_mu, a_sg);

    rowstats_kernel<<<NTOK, 256, 0, stream>>>(a_mu, a_sg, armu2, arsg);
    linear_vdp_kernel<true><<<lgrid, 256, 0, stream>>>(a_mu, a_sg, wo, spws + 3 * E, armu2, arsg, out_mu, out_sg);

    kl_kernel<<<512, 256, 0, stream>>>(wq, wk, wvp, wo, wqs, wks, wvs, wos, kl_out);
}

// Round 2
// 976.166 us; speedup vs baseline: 3.8131x; 3.8131x over previous
//
#include <hip/hip_runtime.h>
#include <math.h>

#define E 768
#define S 1024
#define BATCH 4
#define NH 12
#define HD 64
#define NTOK 4096  /* BATCH*S */

typedef __attribute__((ext_vector_type(8))) __bf16 bf16x8;
typedef __attribute__((ext_vector_type(4))) float f32x4;
typedef unsigned int u32;
typedef unsigned short u16;

__device__ __forceinline__ float sp_f(float x) {
    // jax.nn.softplus(x) = max(x,0) + log1p(exp(-|x|))
    return fmaxf(x, 0.f) + log1pf(__expf(-fabsf(x)));
}
__device__ __forceinline__ u16 f2bf(float f) {
    u32 u = __float_as_uint(f);
    u = u + 0x7fffu + ((u >> 16) & 1u);   // RNE
    return (u16)(u >> 16);
}
__device__ __forceinline__ u32 pk2(float a, float b) {
    return (u32)f2bf(a) | ((u32)f2bf(b) << 16);
}

// ---------------------------------------------------------------- prep ----
__global__ void prep_kernel(const float* __restrict__ wqs, const float* __restrict__ wks,
                            const float* __restrict__ wvs, const float* __restrict__ wos,
                            float* __restrict__ spws, float* __restrict__ kl_out)
{
    int i = blockIdx.x * 256 + threadIdx.x;
    if (i < 4 * E) {
        const float* src;
        int j;
        if (i < E)            { src = wqs; j = i; }
        else if (i < 2 * E)   { src = wks; j = i - E; }
        else if (i < 3 * E)   { src = wvs; j = i - 2 * E; }
        else                  { src = wos; j = i - 3 * E; }
        spws[i] = sp_f(src[j]);
    }
    if (i == 4 * E) {
        *kl_out = 2.f * (logf(0.01f) - 1.f);
    }
}

// ------------------------------------------------------------ row stats ----
__global__ void rowstats_kernel(const float* __restrict__ mu, const float* __restrict__ sg,
                                float* __restrict__ rmu2, float* __restrict__ rsg)
{
    const int n = blockIdx.x;
    const int tid = threadIdx.x;
    const float* mrow = mu + (size_t)n * E;
    const float* srow = sg + (size_t)n * E;
    float s1 = 0.f, s2 = 0.f;
    for (int i = tid; i < E; i += 256) {
        float m = mrow[i];
        s1 += m * m;
        s2 += srow[i];
    }
    for (int off = 32; off; off >>= 1) {
        s1 += __shfl_xor(s1, off);
        s2 += __shfl_xor(s2, off);
    }
    __shared__ float r1[4], r2[4];
    int w = tid >> 6;
    if ((tid & 63) == 0) { r1[w] = s1; r2[w] = s2; }
    __syncthreads();
    if (tid == 0) {
        rmu2[n] = r1[0] + r1[1] + r1[2] + r1[3];
        rsg[n]  = r2[0] + r2[1] + r2[2] + r2[3];
    }
}

// ------------------------------------------------------------ linear_vdp ---
// MODE 0: fp32 std outputs + extra softplus (O-projection)
// MODE 1: Q -> bf16 row-major [bh][s][d]: mu, sg, (mu^2+sg)/64
// MODE 2: K -> bf16 row-major: mu, sg, mu^2/64
// MODE 3: V -> bf16 transposed [bh][d][s]: mu, sg, mu^2+sg
template<int MODE>
__global__ __launch_bounds__(256) void linear_vdp_kernel(
    const float* __restrict__ mu_in, const float* __restrict__ sg_in,
    const float* __restrict__ w_mu,  const float* __restrict__ spws,
    const float* __restrict__ rmu2,  const float* __restrict__ rsg,
    float* __restrict__ mu_out, float* __restrict__ sg_out,
    u16* __restrict__ b0, u16* __restrict__ b1, u16* __restrict__ b2)
{
    __shared__ float Amu[16][64];
    __shared__ float Asg[16][64];
    __shared__ float Bw [16][64];

    const int tid = threadIdx.x;
    const int tx = tid & 15, ty = tid >> 4;
    const int j0 = blockIdx.x * 64;
    const int n0 = blockIdx.y * 64;

    const int arow = tid >> 2, au = tid & 3;
    const int bkk  = tid >> 4, bc = tid & 15;

    float acc1[4][4];
    float acc2[4][4];
#pragma unroll
    for (int i = 0; i < 4; ++i)
#pragma unroll
        for (int j = 0; j < 4; ++j) { acc1[i][j] = 0.f; acc2[i][j] = 0.f; }

    const float inv_din = 1.f / (float)E;

    for (int k0 = 0; k0 < E; k0 += 16) {
        float4 va = *(const float4*)(mu_in + (size_t)(n0 + arow) * E + k0 + 4 * au);
        float4 vb = *(const float4*)(sg_in + (size_t)(n0 + arow) * E + k0 + 4 * au);
        float4 vw = *(const float4*)(w_mu + (size_t)(k0 + bkk) * E + j0 + 4 * bc);
        __syncthreads();
        Amu[4 * au + 0][arow] = va.x; Amu[4 * au + 1][arow] = va.y;
        Amu[4 * au + 2][arow] = va.z; Amu[4 * au + 3][arow] = va.w;
        Asg[4 * au + 0][arow] = vb.x; Asg[4 * au + 1][arow] = vb.y;
        Asg[4 * au + 2][arow] = vb.z; Asg[4 * au + 3][arow] = vb.w;
        *(float4*)&Bw[bkk][4 * bc] = vw;
        __syncthreads();
#pragma unroll
        for (int kk = 0; kk < 16; ++kk) {
            float4 am = *(const float4*)&Amu[kk][4 * ty];
            float4 as = *(const float4*)&Asg[kk][4 * ty];
            float4 bq = *(const float4*)&Bw[kk][4 * tx];
            float a_m[4] = {am.x, am.y, am.z, am.w};
            float a_s[4] = {as.x, as.y, as.z, as.w};
            float b_q[4] = {bq.x, bq.y, bq.z, bq.w};
            float b_2[4];
#pragma unroll
            for (int j = 0; j < 4; ++j) b_2[j] = b_q[j] * b_q[j] * inv_din;
#pragma unroll
            for (int i = 0; i < 4; ++i)
#pragma unroll
                for (int j = 0; j < 4; ++j) {
                    acc1[i][j] += a_m[i] * b_q[j];
                    acc2[i][j] += a_s[i] * b_2[j];
                }
        }
    }

    const float inv_din2 = 1.f / ((float)E * (float)E);
    const float inv_dout = 1.f / (float)E;
    float sgm[4][4];
#pragma unroll
    for (int i = 0; i < 4; ++i) {
        int row = n0 + 4 * ty + i;
        float rm = rmu2[row] * inv_din2;
        float rs_ = rsg[row] * inv_dout;
#pragma unroll
        for (int j = 0; j < 4; ++j) {
            int col = j0 + 4 * tx + j;
            float spw = spws[col];
            float sig = acc2[i][j] + (rm + rs_) * spw;
            float o = sp_f(sig);
            if (MODE == 0) o = sp_f(o);
            sgm[i][j] = o;
        }
    }

    if (MODE == 0) {
#pragma unroll
        for (int i = 0; i < 4; ++i) {
            int row = n0 + 4 * ty + i;
            *(float4*)(mu_out + (size_t)row * E + j0 + 4 * tx) =
                make_float4(acc1[i][0], acc1[i][1], acc1[i][2], acc1[i][3]);
            *(float4*)(sg_out + (size_t)row * E + j0 + 4 * tx) =
                make_float4(sgm[i][0], sgm[i][1], sgm[i][2], sgm[i][3]);
        }
    } else if (MODE == 1 || MODE == 2) {
        const int h = blockIdx.x;   // gridDim.x == 12, tile width 64 == head dim
#pragma unroll
        for (int i = 0; i < 4; ++i) {
            int t = n0 + 4 * ty + i;
            int bb = t >> 10, s = t & 1023;
            size_t rb = ((size_t)(bb * 12 + h) << 16) + (size_t)(s << 6) + 4 * tx;
            float ex[4];
#pragma unroll
            for (int j = 0; j < 4; ++j) {
                float m = acc1[i][j];
                ex[j] = (MODE == 1) ? (m * m + sgm[i][j]) * (1.f / 64.f)
                                    : (m * m) * (1.f / 64.f);
            }
            uint2 um = make_uint2(pk2(acc1[i][0], acc1[i][1]), pk2(acc1[i][2], acc1[i][3]));
            uint2 us = make_uint2(pk2(sgm[i][0], sgm[i][1]), pk2(sgm[i][2], sgm[i][3]));
            uint2 ue = make_uint2(pk2(ex[0], ex[1]), pk2(ex[2], ex[3]));
            *(uint2*)(b0 + rb) = um;
            *(uint2*)(b1 + rb) = us;
            *(uint2*)(b2 + rb) = ue;
        }
    } else {
        const int h = blockIdx.x;
        const int bb = n0 >> 10;
        const int s0 = (n0 & 1023) + 4 * ty;
#pragma unroll
        for (int j = 0; j < 4; ++j) {
            int dd = 4 * tx + j;
            size_t tb = ((size_t)((bb * 12 + h) * 64 + dd) << 10) + s0;
            float w2[4];
#pragma unroll
            for (int i = 0; i < 4; ++i) w2[i] = acc1[i][j] * acc1[i][j] + sgm[i][j];
            uint2 um = make_uint2(pk2(acc1[0][j], acc1[1][j]), pk2(acc1[2][j], acc1[3][j]));
            uint2 us = make_uint2(pk2(sgm[0][j], sgm[1][j]), pk2(sgm[2][j], sgm[3][j]));
            uint2 uw = make_uint2(pk2(w2[0], w2[1]), pk2(w2[2], w2[3]));
            *(uint2*)(b0 + tb) = um;
            *(uint2*)(b1 + tb) = us;
            *(uint2*)(b2 + tb) = uw;
        }
    }
}

// ------------------------------------------------------------- attention ---
// Block = (bh, qt): 64 q-rows. 4 waves, each owns 16 q-rows.
// Scores computed SWAPPED (C[k,q] = mfma(A=K-side rows, B=Q-side cols)) so each
// lane holds a full 64-k slice for one q row (softmax = in-lane + 2 shfl).
// P/P2/SW round-trip through chunk-XOR-swizzled per-wave LDS to become PV
// A-fragments; V-side arrays are pre-transposed [bh][d][s] for B-fragments.
__global__ __launch_bounds__(256, 2) void vdp_attn_mfma(
    const u16* __restrict__ Kmu, const u16* __restrict__ Ksg, const u16* __restrict__ Asq,
    const u16* __restrict__ Qmu, const u16* __restrict__ Q1v, const u16* __restrict__ Q2v,
    const u16* __restrict__ Vmu, const u16* __restrict__ Vsg, const u16* __restrict__ Vw2,
    float* __restrict__ om, float* __restrict__ osg)
{
    __shared__ __align__(16) u16 Pl[4][3][16][64];

    const int wgid = blockIdx.x;
    const int swz = (wgid & 7) * 96 + (wgid >> 3);   // XCD-contiguous bh groups
    const int bh = swz >> 4, qt = swz & 15;
    const int tid = threadIdx.x;
    const int wv = tid >> 6, lane = tid & 63;
    const int g = lane >> 4, q15 = lane & 15;
    const size_t hb = (size_t)bh << 16;

    // Q-side B fragments (persistent)
    const size_t qoff = hb + (size_t)((qt * 64 + wv * 16 + q15) * 64) + g * 8;
    bf16x8 bq[2], b1[2], b2[2];
    bq[0] = *(const bf16x8*)(Qmu + qoff); bq[1] = *(const bf16x8*)(Qmu + qoff + 32);
    b1[0] = *(const bf16x8*)(Q1v + qoff); b1[1] = *(const bf16x8*)(Q1v + qoff + 32);
    b2[0] = *(const bf16x8*)(Q2v + qoff); b2[1] = *(const bf16x8*)(Q2v + qoff + 32);

    // ---- pass 1: softmax stats (mu scores only)
    float m = -1e30f, l = 0.f;
    for (int t = 0; t < 16; ++t) {
        f32x4 sc[4];
#pragma unroll
        for (int kt = 0; kt < 4; ++kt) sc[kt] = (f32x4){0.f, 0.f, 0.f, 0.f};
#pragma unroll
        for (int kt = 0; kt < 4; ++kt) {
            size_t ar = hb + (size_t)(((t << 6) + (kt << 4) + q15) << 6) + g * 8;
            sc[kt] = __builtin_amdgcn_mfma_f32_16x16x32_bf16(*(const bf16x8*)(Kmu + ar), bq[0], sc[kt], 0, 0, 0);
            sc[kt] = __builtin_amdgcn_mfma_f32_16x16x32_bf16(*(const bf16x8*)(Kmu + ar + 32), bq[1], sc[kt], 0, 0, 0);
        }
        float tm = -1e30f;
#pragma unroll
        for (int kt = 0; kt < 4; ++kt)
#pragma unroll
            for (int r = 0; r < 4; ++r) tm = fmaxf(tm, sc[kt][r]);
        tm = fmaxf(tm, __shfl_xor(tm, 16));
        tm = fmaxf(tm, __shfl_xor(tm, 32));
        tm *= 0.125f;
        float mn = fmaxf(m, tm);
        float ls = 0.f;
#pragma unroll
        for (int kt = 0; kt < 4; ++kt)
#pragma unroll
            for (int r = 0; r < 4; ++r) ls += __expf(sc[kt][r] * 0.125f - mn);
        ls += __shfl_xor(ls, 16);
        ls += __shfl_xor(ls, 32);
        l = l * __expf(m - mn) + ls;
        m = mn;
    }
    const float linv = 1.f / l;

    // ---- pass 2
    f32x4 accm[4], accd[4], acce[4];
#pragma unroll
    for (int nt = 0; nt < 4; ++nt) {
        accm[nt] = (f32x4){0.f, 0.f, 0.f, 0.f};
        accd[nt] = (f32x4){0.f, 0.f, 0.f, 0.f};
        acce[nt] = (f32x4){0.f, 0.f, 0.f, 0.f};
    }

    for (int t = 0; t < 16; ++t) {
        f32x4 sc[4], sgc[4];
#pragma unroll
        for (int kt = 0; kt < 4; ++kt) { sc[kt] = (f32x4){0.f,0.f,0.f,0.f}; sgc[kt] = (f32x4){0.f,0.f,0.f,0.f}; }
#pragma unroll
        for (int kt = 0; kt < 4; ++kt) {
            size_t ar = hb + (size_t)(((t << 6) + (kt << 4) + q15) << 6) + g * 8;
            sc[kt]  = __builtin_amdgcn_mfma_f32_16x16x32_bf16(*(const bf16x8*)(Kmu + ar),      bq[0], sc[kt],  0, 0, 0);
            sc[kt]  = __builtin_amdgcn_mfma_f32_16x16x32_bf16(*(const bf16x8*)(Kmu + ar + 32), bq[1], sc[kt],  0, 0, 0);
            sgc[kt] = __builtin_amdgcn_mfma_f32_16x16x32_bf16(*(const bf16x8*)(Ksg + ar),      b1[0], sgc[kt], 0, 0, 0);
            sgc[kt] = __builtin_amdgcn_mfma_f32_16x16x32_bf16(*(const bf16x8*)(Ksg + ar + 32), b1[1], sgc[kt], 0, 0, 0);
            sgc[kt] = __builtin_amdgcn_mfma_f32_16x16x32_bf16(*(const bf16x8*)(Asq + ar),      b2[0], sgc[kt], 0, 0, 0);
            sgc[kt] = __builtin_amdgcn_mfma_f32_16x16x32_bf16(*(const bf16x8*)(Asq + ar + 32), b2[1], sgc[kt], 0, 0, 0);
        }
        // p / p2 / sw -> swizzled LDS (bf16)
#pragma unroll
        for (int kt = 0; kt < 4; ++kt) {
            float p[4], sw[4];
#pragma unroll
            for (int r = 0; r < 4; ++r) {
                float pv = __expf(sc[kt][r] * 0.125f - m) * linv;
                p[r] = pv;
                float gq = pv - pv * pv; gq *= gq;
                sw[r] = gq * sgc[kt][r] * (1.f / 67108864.f);   // /(64*1024*1024)
            }
            int kb = (kt << 4) + (g << 2);
#pragma unroll
            for (int rp = 0; rp < 4; rp += 2) {
                int k = kb + rp;
                int widx = (((k >> 3) ^ (q15 & 7)) << 3) | (k & 7);
                *(u32*)&Pl[wv][0][q15][widx] = pk2(p[rp], p[rp + 1]);
                *(u32*)&Pl[wv][1][q15][widx] = pk2(p[rp] * p[rp] * (1.f / 1024.f),
                                                   p[rp + 1] * p[rp + 1] * (1.f / 1024.f));
                *(u32*)&Pl[wv][2][q15][widx] = pk2(sw[rp], sw[rp + 1]);
            }
        }
        __syncthreads();

        // PV: A from LDS, B from transposed global V arrays
#pragma unroll
        for (int ks = 0; ks < 2; ++ks) {
            int cc = (((ks << 2) | g) ^ (q15 & 7)) << 3;
            bf16x8 pa  = *(const bf16x8*)&Pl[wv][0][q15][cc];
            bf16x8 p2a = *(const bf16x8*)&Pl[wv][1][q15][cc];
            bf16x8 swa = *(const bf16x8*)&Pl[wv][2][q15][cc];
#pragma unroll
            for (int nt = 0; nt < 4; ++nt) {
                size_t vr = hb + (size_t)(((nt << 4) + q15) << 10) + (t << 6) + (ks << 5) + g * 8;
                accm[nt] = __builtin_amdgcn_mfma_f32_16x16x32_bf16(pa,  *(const bf16x8*)(Vmu + vr), accm[nt], 0, 0, 0);
                accd[nt] = __builtin_amdgcn_mfma_f32_16x16x32_bf16(p2a, *(const bf16x8*)(Vsg + vr), accd[nt], 0, 0, 0);
                acce[nt] = __builtin_amdgcn_mfma_f32_16x16x32_bf16(swa, *(const bf16x8*)(Vw2 + vr), acce[nt], 0, 0, 0);
            }
        }
        __syncthreads();
    }

    // ---- store (fp32, standard [B,S,E] layout)
    const int b_ = bh / 12, h_ = bh % 12;
#pragma unroll
    for (int nt = 0; nt < 4; ++nt) {
#pragma unroll
        for (int r = 0; r < 4; ++r) {
            int srow = qt * 64 + wv * 16 + (g << 2) + r;
            int d = (nt << 4) + q15;
            size_t idx = ((size_t)(b_ * 1024 + srow)) * E + h_ * 64 + d;
            om[idx] = accm[nt][r];
            osg[idx] = sp_f(accd[nt][r] + acce[nt][r]);
        }
    }
}

// ------------------------------------------------------------------- kl ----
__global__ void kl_kernel(const float* __restrict__ w0, const float* __restrict__ w1,
                          const float* __restrict__ w2, const float* __restrict__ w3,
                          const float* __restrict__ s0, const float* __restrict__ s1,
                          const float* __restrict__ s2, const float* __restrict__ s3,
                          float* __restrict__ kl_out)
{
    const int gid = blockIdx.x * 256 + threadIdx.x;
    const int gsz = gridDim.x * 256;
    float acc = 0.f;
    const float cw = 100.f / ((float)E * (float)E);
#pragma unroll
    for (int mm = 0; mm < 4; ++mm) {
        const float* w = (mm == 0) ? w0 : (mm == 1) ? w1 : (mm == 2) ? w2 : w3;
        const float* sv = (mm == 0) ? s0 : (mm == 1) ? s1 : (mm == 2) ? s2 : s3;
        for (int i = gid; i < E * E; i += gsz) { float x = w[i]; acc += x * x * cw; }
        for (int i = gid; i < E; i += gsz) { float x = sv[i]; acc += (-x + sp_f(x) * 100.f) * (1.f / (float)E); }
    }
    for (int off = 32; off; off >>= 1) acc += __shfl_xor(acc, off);
    __shared__ float r[4];
    int tid = threadIdx.x, w_ = tid >> 6;
    if ((tid & 63) == 0) r[w_] = acc;
    __syncthreads();
    if (tid == 0) atomicAdd(kl_out, 0.5f * (r[0] + r[1] + r[2] + r[3]));
}

// --------------------------------------------------------------- launch ----
extern "C" void kernel_launch(void* const* d_in, const int* in_sizes, int n_in,
                              void* d_out, int out_size, void* d_ws, size_t ws_size,
                              hipStream_t stream)
{
    const float* mu_in = (const float*)d_in[0];
    const float* sg_in = (const float*)d_in[1];
    const float* wq  = (const float*)d_in[2];
    const float* wqs = (const float*)d_in[3];
    const float* wk  = (const float*)d_in[4];
    const float* wks = (const float*)d_in[5];
    const float* wvp = (const float*)d_in[6];
    const float* wvs = (const float*)d_in[7];
    const float* wo  = (const float*)d_in[8];
    const float* wos = (const float*)d_in[9];

    float* out_mu = (float*)d_out;
    float* out_sg = out_mu + (size_t)NTOK * E;
    float* kl_out = out_mu + 2 * (size_t)NTOK * E;

    float* ws = (float*)d_ws;
    size_t off = 0;
    auto allocf = [&](size_t n) { float* p = ws + off; off += n; return p; };
    float* a_mu = allocf((size_t)NTOK * E);
    float* a_sg = allocf((size_t)NTOK * E);
    float* rmu2  = allocf(NTOK);
    float* rsgs  = allocf(NTOK);
    float* armu2 = allocf(NTOK);
    float* arsg  = allocf(NTOK);
    float* spws  = allocf(4 * E);

    const size_t BFN = (size_t)48 * 65536;   // elements per bf16 [bh][1024][64] array
    u16* ub = (u16*)(ws + off);
    size_t uoff = 0;
    auto allocu = [&]() { u16* p = ub + uoff; uoff += BFN; return p; };
    u16* qmu_b = allocu();  u16* qsg_b = allocu();  u16* q1_b = allocu();
    u16* kmu_b = allocu();  u16* ksg_b = allocu();  u16* q2_b = allocu();
    u16* vmu_t = allocu();  u16* vsg_t = allocu();  u16* vw2_t = allocu();
    (void)ws_size; (void)in_sizes; (void)n_in; (void)out_size;

    prep_kernel<<<13, 256, 0, stream>>>(wqs, wks, wvs, wos, spws, kl_out);
    rowstats_kernel<<<NTOK, 256, 0, stream>>>(mu_in, sg_in, rmu2, rsgs);

    dim3 lgrid(E / 64, NTOK / 64);
    linear_vdp_kernel<1><<<lgrid, 256, 0, stream>>>(mu_in, sg_in, wq,  spws + 0 * E, rmu2, rsgs,
                                                    nullptr, nullptr, qmu_b, qsg_b, q1_b);
    linear_vdp_kernel<2><<<lgrid, 256, 0, stream>>>(mu_in, sg_in, wk,  spws + 1 * E, rmu2, rsgs,
                                                    nullptr, nullptr, kmu_b, ksg_b, q2_b);
    linear_vdp_kernel<3><<<lgrid, 256, 0, stream>>>(mu_in, sg_in, wvp, spws + 2 * E, rmu2, rsgs,
                                                    nullptr, nullptr, vmu_t, vsg_t, vw2_t);

    vdp_attn_mfma<<<768, 256, 0, stream>>>(kmu_b, ksg_b, qsg_b, qmu_b, q1_b, q2_b,
                                           vmu_t, vsg_t, vw2_t, a_mu, a_sg);

    rowstats_kernel<<<NTOK, 256, 0, stream>>>(a_mu, a_sg, armu2, arsg);
    linear_vdp_kernel<0><<<lgrid, 256, 0, stream>>>(a_mu, a_sg, wo, spws + 3 * E, armu2, arsg,
                                                    out_mu, out_sg, nullptr, nullptr, nullptr);

    kl_kernel<<<512, 256, 0, stream>>>(wq, wk, wvp, wo, wqs, wks, wvs, wos, kl_out);
}

// Round 3
// 702.856 us; speedup vs baseline: 5.2958x; 1.3889x over previous
//
#include <hip/hip_runtime.h>
#include <math.h>

#define E 768
#define S 1024
#define BATCH 4
#define NH 12
#define HD 64
#define NTOK 4096  /* BATCH*S */

typedef __attribute__((ext_vector_type(8))) __bf16 bf16x8;
typedef __attribute__((ext_vector_type(4))) float f32x4;
typedef unsigned int u32;
typedef unsigned short u16;

__device__ __forceinline__ float sp_f(float x) {
    return fmaxf(x, 0.f) + log1pf(__expf(-fabsf(x)));
}
__device__ __forceinline__ u16 f2bf(float f) {
    u32 u = __float_as_uint(f);
    u = u + 0x7fffu + ((u >> 16) & 1u);   // RNE
    return (u16)(u >> 16);
}
__device__ __forceinline__ u32 pk2(float a, float b) {
    return (u32)f2bf(a) | ((u32)f2bf(b) << 16);
}
__device__ __forceinline__ float bfl(u32 u) { return __uint_as_float(u << 16); }
__device__ __forceinline__ float bfh(u32 u) { return __uint_as_float(u & 0xffff0000u); }

// ---------------------------------------------------------------- prep ----
__global__ void prep_kernel(const float* __restrict__ wqs, const float* __restrict__ wks,
                            const float* __restrict__ wvs, const float* __restrict__ wos,
                            float* __restrict__ spws, float* __restrict__ kl_out)
{
    int i = blockIdx.x * 256 + threadIdx.x;
    if (i < 4 * E) {
        const float* src;
        int j;
        if (i < E)            { src = wqs; j = i; }
        else if (i < 2 * E)   { src = wks; j = i - E; }
        else if (i < 3 * E)   { src = wvs; j = i - 2 * E; }
        else                  { src = wos; j = i - 3 * E; }
        spws[i] = sp_f(src[j]);
    }
    if (i == 4 * E) {
        *kl_out = 2.f * (logf(0.01f) - 1.f);
    }
}

// ----------------------------------------------------- input fp32 -> bf16 --
__global__ void conv_in_kernel(const float* __restrict__ a, const float* __restrict__ b,
                               u16* __restrict__ ab, u16* __restrict__ bb)
{
    size_t i = ((size_t)blockIdx.x * 256 + threadIdx.x) * 8;
    if (i >= (size_t)NTOK * E) return;
    float4 v0 = *(const float4*)(a + i), v1 = *(const float4*)(a + i + 4);
    *(uint4*)(ab + i) = make_uint4(pk2(v0.x, v0.y), pk2(v0.z, v0.w), pk2(v1.x, v1.y), pk2(v1.z, v1.w));
    float4 w0 = *(const float4*)(b + i), w1 = *(const float4*)(b + i + 4);
    *(uint4*)(bb + i) = make_uint4(pk2(w0.x, w0.y), pk2(w0.z, w0.w), pk2(w1.x, w1.y), pk2(w1.z, w1.w));
}

// -------------------------------------------- weight transpose + square ----
// W fp32 [k][j] -> Wt bf16 [j][k], W2t bf16 [j][k] = (W[k][j]^2)/768
__global__ void transpose_w_kernel(const float* __restrict__ W,
                                   u16* __restrict__ Wt, u16* __restrict__ W2t)
{
    __shared__ float T[32][33];
    const int j0 = blockIdx.x * 32, k0 = blockIdx.y * 32;
    const int tid = threadIdx.x;
    const int r = tid >> 3, c = (tid & 7) * 4;
    float4 v = *(const float4*)(W + (size_t)(k0 + r) * E + j0 + c);
    T[r][c] = v.x; T[r][c + 1] = v.y; T[r][c + 2] = v.z; T[r][c + 3] = v.w;
    __syncthreads();
    const int j = tid >> 3, kc = (tid & 7) * 4;
    float w0 = T[kc][j], w1 = T[kc + 1][j], w2 = T[kc + 2][j], w3 = T[kc + 3][j];
    size_t o = (size_t)(j0 + j) * E + k0 + kc;
    *(uint2*)(Wt + o) = make_uint2(pk2(w0, w1), pk2(w2, w3));
    const float s = 1.f / 768.f;
    *(uint2*)(W2t + o) = make_uint2(pk2(w0 * w0 * s, w1 * w1 * s), pk2(w2 * w2 * s, w3 * w3 * s));
}

// ------------------------------------------------------------ row stats ----
__global__ void rowstats_kernel(const float* __restrict__ mu, const float* __restrict__ sg,
                                float* __restrict__ rmu2, float* __restrict__ rsg)
{
    const int n = blockIdx.x;
    const int tid = threadIdx.x;
    const float* mrow = mu + (size_t)n * E;
    const float* srow = sg + (size_t)n * E;
    float s1 = 0.f, s2 = 0.f;
    for (int i = tid; i < E; i += 256) {
        float m = mrow[i];
        s1 += m * m;
        s2 += srow[i];
    }
    for (int off = 32; off; off >>= 1) {
        s1 += __shfl_xor(s1, off);
        s2 += __shfl_xor(s2, off);
    }
    __shared__ float r1[4], r2[4];
    int w = tid >> 6;
    if ((tid & 63) == 0) { r1[w] = s1; r2[w] = s2; }
    __syncthreads();
    if (tid == 0) {
        rmu2[n] = r1[0] + r1[1] + r1[2] + r1[3];
        rsg[n]  = r2[0] + r2[1] + r2[2] + r2[3];
    }
}

__global__ void rowstats_bf16_kernel(const u16* __restrict__ mu, const u16* __restrict__ sg,
                                     float* __restrict__ rmu2, float* __restrict__ rsg)
{
    const int n = blockIdx.x, tid = threadIdx.x;
    float s1 = 0.f, s2 = 0.f;
    if (tid < 96) {
        uint4 um = *(const uint4*)(mu + (size_t)n * E + tid * 8);
        uint4 us = *(const uint4*)(sg + (size_t)n * E + tid * 8);
        u32 ua[4] = {um.x, um.y, um.z, um.w};
        u32 ub[4] = {us.x, us.y, us.z, us.w};
#pragma unroll
        for (int j = 0; j < 4; ++j) {
            float a0 = bfl(ua[j]), a1 = bfh(ua[j]);
            s1 += a0 * a0 + a1 * a1;
            s2 += bfl(ub[j]) + bfh(ub[j]);
        }
    }
    for (int off = 32; off; off >>= 1) {
        s1 += __shfl_xor(s1, off);
        s2 += __shfl_xor(s2, off);
    }
    __shared__ float r1[2], r2[2];
    if ((tid & 63) == 0) { r1[tid >> 6] = s1; r2[tid >> 6] = s2; }
    __syncthreads();
    if (tid == 0) { rmu2[n] = r1[0] + r1[1]; rsg[n] = r2[0] + r2[1]; }
}

// ----------------------------------------------------- linear (bf16 MFMA) --
// A bf16 row-major [4096][768]; B = Wt/W2t bf16 [dout][k]. No LDS: all MFMA
// operands are direct 16B global loads (L2-resident per XCD-swizzled chunk).
// MODE 0: fp32 out + double softplus (O-proj)
// MODE 1: Q -> bf16 [bh][s][d]: mu, sg, (mu^2+sg)/64
// MODE 2: K -> bf16 [bh][s][d]: mu, sg, mu^2/64
// MODE 3: V -> bf16 [bh][d][s] (transposed via LDS): mu, sg, mu^2+sg
template<int MODE>
__global__ __launch_bounds__(256) void linear_mfma(
    const u16* __restrict__ Amu, const u16* __restrict__ Asg,
    const u16* __restrict__ Wt, const u16* __restrict__ W2t,
    const float* __restrict__ spw_a, const float* __restrict__ rmu2, const float* __restrict__ rsg,
    float* __restrict__ mu_out, float* __restrict__ sg_out,
    u16* __restrict__ b0, u16* __restrict__ b1, u16* __restrict__ b2)
{
    const int wgid = blockIdx.x;                 // 768 = 64 Mblk x 12 Nblk
    const int xcd = wgid & 7, local = wgid >> 3; // per XCD: 8 Mblk x 12 Nblk
    const int m_blk = xcd * 8 + local / 12;
    const int n_blk = local % 12;
    const int tid = threadIdx.x, wv = tid >> 6, lane = tid & 63, g = lane >> 4, q15 = lane & 15;
    const int row0 = m_blk * 64 + wv * 16;
    const int col0 = n_blk * 64;

    const u16* pAm = Amu + (size_t)(row0 + q15) * E + g * 8;
    const u16* pAs = Asg + (size_t)(row0 + q15) * E + g * 8;
    const u16* pW  = Wt  + (size_t)(col0 + q15) * E + g * 8;
    const u16* pW2 = W2t + (size_t)(col0 + q15) * E + g * 8;

    f32x4 acc1[4], acc2[4];
#pragma unroll
    for (int ni = 0; ni < 4; ++ni) { acc1[ni] = (f32x4){0.f,0.f,0.f,0.f}; acc2[ni] = (f32x4){0.f,0.f,0.f,0.f}; }

    bf16x8 am0 = *(const bf16x8*)(pAm);
    bf16x8 as0 = *(const bf16x8*)(pAs);
    bf16x8 bw0[4], b20[4];
#pragma unroll
    for (int ni = 0; ni < 4; ++ni) {
        bw0[ni] = *(const bf16x8*)(pW  + (size_t)ni * 16 * E);
        b20[ni] = *(const bf16x8*)(pW2 + (size_t)ni * 16 * E);
    }

    for (int k = 0; k < E; k += 32) {
        bf16x8 am1 = am0, as1 = as0, bw1[4], b21[4];
#pragma unroll
        for (int ni = 0; ni < 4; ++ni) { bw1[ni] = bw0[ni]; b21[ni] = b20[ni]; }
        if (k + 32 < E) {
            am1 = *(const bf16x8*)(pAm + k + 32);
            as1 = *(const bf16x8*)(pAs + k + 32);
#pragma unroll
            for (int ni = 0; ni < 4; ++ni) {
                bw1[ni] = *(const bf16x8*)(pW  + (size_t)ni * 16 * E + k + 32);
                b21[ni] = *(const bf16x8*)(pW2 + (size_t)ni * 16 * E + k + 32);
            }
        }
#pragma unroll
        for (int ni = 0; ni < 4; ++ni) {
            acc1[ni] = __builtin_amdgcn_mfma_f32_16x16x32_bf16(am0, bw0[ni], acc1[ni], 0, 0, 0);
            acc2[ni] = __builtin_amdgcn_mfma_f32_16x16x32_bf16(as0, b20[ni], acc2[ni], 0, 0, 0);
        }
        am0 = am1; as0 = as1;
#pragma unroll
        for (int ni = 0; ni < 4; ++ni) { bw0[ni] = bw1[ni]; b20[ni] = b21[ni]; }
    }

    const float inv_din2 = 1.f / (768.f * 768.f);
    const float inv_dout = 1.f / 768.f;

    if constexpr (MODE == 3) {
        __shared__ u16 T[64][72];
        float vm[4][4], vs[4][4], vw[4][4];
#pragma unroll
        for (int r = 0; r < 4; ++r) {
            const int row = row0 + g * 4 + r;
            const float rr = rmu2[row] * inv_din2 + rsg[row] * inv_dout;
#pragma unroll
            for (int ni = 0; ni < 4; ++ni) {
                const int col = col0 + ni * 16 + q15;
                float mu = acc1[ni][r];
                float sg = sp_f(acc2[ni][r] + rr * spw_a[col]);
                vm[ni][r] = mu; vs[ni][r] = sg; vw[ni][r] = mu * mu + sg;
            }
        }
        const int bb = (m_blk * 64) >> 10, s0 = (m_blk * 64) & 1023;
        const int h = n_blk;
#pragma unroll
        for (int a = 0; a < 3; ++a) {
            __syncthreads();
#pragma unroll
            for (int r = 0; r < 4; ++r)
#pragma unroll
                for (int ni = 0; ni < 4; ++ni) {
                    float v = (a == 0) ? vm[ni][r] : (a == 1) ? vs[ni][r] : vw[ni][r];
                    T[ni * 16 + q15][wv * 16 + g * 4 + r] = f2bf(v);
                }
            __syncthreads();
            const int d = tid >> 2, sc = (tid & 3) * 16;
            u16* dst = (a == 0) ? b0 : (a == 1) ? b1 : b2;
            size_t ga = ((size_t)((bb * 12 + h) * 64 + d) << 10) + s0 + sc;
            *(uint2*)(dst + ga)      = *(const uint2*)&T[d][sc];
            *(uint2*)(dst + ga + 4)  = *(const uint2*)&T[d][sc + 4];
            *(uint2*)(dst + ga + 8)  = *(const uint2*)&T[d][sc + 8];
            *(uint2*)(dst + ga + 12) = *(const uint2*)&T[d][sc + 12];
        }
    } else {
#pragma unroll
        for (int r = 0; r < 4; ++r) {
            const int row = row0 + g * 4 + r;
            const float rr = rmu2[row] * inv_din2 + rsg[row] * inv_dout;
#pragma unroll
            for (int ni = 0; ni < 4; ++ni) {
                const int col = col0 + ni * 16 + q15;
                float mu = acc1[ni][r];
                float sg = sp_f(acc2[ni][r] + rr * spw_a[col]);
                if (MODE == 0) {
                    sg = sp_f(sg);
                    mu_out[(size_t)row * E + col] = mu;
                    sg_out[(size_t)row * E + col] = sg;
                } else {
                    const int h = n_blk, d = ni * 16 + q15;
                    const int bb = row >> 10, s = row & 1023;
                    size_t rb = ((size_t)(bb * 12 + h) << 16) + ((size_t)s << 6) + d;
                    b0[rb] = f2bf(mu);
                    b1[rb] = f2bf(sg);
                    b2[rb] = f2bf(MODE == 1 ? (mu * mu + sg) * (1.f / 64.f)
                                            : (mu * mu) * (1.f / 64.f));
                }
            }
        }
    }
}

// ------------------------------------------------------------- attention ---
// 128 threads = 2 waves. Wave kh handles K-half [kh*512, +512) of the same
// 16 q-rows; softmax stats merged via LDS; final accumulators reduced via LDS
// (reduce buffer aliases the per-wave P-tile region). No barriers in K loop.
__global__ __launch_bounds__(128) void vdp_attn2(
    const u16* __restrict__ Kmu, const u16* __restrict__ Ksg, const u16* __restrict__ Asq,
    const u16* __restrict__ Qmu, const u16* __restrict__ Q1v, const u16* __restrict__ Q2v,
    const u16* __restrict__ Vmu, const u16* __restrict__ Vsg, const u16* __restrict__ Vw2,
    u16* __restrict__ om, u16* __restrict__ osg)
{
    __shared__ __align__(16) unsigned char smem[12288 + 256];
    u16 (*Pl)[3][16][64] = (u16 (*)[3][16][64])smem;      // [kh][arr][q][k]
    float (*Red)[16][64] = (float (*)[16][64])smem;       // [arr][q][d] (aliases Pl)
    float* Sm = (float*)(smem + 12288);
    float* Sl = Sm + 32;

    const int wgid = blockIdx.x;                 // 3072 = 48 bh x 64 qt
    const int seq = (wgid & 7) * 384 + (wgid >> 3);
    const int bh = seq >> 6, qt = seq & 63;
    const int tid = threadIdx.x, kh = tid >> 6, lane = tid & 63, g = lane >> 4, q15 = lane & 15;
    const size_t hb = (size_t)bh << 16;

    const size_t qoff = hb + (size_t)((qt * 16 + q15) << 6) + g * 8;
    bf16x8 bq[2], b1f[2], b2f[2];
    bq[0]  = *(const bf16x8*)(Qmu + qoff); bq[1]  = *(const bf16x8*)(Qmu + qoff + 32);
    b1f[0] = *(const bf16x8*)(Q1v + qoff); b1f[1] = *(const bf16x8*)(Q1v + qoff + 32);
    b2f[0] = *(const bf16x8*)(Q2v + qoff); b2f[1] = *(const bf16x8*)(Q2v + qoff + 32);

    // ---- pass 1: softmax stats over this wave's K half
    float m = -1e30f, l = 0.f;
    for (int tt = 0; tt < 8; ++tt) {
        const int t = kh * 8 + tt;
        f32x4 sc[4];
#pragma unroll
        for (int kt = 0; kt < 4; ++kt) sc[kt] = (f32x4){0.f, 0.f, 0.f, 0.f};
        __builtin_amdgcn_s_setprio(1);
#pragma unroll
        for (int kt = 0; kt < 4; ++kt) {
            size_t ar = hb + (size_t)(((t << 6) + (kt << 4) + q15) << 6) + g * 8;
            sc[kt] = __builtin_amdgcn_mfma_f32_16x16x32_bf16(*(const bf16x8*)(Kmu + ar),      bq[0], sc[kt], 0, 0, 0);
            sc[kt] = __builtin_amdgcn_mfma_f32_16x16x32_bf16(*(const bf16x8*)(Kmu + ar + 32), bq[1], sc[kt], 0, 0, 0);
        }
        __builtin_amdgcn_s_setprio(0);
        float tm = -1e30f;
#pragma unroll
        for (int kt = 0; kt < 4; ++kt)
#pragma unroll
            for (int r = 0; r < 4; ++r) tm = fmaxf(tm, sc[kt][r]);
        tm = fmaxf(tm, __shfl_xor(tm, 16));
        tm = fmaxf(tm, __shfl_xor(tm, 32));
        tm *= 0.125f;
        float mn = fmaxf(m, tm);
        float ls = 0.f;
#pragma unroll
        for (int kt = 0; kt < 4; ++kt)
#pragma unroll
            for (int r = 0; r < 4; ++r) ls += __expf(sc[kt][r] * 0.125f - mn);
        ls += __shfl_xor(ls, 16);
        ls += __shfl_xor(ls, 32);
        l = l * __expf(m - mn) + ls;
        m = mn;
    }
    if (lane < 16) { Sm[kh * 16 + lane] = m; Sl[kh * 16 + lane] = l; }
    __syncthreads();
    {
        float m0 = Sm[q15], m1 = Sm[16 + q15];
        float l0 = Sl[q15], l1 = Sl[16 + q15];
        m = fmaxf(m0, m1);
        l = l0 * __expf(m0 - m) + l1 * __expf(m1 - m);
    }
    const float linv = 1.f / l;

    // ---- pass 2
    f32x4 accm[4], accd[4], acce[4];
#pragma unroll
    for (int nt = 0; nt < 4; ++nt) {
        accm[nt] = (f32x4){0.f, 0.f, 0.f, 0.f};
        accd[nt] = (f32x4){0.f, 0.f, 0.f, 0.f};
        acce[nt] = (f32x4){0.f, 0.f, 0.f, 0.f};
    }

    for (int tt = 0; tt < 8; ++tt) {
        const int t = kh * 8 + tt;
        f32x4 sc[4], sgc[4];
#pragma unroll
        for (int kt = 0; kt < 4; ++kt) { sc[kt] = (f32x4){0.f,0.f,0.f,0.f}; sgc[kt] = (f32x4){0.f,0.f,0.f,0.f}; }
        __builtin_amdgcn_s_setprio(1);
#pragma unroll
        for (int kt = 0; kt < 4; ++kt) {
            size_t ar = hb + (size_t)(((t << 6) + (kt << 4) + q15) << 6) + g * 8;
            sc[kt]  = __builtin_amdgcn_mfma_f32_16x16x32_bf16(*(const bf16x8*)(Kmu + ar),      bq[0],  sc[kt],  0, 0, 0);
            sc[kt]  = __builtin_amdgcn_mfma_f32_16x16x32_bf16(*(const bf16x8*)(Kmu + ar + 32), bq[1],  sc[kt],  0, 0, 0);
            sgc[kt] = __builtin_amdgcn_mfma_f32_16x16x32_bf16(*(const bf16x8*)(Ksg + ar),      b1f[0], sgc[kt], 0, 0, 0);
            sgc[kt] = __builtin_amdgcn_mfma_f32_16x16x32_bf16(*(const bf16x8*)(Ksg + ar + 32), b1f[1], sgc[kt], 0, 0, 0);
            sgc[kt] = __builtin_amdgcn_mfma_f32_16x16x32_bf16(*(const bf16x8*)(Asq + ar),      b2f[0], sgc[kt], 0, 0, 0);
            sgc[kt] = __builtin_amdgcn_mfma_f32_16x16x32_bf16(*(const bf16x8*)(Asq + ar + 32), b2f[1], sgc[kt], 0, 0, 0);
        }
        __builtin_amdgcn_s_setprio(0);
#pragma unroll
        for (int kt = 0; kt < 4; ++kt) {
            float p[4], sw[4];
#pragma unroll
            for (int r = 0; r < 4; ++r) {
                float pv = __expf(sc[kt][r] * 0.125f - m) * linv;
                p[r] = pv;
                float gq = pv - pv * pv; gq *= gq;
                sw[r] = gq * sgc[kt][r] * (1.f / 67108864.f);
            }
            int kb = (kt << 4) + (g << 2);
#pragma unroll
            for (int rp = 0; rp < 4; rp += 2) {
                int k = kb + rp;
                int widx = (((k >> 3) ^ (q15 & 7)) << 3) | (k & 7);
                *(u32*)&Pl[kh][0][q15][widx] = pk2(p[rp], p[rp + 1]);
                *(u32*)&Pl[kh][1][q15][widx] = pk2(p[rp] * p[rp] * (1.f / 1024.f),
                                                   p[rp + 1] * p[rp + 1] * (1.f / 1024.f));
                *(u32*)&Pl[kh][2][q15][widx] = pk2(sw[rp], sw[rp + 1]);
            }
        }
        __builtin_amdgcn_s_setprio(1);
#pragma unroll
        for (int ks = 0; ks < 2; ++ks) {
            int cc = (((ks << 2) | g) ^ (q15 & 7)) << 3;
            bf16x8 pa  = *(const bf16x8*)&Pl[kh][0][q15][cc];
            bf16x8 p2a = *(const bf16x8*)&Pl[kh][1][q15][cc];
            bf16x8 swa = *(const bf16x8*)&Pl[kh][2][q15][cc];
#pragma unroll
            for (int nt = 0; nt < 4; ++nt) {
                size_t vr = hb + (size_t)(((nt << 4) + q15) << 10) + (t << 6) + (ks << 5) + g * 8;
                accm[nt] = __builtin_amdgcn_mfma_f32_16x16x32_bf16(pa,  *(const bf16x8*)(Vmu + vr), accm[nt], 0, 0, 0);
                accd[nt] = __builtin_amdgcn_mfma_f32_16x16x32_bf16(p2a, *(const bf16x8*)(Vsg + vr), accd[nt], 0, 0, 0);
                acce[nt] = __builtin_amdgcn_mfma_f32_16x16x32_bf16(swa, *(const bf16x8*)(Vw2 + vr), acce[nt], 0, 0, 0);
            }
        }
        __builtin_amdgcn_s_setprio(0);
    }

    __syncthreads();
    if (kh == 1) {
#pragma unroll
        for (int nt = 0; nt < 4; ++nt)
#pragma unroll
            for (int r = 0; r < 4; ++r) {
                Red[0][g * 4 + r][nt * 16 + q15] = accm[nt][r];
                Red[1][g * 4 + r][nt * 16 + q15] = accd[nt][r];
                Red[2][g * 4 + r][nt * 16 + q15] = acce[nt][r];
            }
    }
    __syncthreads();
    if (kh == 0) {
        const int b_ = bh / 12, h_ = bh % 12;
#pragma unroll
        for (int nt = 0; nt < 4; ++nt)
#pragma unroll
            for (int r = 0; r < 4; ++r) {
                int q = g * 4 + r, d = nt * 16 + q15;
                float mu = accm[nt][r] + Red[0][q][d];
                float dt = accd[nt][r] + Red[1][q][d];
                float et = acce[nt][r] + Red[2][q][d];
                int srow = qt * 16 + q;
                size_t o = (size_t)(b_ * 1024 + srow) * E + h_ * 64 + d;
                om[o]  = f2bf(mu);
                osg[o] = f2bf(sp_f(dt + et));
            }
    }
}

// ------------------------------------------------------------------- kl ----
__global__ void kl_kernel(const float* __restrict__ w0, const float* __restrict__ w1,
                          const float* __restrict__ w2, const float* __restrict__ w3,
                          const float* __restrict__ s0, const float* __restrict__ s1,
                          const float* __restrict__ s2, const float* __restrict__ s3,
                          float* __restrict__ kl_out)
{
    const int gid = blockIdx.x * 256 + threadIdx.x;
    const int gsz = gridDim.x * 256;
    float acc = 0.f;
    const float cw = 100.f / ((float)E * (float)E);
#pragma unroll
    for (int mm = 0; mm < 4; ++mm) {
        const float* w = (mm == 0) ? w0 : (mm == 1) ? w1 : (mm == 2) ? w2 : w3;
        const float* sv = (mm == 0) ? s0 : (mm == 1) ? s1 : (mm == 2) ? s2 : s3;
        for (int i = gid; i < E * E; i += gsz) { float x = w[i]; acc += x * x * cw; }
        for (int i = gid; i < E; i += gsz) { float x = sv[i]; acc += (-x + sp_f(x) * 100.f) * (1.f / (float)E); }
    }
    for (int off = 32; off; off >>= 1) acc += __shfl_xor(acc, off);
    __shared__ float r[4];
    int tid = threadIdx.x, w_ = tid >> 6;
    if ((tid & 63) == 0) r[w_] = acc;
    __syncthreads();
    if (tid == 0) atomicAdd(kl_out, 0.5f * (r[0] + r[1] + r[2] + r[3]));
}

// --------------------------------------------------------------- launch ----
extern "C" void kernel_launch(void* const* d_in, const int* in_sizes, int n_in,
                              void* d_out, int out_size, void* d_ws, size_t ws_size,
                              hipStream_t stream)
{
    const float* mu_in = (const float*)d_in[0];
    const float* sg_in = (const float*)d_in[1];
    const float* wq  = (const float*)d_in[2];
    const float* wqs = (const float*)d_in[3];
    const float* wk  = (const float*)d_in[4];
    const float* wks = (const float*)d_in[5];
    const float* wvp = (const float*)d_in[6];
    const float* wvs = (const float*)d_in[7];
    const float* wo  = (const float*)d_in[8];
    const float* wos = (const float*)d_in[9];

    float* out_mu = (float*)d_out;
    float* out_sg = out_mu + (size_t)NTOK * E;
    float* kl_out = out_mu + 2 * (size_t)NTOK * E;

    float* ws = (float*)d_ws;
    size_t off = 0;
    auto allocf = [&](size_t n) { float* p = ws + off; off += n; return p; };
    float* rmu2  = allocf(NTOK);
    float* rsgs  = allocf(NTOK);
    float* armu2 = allocf(NTOK);
    float* arsg  = allocf(NTOK);
    float* spws  = allocf(4 * E);   // 19456 floats total -> 16B aligned tail

    const size_t BFN = (size_t)NTOK * E;       // 3,145,728
    const size_t WFN = (size_t)E * E;          // 589,824
    u16* ub = (u16*)(ws + off);
    size_t uoff = 0;
    auto allocu = [&](size_t n) { u16* p = ub + uoff; uoff += n; return p; };
    u16* Xmu = allocu(BFN);  u16* Xsg = allocu(BFN);
    u16* Wt0 = allocu(WFN);  u16* W2t0 = allocu(WFN);
    u16* Wt1 = allocu(WFN);  u16* W2t1 = allocu(WFN);
    u16* Wt2 = allocu(WFN);  u16* W2t2 = allocu(WFN);
    u16* Wt3 = allocu(WFN);  u16* W2t3 = allocu(WFN);
    u16* qmu_b = allocu(BFN); u16* qsg_b = allocu(BFN); u16* q1_b = allocu(BFN);
    u16* kmu_b = allocu(BFN); u16* ksg_b = allocu(BFN); u16* q2_b = allocu(BFN);
    u16* vmu_t = allocu(BFN); u16* vsg_t = allocu(BFN); u16* vw2_t = allocu(BFN);
    u16* amu_b = allocu(BFN); u16* asg_b = allocu(BFN);
    (void)ws_size; (void)in_sizes; (void)n_in; (void)out_size;

    prep_kernel<<<13, 256, 0, stream>>>(wqs, wks, wvs, wos, spws, kl_out);
    conv_in_kernel<<<1536, 256, 0, stream>>>(mu_in, sg_in, Xmu, Xsg);
    dim3 tgrid(24, 24);
    transpose_w_kernel<<<tgrid, 256, 0, stream>>>(wq,  Wt0, W2t0);
    transpose_w_kernel<<<tgrid, 256, 0, stream>>>(wk,  Wt1, W2t1);
    transpose_w_kernel<<<tgrid, 256, 0, stream>>>(wvp, Wt2, W2t2);
    transpose_w_kernel<<<tgrid, 256, 0, stream>>>(wo,  Wt3, W2t3);
    rowstats_kernel<<<NTOK, 256, 0, stream>>>(mu_in, sg_in, rmu2, rsgs);

    linear_mfma<1><<<768, 256, 0, stream>>>(Xmu, Xsg, Wt0, W2t0, spws + 0 * E, rmu2, rsgs,
                                            nullptr, nullptr, qmu_b, qsg_b, q1_b);
    linear_mfma<2><<<768, 256, 0, stream>>>(Xmu, Xsg, Wt1, W2t1, spws + 1 * E, rmu2, rsgs,
                                            nullptr, nullptr, kmu_b, ksg_b, q2_b);
    linear_mfma<3><<<768, 256, 0, stream>>>(Xmu, Xsg, Wt2, W2t2, spws + 2 * E, rmu2, rsgs,
                                            nullptr, nullptr, vmu_t, vsg_t, vw2_t);

    vdp_attn2<<<3072, 128, 0, stream>>>(kmu_b, ksg_b, qsg_b, qmu_b, q1_b, q2_b,
                                        vmu_t, vsg_t, vw2_t, amu_b, asg_b);

    rowstats_bf16_kernel<<<NTOK, 128, 0, stream>>>(amu_b, asg_b, armu2, arsg);
    linear_mfma<0><<<768, 256, 0, stream>>>(amu_b, asg_b, Wt3, W2t3, spws + 3 * E, armu2, arsg,
                                            out_mu, out_sg, nullptr, nullptr, nullptr);

    kl_kernel<<<512, 256, 0, stream>>>(wq, wk, wvp, wo, wqs, wks, wvs, wos, kl_out);
}

// Round 4
// 454.205 us; speedup vs baseline: 8.1950x; 1.5474x over previous
//
#include <hip/hip_runtime.h>
#include <math.h>

#define E 768
#define NTOK 4096  /* BATCH*S */

typedef __attribute__((ext_vector_type(8))) __bf16 bf16x8;
typedef __attribute__((ext_vector_type(4))) float f32x4;
typedef unsigned int u32;
typedef unsigned short u16;

#define BFN ((size_t)NTOK * E)
#define WFN ((size_t)E * E)
#define QSC 1.4901161193847656e-08f   /* 2^-26: folds /64 (score/d) and /(1024*1024*64) epilogue consts */
#define C2E 0.18033688011112042f      /* 0.125 * log2(e) */

__device__ __forceinline__ float sp_f(float x) {
    return fmaxf(x, 0.f) + log1pf(__expf(-fabsf(x)));
}
__device__ __forceinline__ u16 f2bf(float f) {
    u32 u = __float_as_uint(f);
    u += 0x7fffu + ((u >> 16) & 1u);
    return (u16)(u >> 16);
}
__device__ __forceinline__ u32 pk2(float a, float b) {
    return (u32)f2bf(a) | ((u32)f2bf(b) << 16);
}
__device__ __forceinline__ u32 cvtpk(float a, float b) {
    u32 r; asm("v_cvt_pk_bf16_f32 %0, %1, %2" : "=v"(r) : "v"(a), "v"(b)); return r;
}
__device__ __forceinline__ float ex2(float x) {
    float r; asm("v_exp_f32 %0, %1" : "=v"(r) : "v"(x)); return r;
}
__device__ __forceinline__ float lg2(float x) {
    float r; asm("v_log_f32 %0, %1" : "=v"(r) : "v"(x)); return r;
}
__device__ __forceinline__ float bfl(u32 u) { return __uint_as_float(u << 16); }
__device__ __forceinline__ float bfh(u32 u) { return __uint_as_float(u & 0xffff0000u); }

#define GLL16(gp, lp) __builtin_amdgcn_global_load_lds( \
    (const __attribute__((address_space(1))) u32*)(gp), \
    (__attribute__((address_space(3))) u32*)(lp), 16, 0, 0)

// ---------------------------------------------------------------- prep ----
__global__ void prep_kernel(const float* __restrict__ wqs, const float* __restrict__ wks,
                            const float* __restrict__ wvs, const float* __restrict__ wos,
                            float* __restrict__ spws, float* __restrict__ kl_out)
{
    int i = blockIdx.x * 256 + threadIdx.x;
    if (i < 4 * E) {
        const float* src;
        int j;
        if (i < E)            { src = wqs; j = i; }
        else if (i < 2 * E)   { src = wks; j = i - E; }
        else if (i < 3 * E)   { src = wvs; j = i - 2 * E; }
        else                  { src = wos; j = i - 3 * E; }
        spws[i] = sp_f(src[j]);
    }
    if (i == 4 * E) *kl_out = 2.f * (logf(0.01f) - 1.f);
}

// ---------------------------------------- fused fp32->bf16 + row stats ----
__global__ __launch_bounds__(128) void convstats_kernel(
    const float* __restrict__ mu, const float* __restrict__ sg,
    u16* __restrict__ Xmu, u16* __restrict__ Xsg,
    float* __restrict__ rmu2, float* __restrict__ rsg)
{
    const int n = blockIdx.x, tid = threadIdx.x;
    float s1 = 0.f, s2 = 0.f;
    if (tid < 96) {
        size_t o = (size_t)n * E + tid * 8;
        float4 a0 = *(const float4*)(mu + o), a1 = *(const float4*)(mu + o + 4);
        float4 b0 = *(const float4*)(sg + o), b1 = *(const float4*)(sg + o + 4);
        *(uint4*)(Xmu + o) = make_uint4(pk2(a0.x, a0.y), pk2(a0.z, a0.w), pk2(a1.x, a1.y), pk2(a1.z, a1.w));
        *(uint4*)(Xsg + o) = make_uint4(pk2(b0.x, b0.y), pk2(b0.z, b0.w), pk2(b1.x, b1.y), pk2(b1.z, b1.w));
        s1 = a0.x*a0.x + a0.y*a0.y + a0.z*a0.z + a0.w*a0.w + a1.x*a1.x + a1.y*a1.y + a1.z*a1.z + a1.w*a1.w;
        s2 = b0.x + b0.y + b0.z + b0.w + b1.x + b1.y + b1.z + b1.w;
    }
    for (int off = 32; off; off >>= 1) {
        s1 += __shfl_xor(s1, off);
        s2 += __shfl_xor(s2, off);
    }
    __shared__ float r1[2], r2[2];
    if ((tid & 63) == 0) { r1[tid >> 6] = s1; r2[tid >> 6] = s2; }
    __syncthreads();
    if (tid == 0) { rmu2[n] = r1[0] + r1[1]; rsg[n] = r2[0] + r2[1]; }
}

__global__ __launch_bounds__(128) void rowstats_bf16_kernel(
    const u16* __restrict__ mu, const u16* __restrict__ sg,
    float* __restrict__ rmu2, float* __restrict__ rsg)
{
    const int n = blockIdx.x, tid = threadIdx.x;
    float s1 = 0.f, s2 = 0.f;
    if (tid < 96) {
        uint4 um = *(const uint4*)(mu + (size_t)n * E + tid * 8);
        uint4 us = *(const uint4*)(sg + (size_t)n * E + tid * 8);
        u32 ua[4] = {um.x, um.y, um.z, um.w};
        u32 ub[4] = {us.x, us.y, us.z, us.w};
#pragma unroll
        for (int j = 0; j < 4; ++j) {
            float a0 = bfl(ua[j]), a1 = bfh(ua[j]);
            s1 += a0 * a0 + a1 * a1;
            s2 += bfl(ub[j]) + bfh(ub[j]);
        }
    }
    for (int off = 32; off; off >>= 1) {
        s1 += __shfl_xor(s1, off);
        s2 += __shfl_xor(s2, off);
    }
    __shared__ float r1[2], r2[2];
    if ((tid & 63) == 0) { r1[tid >> 6] = s1; r2[tid >> 6] = s2; }
    __syncthreads();
    if (tid == 0) { rmu2[n] = r1[0] + r1[1]; rsg[n] = r2[0] + r2[1]; }
}

// -------------------------------------------- weight transpose + square ----
__global__ void transpose_w_kernel(const float* __restrict__ W,
                                   u16* __restrict__ Wt, u16* __restrict__ W2t)
{
    __shared__ float T[32][33];
    const int j0 = blockIdx.x * 32, k0 = blockIdx.y * 32;
    const int tid = threadIdx.x;
    const int r = tid >> 3, c = (tid & 7) * 4;
    float4 v = *(const float4*)(W + (size_t)(k0 + r) * E + j0 + c);
    T[r][c] = v.x; T[r][c + 1] = v.y; T[r][c + 2] = v.z; T[r][c + 3] = v.w;
    __syncthreads();
    const int j = tid >> 3, kc = (tid & 7) * 4;
    float w0 = T[kc][j], w1 = T[kc + 1][j], w2 = T[kc + 2][j], w3 = T[kc + 3][j];
    size_t o = (size_t)(j0 + j) * E + k0 + kc;
    *(uint2*)(Wt + o) = make_uint2(pk2(w0, w1), pk2(w2, w3));
    const float s = 1.f / 768.f;
    *(uint2*)(W2t + o) = make_uint2(pk2(w0 * w0 * s, w1 * w1 * s), pk2(w2 * w2 * s, w3 * w3 * s));
}

// --------------------------------------- linear (LDS-staged bf16 MFMA) ----
// 128M x 64N tile, BK=64, 4 waves (each 32Mx64N). global_load_lds staging with
// chunk-XOR-swizzled SOURCE (linear LDS dest), 2-barrier K-loop (m97 style).
// MODE 1: fused QKV (N=2304): n_blk/12 -> proj, epilogues per proj.
// MODE 0: O-proj (N=768): fp32 out + double softplus.
template<int MODE>
__global__ __launch_bounds__(256, 3) void linear_fused(
    const u16* __restrict__ Am, const u16* __restrict__ As,
    const u16* __restrict__ Wt, const u16* __restrict__ W2t,
    const float* __restrict__ spws, const float* __restrict__ rmu2, const float* __restrict__ rsg,
    float* __restrict__ mu_out, float* __restrict__ sg_out, u16* __restrict__ QKVB)
{
    __shared__ __align__(16) u16 L[24576];   // 48KB: Amu(16K) Asg(16K) Wt(8K) W2t(8K)

    const int wgid = blockIdx.x;
    const int NW = (MODE == 1) ? 144 : 48;
    const int NB = (MODE == 1) ? 36 : 12;
    const int swz = (wgid & 7) * NW + (wgid >> 3);
    const int m_blk = swz / NB, n_blk = swz % NB;
    const int m0 = m_blk * 128, col0 = n_blk * 64;
    const int tid = threadIdx.x, wv = tid >> 6, lane = tid & 63;
    const int g = lane >> 4, q15 = lane & 15;

    // staging map: chunk ch = j*256+tid; arrays 0..1023=Amu 1024..2047=Asg
    // 2048..2559=Wt 2560..3071=W2t; source chunk pre-swizzled: c ^ (row&7)
    const u16* sp_[12];
#pragma unroll
    for (int j = 0; j < 12; ++j) {
        int ch = j * 256 + tid;
        int arr = (ch < 1024) ? 0 : (ch < 2048) ? 1 : (ch < 2560) ? 2 : 3;
        int local = ch - ((arr == 0) ? 0 : (arr == 1) ? 1024 : (arr == 2) ? 2048 : 2560);
        int r = local >> 3, c = local & 7;
        int cs = (c ^ (r & 7)) * 8;
        const u16* base = (arr == 0) ? (Am + (size_t)(m0 + r) * E) :
                          (arr == 1) ? (As + (size_t)(m0 + r) * E) :
                          (arr == 2) ? (Wt + (size_t)(col0 + r) * E) :
                                       (W2t + (size_t)(col0 + r) * E);
        sp_[j] = base + cs;
    }

    f32x4 acc1[2][4], acc2[2][4];
#pragma unroll
    for (int mt = 0; mt < 2; ++mt)
#pragma unroll
        for (int nt = 0; nt < 4; ++nt) {
            acc1[mt][nt] = (f32x4){0.f, 0.f, 0.f, 0.f};
            acc2[mt][nt] = (f32x4){0.f, 0.f, 0.f, 0.f};
        }

    for (int t = 0; t < 12; ++t) {
#pragma unroll
        for (int j = 0; j < 12; ++j)
            GLL16(sp_[j] + t * 64, (u16*)((char*)L + j * 4096 + wv * 1024));
        __syncthreads();
#pragma unroll
        for (int kk = 0; kk < 2; ++kk) {
            bf16x8 am[2], asg[2];
#pragma unroll
            for (int mt = 0; mt < 2; ++mt) {
                int r = wv * 32 + mt * 16 + q15;
                int c = ((kk * 4 + g) ^ (r & 7)) * 8;
                am[mt]  = *(const bf16x8*)&L[(r << 6) + c];
                asg[mt] = *(const bf16x8*)&L[8192 + (r << 6) + c];
            }
#pragma unroll
            for (int nt = 0; nt < 4; ++nt) {
                int rb = nt * 16 + q15;
                int cb = ((kk * 4 + g) ^ (rb & 7)) * 8;
                bf16x8 bw = *(const bf16x8*)&L[16384 + (rb << 6) + cb];
                bf16x8 b2 = *(const bf16x8*)&L[20480 + (rb << 6) + cb];
                acc1[0][nt] = __builtin_amdgcn_mfma_f32_16x16x32_bf16(am[0], bw, acc1[0][nt], 0, 0, 0);
                acc1[1][nt] = __builtin_amdgcn_mfma_f32_16x16x32_bf16(am[1], bw, acc1[1][nt], 0, 0, 0);
                acc2[0][nt] = __builtin_amdgcn_mfma_f32_16x16x32_bf16(asg[0], b2, acc2[0][nt], 0, 0, 0);
                acc2[1][nt] = __builtin_amdgcn_mfma_f32_16x16x32_bf16(asg[1], b2, acc2[1][nt], 0, 0, 0);
            }
        }
        __syncthreads();
    }

    const float inv2 = 1.f / (768.f * 768.f), invd = 1.f / 768.f;
    float rr[2][4];
#pragma unroll
    for (int mt = 0; mt < 2; ++mt)
#pragma unroll
        for (int r = 0; r < 4; ++r) {
            int row = m0 + wv * 32 + mt * 16 + g * 4 + r;
            rr[mt][r] = rmu2[row] * inv2 + rsg[row] * invd;
        }

    if (MODE == 0) {
#pragma unroll
        for (int mt = 0; mt < 2; ++mt)
#pragma unroll
            for (int nt = 0; nt < 4; ++nt)
#pragma unroll
                for (int r = 0; r < 4; ++r) {
                    int row = m0 + wv * 32 + mt * 16 + g * 4 + r;
                    int col = col0 + nt * 16 + q15;
                    float mu = acc1[mt][nt][r];
                    float sg = sp_f(sp_f(acc2[mt][nt][r] + rr[mt][r] * spws[col]));
                    mu_out[(size_t)row * E + col] = mu;
                    sg_out[(size_t)row * E + col] = sg;
                }
    } else {
        const int proj = n_blk / 12, h = n_blk % 12;
        if (proj < 2) {
            u16* b0 = QKVB + (size_t)(proj * 3 + 0) * BFN;
            u16* b1 = QKVB + (size_t)(proj * 3 + 1) * BFN;
            u16* b2 = QKVB + (size_t)(proj * 3 + 2) * BFN;
#pragma unroll
            for (int mt = 0; mt < 2; ++mt)
#pragma unroll
                for (int nt = 0; nt < 4; ++nt)
#pragma unroll
                    for (int r = 0; r < 4; ++r) {
                        int row = m0 + wv * 32 + mt * 16 + g * 4 + r;
                        int col = col0 + nt * 16 + q15;
                        float mu = acc1[mt][nt][r];
                        float sg = sp_f(acc2[mt][nt][r] + rr[mt][r] * spws[col]);
                        int bb = row >> 10, s = row & 1023, d = nt * 16 + q15;
                        size_t rb = ((size_t)(bb * 12 + h) << 16) + ((size_t)s << 6) + d;
                        b0[rb] = f2bf(mu);
                        b1[rb] = f2bf(sg);
                        b2[rb] = f2bf(proj == 0 ? (mu * mu + sg) * QSC : mu * mu * QSC);
                    }
        } else {
            // V: transposed store [bh][d][s]; vsg pre-scaled by 2^-10
            float sgv[2][4][4];
#pragma unroll
            for (int mt = 0; mt < 2; ++mt)
#pragma unroll
                for (int nt = 0; nt < 4; ++nt)
#pragma unroll
                    for (int r = 0; r < 4; ++r) {
                        int col = col0 + nt * 16 + q15;
                        sgv[mt][nt][r] = sp_f(acc2[mt][nt][r] + rr[mt][r] * spws[col]);
                    }
            const int bb = m0 >> 10, s0 = m0 & 1023;
#pragma unroll
            for (int a = 0; a < 3; ++a) {
                __syncthreads();
#pragma unroll
                for (int mt = 0; mt < 2; ++mt)
#pragma unroll
                    for (int nt = 0; nt < 4; ++nt)
#pragma unroll
                        for (int r = 0; r < 4; ++r) {
                            float mu = acc1[mt][nt][r], sg = sgv[mt][nt][r];
                            float v = (a == 0) ? mu : (a == 1) ? sg * 0.0009765625f : mu * mu + sg;
                            L[(nt * 16 + q15) * 136 + wv * 32 + mt * 16 + g * 4 + r] = f2bf(v);
                        }
                __syncthreads();
                const int d = tid >> 2, sc = (tid & 3) * 32;
                u16* dst = QKVB + (size_t)(6 + a) * BFN;
                size_t ga = ((size_t)((bb * 12 + h) * 64 + d) << 10) + s0 + sc;
                *(uint4*)(dst + ga)      = *(const uint4*)&L[d * 136 + sc];
                *(uint4*)(dst + ga + 8)  = *(const uint4*)&L[d * 136 + sc + 8];
                *(uint4*)(dst + ga + 16) = *(const uint4*)&L[d * 136 + sc + 16];
                *(uint4*)(dst + ga + 24) = *(const uint4*)&L[d * 136 + sc + 24];
            }
        }
    }
}

// ------------------------------------------------------------- attention ---
// 256 threads = 4 fully independent waves (no barriers). Each wave: 16 q-rows,
// full K=1024. Swapped scores C[k,q]; exp2-domain defer-max softmax; P/P2/SW
// packed via v_cvt_pk_bf16_f32 into per-wave swizzled LDS; PV B-frags from
// transposed V arrays. Constants pre-folded (2^-26 in Q1/Q2, 2^-10 in Vsg).
__global__ __launch_bounds__(256, 3) void vdp_attn4(
    const u16* __restrict__ Kmu, const u16* __restrict__ Ksg, const u16* __restrict__ Asq,
    const u16* __restrict__ Qmu, const u16* __restrict__ Q1v, const u16* __restrict__ Q2v,
    const u16* __restrict__ Vmu, const u16* __restrict__ Vsg, const u16* __restrict__ Vw2,
    u16* __restrict__ om, u16* __restrict__ osg)
{
    __shared__ __align__(16) u16 Pl[4][3][16][64];

    const int wgid = blockIdx.x;                  // 768 = 48bh x 16qt
    const int seq = (wgid & 7) * 96 + (wgid >> 3);
    const int bh = seq >> 4, qt = seq & 15;
    const int tid = threadIdx.x, wv = tid >> 6, lane = tid & 63;
    const int g = lane >> 4, q15 = lane & 15;
    const size_t hb = (size_t)bh << 16;

    const size_t qoff = hb + (size_t)((qt * 64 + wv * 16 + q15) << 6) + g * 8;
    bf16x8 bq0 = *(const bf16x8*)(Qmu + qoff), bq1 = *(const bf16x8*)(Qmu + qoff + 32);
    bf16x8 b10 = *(const bf16x8*)(Q1v + qoff), b11 = *(const bf16x8*)(Q1v + qoff + 32);
    bf16x8 b20 = *(const bf16x8*)(Q2v + qoff), b21 = *(const bf16x8*)(Q2v + qoff + 32);

    // ---- pass 1: defer-max online stats in exp2 domain (in-lane only)
    float m2 = -3.0e38f;
    float lacc[4] = {0.f, 0.f, 0.f, 0.f};
    for (int t = 0; t < 16; ++t) {
        f32x4 sc[4];
#pragma unroll
        for (int kt = 0; kt < 4; ++kt) sc[kt] = (f32x4){0.f, 0.f, 0.f, 0.f};
        __builtin_amdgcn_s_setprio(1);
#pragma unroll
        for (int kt = 0; kt < 4; ++kt) {
            size_t ar = hb + (size_t)(((t << 6) + (kt << 4) + q15) << 6) + g * 8;
            sc[kt] = __builtin_amdgcn_mfma_f32_16x16x32_bf16(*(const bf16x8*)(Kmu + ar),      bq0, sc[kt], 0, 0, 0);
            sc[kt] = __builtin_amdgcn_mfma_f32_16x16x32_bf16(*(const bf16x8*)(Kmu + ar + 32), bq1, sc[kt], 0, 0, 0);
        }
        __builtin_amdgcn_s_setprio(0);
        float t0 = fmaxf(fmaxf(sc[0][0], sc[0][1]), fmaxf(sc[0][2], sc[0][3]));
        float t1 = fmaxf(fmaxf(sc[1][0], sc[1][1]), fmaxf(sc[1][2], sc[1][3]));
        float t2 = fmaxf(fmaxf(sc[2][0], sc[2][1]), fmaxf(sc[2][2], sc[2][3]));
        float t3 = fmaxf(fmaxf(sc[3][0], sc[3][1]), fmaxf(sc[3][2], sc[3][3]));
        float tm = fmaxf(fmaxf(t0, t1), fmaxf(t2, t3)) * C2E;
        if (tm > m2 + 8.f) {
            float f = ex2(m2 - tm);
            lacc[0] *= f; lacc[1] *= f; lacc[2] *= f; lacc[3] *= f;
            m2 = tm;
        }
#pragma unroll
        for (int kt = 0; kt < 4; ++kt)
#pragma unroll
            for (int r = 0; r < 4; ++r)
                lacc[kt] += ex2(fmaf(sc[kt][r], C2E, -m2));
    }
    float l = (lacc[0] + lacc[1]) + (lacc[2] + lacc[3]);
#pragma unroll
    for (int off = 16; off <= 32; off <<= 1) {
        float mo = __shfl_xor(m2, off), lo = __shfl_xor(l, off);
        float nm = fmaxf(m2, mo);
        l = l * ex2(m2 - nm) + lo * ex2(mo - nm);
        m2 = nm;
    }
    const float M = m2 + lg2(l);

    // ---- pass 2
    f32x4 accm[4], accd[4], acce[4];
#pragma unroll
    for (int nt = 0; nt < 4; ++nt) {
        accm[nt] = (f32x4){0.f, 0.f, 0.f, 0.f};
        accd[nt] = (f32x4){0.f, 0.f, 0.f, 0.f};
        acce[nt] = (f32x4){0.f, 0.f, 0.f, 0.f};
    }

    for (int t = 0; t < 16; ++t) {
        f32x4 sc[4], sgc[4];
#pragma unroll
        for (int kt = 0; kt < 4; ++kt) { sc[kt] = (f32x4){0.f,0.f,0.f,0.f}; sgc[kt] = (f32x4){0.f,0.f,0.f,0.f}; }
        __builtin_amdgcn_s_setprio(1);
#pragma unroll
        for (int kt = 0; kt < 4; ++kt) {
            size_t ar = hb + (size_t)(((t << 6) + (kt << 4) + q15) << 6) + g * 8;
            sc[kt]  = __builtin_amdgcn_mfma_f32_16x16x32_bf16(*(const bf16x8*)(Kmu + ar),      bq0, sc[kt],  0, 0, 0);
            sc[kt]  = __builtin_amdgcn_mfma_f32_16x16x32_bf16(*(const bf16x8*)(Kmu + ar + 32), bq1, sc[kt],  0, 0, 0);
            sgc[kt] = __builtin_amdgcn_mfma_f32_16x16x32_bf16(*(const bf16x8*)(Ksg + ar),      b10, sgc[kt], 0, 0, 0);
            sgc[kt] = __builtin_amdgcn_mfma_f32_16x16x32_bf16(*(const bf16x8*)(Ksg + ar + 32), b11, sgc[kt], 0, 0, 0);
            sgc[kt] = __builtin_amdgcn_mfma_f32_16x16x32_bf16(*(const bf16x8*)(Asq + ar),      b20, sgc[kt], 0, 0, 0);
            sgc[kt] = __builtin_amdgcn_mfma_f32_16x16x32_bf16(*(const bf16x8*)(Asq + ar + 32), b21, sgc[kt], 0, 0, 0);
        }
        __builtin_amdgcn_s_setprio(0);
#pragma unroll
        for (int kt = 0; kt < 4; ++kt) {
            float p[4], p2[4], sw[4];
#pragma unroll
            for (int r = 0; r < 4; ++r) {
                p[r] = ex2(fmaf(sc[kt][r], C2E, -M));
                p2[r] = p[r] * p[r];
                float gq = p[r] - p2[r];
                sw[r] = gq * gq * sgc[kt][r];
            }
            int kb = (kt << 4) + (g << 2);
#pragma unroll
            for (int rp = 0; rp < 4; rp += 2) {
                int k = kb + rp;
                int widx = (((k >> 3) ^ (q15 & 7)) << 3) | (k & 7);
                *(u32*)&Pl[wv][0][q15][widx] = cvtpk(p[rp],  p[rp + 1]);
                *(u32*)&Pl[wv][1][q15][widx] = cvtpk(p2[rp], p2[rp + 1]);
                *(u32*)&Pl[wv][2][q15][widx] = cvtpk(sw[rp], sw[rp + 1]);
            }
        }
        __builtin_amdgcn_s_setprio(1);
#pragma unroll
        for (int ks = 0; ks < 2; ++ks) {
            int cc = (((ks << 2) | g) ^ (q15 & 7)) << 3;
            bf16x8 pa  = *(const bf16x8*)&Pl[wv][0][q15][cc];
            bf16x8 p2a = *(const bf16x8*)&Pl[wv][1][q15][cc];
            bf16x8 swa = *(const bf16x8*)&Pl[wv][2][q15][cc];
#pragma unroll
            for (int nt = 0; nt < 4; ++nt) {
                size_t vr = hb + (size_t)(((nt << 4) + q15) << 10) + (t << 6) + (ks << 5) + g * 8;
                accm[nt] = __builtin_amdgcn_mfma_f32_16x16x32_bf16(pa,  *(const bf16x8*)(Vmu + vr), accm[nt], 0, 0, 0);
                accd[nt] = __builtin_amdgcn_mfma_f32_16x16x32_bf16(p2a, *(const bf16x8*)(Vsg + vr), accd[nt], 0, 0, 0);
                acce[nt] = __builtin_amdgcn_mfma_f32_16x16x32_bf16(swa, *(const bf16x8*)(Vw2 + vr), acce[nt], 0, 0, 0);
            }
        }
        __builtin_amdgcn_s_setprio(0);
    }

    const int b_ = bh / 12, h_ = bh % 12;
#pragma unroll
    for (int nt = 0; nt < 4; ++nt)
#pragma unroll
        for (int r = 0; r < 4; ++r) {
            int srow = qt * 64 + wv * 16 + g * 4 + r;
            int d = nt * 16 + q15;
            size_t o = (size_t)(b_ * 1024 + srow) * E + h_ * 64 + d;
            om[o]  = f2bf(accm[nt][r]);
            osg[o] = f2bf(sp_f(accd[nt][r] + acce[nt][r]));
        }
}

// ------------------------------------------------------------------- kl ----
__global__ void kl_kernel(const float* __restrict__ w0, const float* __restrict__ w1,
                          const float* __restrict__ w2, const float* __restrict__ w3,
                          const float* __restrict__ s0, const float* __restrict__ s1,
                          const float* __restrict__ s2, const float* __restrict__ s3,
                          float* __restrict__ kl_out)
{
    const int gid = blockIdx.x * 256 + threadIdx.x;
    const int gsz = gridDim.x * 256;
    float acc = 0.f;
    const float cw = 100.f / ((float)E * (float)E);
#pragma unroll
    for (int mm = 0; mm < 4; ++mm) {
        const float* w = (mm == 0) ? w0 : (mm == 1) ? w1 : (mm == 2) ? w2 : w3;
        const float* sv = (mm == 0) ? s0 : (mm == 1) ? s1 : (mm == 2) ? s2 : s3;
        for (int i = gid; i < E * E; i += gsz) { float x = w[i]; acc += x * x * cw; }
        for (int i = gid; i < E; i += gsz) { float x = sv[i]; acc += (-x + sp_f(x) * 100.f) * (1.f / (float)E); }
    }
    for (int off = 32; off; off >>= 1) acc += __shfl_xor(acc, off);
    __shared__ float r[4];
    int tid = threadIdx.x, w_ = tid >> 6;
    if ((tid & 63) == 0) r[w_] = acc;
    __syncthreads();
    if (tid == 0) atomicAdd(kl_out, 0.5f * (r[0] + r[1] + r[2] + r[3]));
}

// --------------------------------------------------------------- launch ----
extern "C" void kernel_launch(void* const* d_in, const int* in_sizes, int n_in,
                              void* d_out, int out_size, void* d_ws, size_t ws_size,
                              hipStream_t stream)
{
    const float* mu_in = (const float*)d_in[0];
    const float* sg_in = (const float*)d_in[1];
    const float* wq  = (const float*)d_in[2];
    const float* wqs = (const float*)d_in[3];
    const float* wk  = (const float*)d_in[4];
    const float* wks = (const float*)d_in[5];
    const float* wvp = (const float*)d_in[6];
    const float* wvs = (const float*)d_in[7];
    const float* wo  = (const float*)d_in[8];
    const float* wos = (const float*)d_in[9];

    float* out_mu = (float*)d_out;
    float* out_sg = out_mu + (size_t)NTOK * E;
    float* kl_out = out_mu + 2 * (size_t)NTOK * E;

    float* ws = (float*)d_ws;
    size_t off = 0;
    auto allocf = [&](size_t n) { float* p = ws + off; off += n; return p; };
    float* rmu2  = allocf(NTOK);
    float* rsgs  = allocf(NTOK);
    float* armu2 = allocf(NTOK);
    float* arsg  = allocf(NTOK);
    float* spws  = allocf(4 * E);   // 19456 floats -> 16B-aligned tail

    u16* ub = (u16*)(ws + off);
    size_t uoff = 0;
    auto allocu = [&](size_t n) { u16* p = ub + uoff; uoff += n; return p; };
    u16* Xmu    = allocu(BFN);
    u16* Xsg    = allocu(BFN);
    u16* WtQKV  = allocu(3 * WFN);
    u16* W2tQKV = allocu(3 * WFN);
    u16* Wt3    = allocu(WFN);
    u16* W2t3   = allocu(WFN);
    u16* QKVB   = allocu(9 * BFN);   // qmu,qsg,q1, kmu,ksg,q2, vmu_t,vsg_t,vw2_t
    u16* amu_b  = allocu(BFN);
    u16* asg_b  = allocu(BFN);
    (void)ws_size; (void)in_sizes; (void)n_in; (void)out_size;

    prep_kernel<<<13, 256, 0, stream>>>(wqs, wks, wvs, wos, spws, kl_out);
    convstats_kernel<<<NTOK, 128, 0, stream>>>(mu_in, sg_in, Xmu, Xsg, rmu2, rsgs);
    dim3 tgrid(24, 24);
    transpose_w_kernel<<<tgrid, 256, 0, stream>>>(wq,  WtQKV,           W2tQKV);
    transpose_w_kernel<<<tgrid, 256, 0, stream>>>(wk,  WtQKV + WFN,     W2tQKV + WFN);
    transpose_w_kernel<<<tgrid, 256, 0, stream>>>(wvp, WtQKV + 2 * WFN, W2tQKV + 2 * WFN);
    transpose_w_kernel<<<tgrid, 256, 0, stream>>>(wo,  Wt3,             W2t3);

    linear_fused<1><<<1152, 256, 0, stream>>>(Xmu, Xsg, WtQKV, W2tQKV, spws, rmu2, rsgs,
                                              nullptr, nullptr, QKVB);

    vdp_attn4<<<768, 256, 0, stream>>>(QKVB + 3 * BFN, QKVB + 4 * BFN, QKVB + 1 * BFN,
                                       QKVB + 0 * BFN, QKVB + 2 * BFN, QKVB + 5 * BFN,
                                       QKVB + 6 * BFN, QKVB + 7 * BFN, QKVB + 8 * BFN,
                                       amu_b, asg_b);

    rowstats_bf16_kernel<<<NTOK, 128, 0, stream>>>(amu_b, asg_b, armu2, arsg);
    linear_fused<0><<<384, 256, 0, stream>>>(amu_b, asg_b, Wt3, W2t3, spws + 3 * E, armu2, arsg,
                                             out_mu, out_sg, nullptr);

    kl_kernel<<<512, 256, 0, stream>>>(wq, wk, wvp, wo, wqs, wks, wvs, wos, kl_out);
}

// Round 5
// 240.008 us; speedup vs baseline: 15.5086x; 1.8925x over previous
//
#include <hip/hip_runtime.h>
#include <math.h>

#define E 768
#define NTOK 4096  /* BATCH*S */

typedef __attribute__((ext_vector_type(8))) __bf16 bf16x8;
typedef __attribute__((ext_vector_type(4))) float f32x4;
typedef unsigned int u32;
typedef unsigned short u16;

#define BFN ((size_t)NTOK * E)
#define WFN ((size_t)E * E)
#define QSC 1.4901161193847656e-08f   /* 2^-26 */
#define C2E 0.18033688011112042f      /* 0.125 * log2(e) */

__device__ __forceinline__ float sp_f(float x) {
    return fmaxf(x, 0.f) + log1pf(__expf(-fabsf(x)));
}
__device__ __forceinline__ u16 f2bf(float f) {
    u32 u = __float_as_uint(f);
    u += 0x7fffu + ((u >> 16) & 1u);
    return (u16)(u >> 16);
}
__device__ __forceinline__ u32 pk2(float a, float b) {
    return (u32)f2bf(a) | ((u32)f2bf(b) << 16);
}
__device__ __forceinline__ u32 cvtpk(float a, float b) {
    u32 r; asm("v_cvt_pk_bf16_f32 %0, %1, %2" : "=v"(r) : "v"(a), "v"(b)); return r;
}
__device__ __forceinline__ float ex2(float x) {
    float r; asm("v_exp_f32 %0, %1" : "=v"(r) : "v"(x)); return r;
}
__device__ __forceinline__ float lg2(float x) {
    float r; asm("v_log_f32 %0, %1" : "=v"(r) : "v"(x)); return r;
}
__device__ __forceinline__ float bfl(u32 u) { return __uint_as_float(u << 16); }
__device__ __forceinline__ float bfh(u32 u) { return __uint_as_float(u & 0xffff0000u); }

#define GLL16(gp, lp) __builtin_amdgcn_global_load_lds( \
    (const __attribute__((address_space(1))) u32*)(gp), \
    (__attribute__((address_space(3))) u32*)(lp), 16, 0, 0)

// ---------------------------------------------------------------- prep ----
__global__ void prep_kernel(const float* __restrict__ wqs, const float* __restrict__ wks,
                            const float* __restrict__ wvs, const float* __restrict__ wos,
                            float* __restrict__ spws, float* __restrict__ kl_out)
{
    int i = blockIdx.x * 256 + threadIdx.x;
    if (i < 4 * E) {
        const float* src;
        int j;
        if (i < E)            { src = wqs; j = i; }
        else if (i < 2 * E)   { src = wks; j = i - E; }
        else if (i < 3 * E)   { src = wvs; j = i - 2 * E; }
        else                  { src = wos; j = i - 3 * E; }
        spws[i] = sp_f(src[j]);
    }
    if (i == 4 * E) *kl_out = 2.f * (logf(0.01f) - 1.f);
}

// ---------------------------------------- fused fp32->bf16 + row stats ----
__global__ __launch_bounds__(128) void convstats_kernel(
    const float* __restrict__ mu, const float* __restrict__ sg,
    u16* __restrict__ Xmu, u16* __restrict__ Xsg,
    float* __restrict__ rmu2, float* __restrict__ rsg)
{
    const int n = blockIdx.x, tid = threadIdx.x;
    float s1 = 0.f, s2 = 0.f;
    if (tid < 96) {
        size_t o = (size_t)n * E + tid * 8;
        float4 a0 = *(const float4*)(mu + o), a1 = *(const float4*)(mu + o + 4);
        float4 b0 = *(const float4*)(sg + o), b1 = *(const float4*)(sg + o + 4);
        *(uint4*)(Xmu + o) = make_uint4(pk2(a0.x, a0.y), pk2(a0.z, a0.w), pk2(a1.x, a1.y), pk2(a1.z, a1.w));
        *(uint4*)(Xsg + o) = make_uint4(pk2(b0.x, b0.y), pk2(b0.z, b0.w), pk2(b1.x, b1.y), pk2(b1.z, b1.w));
        s1 = a0.x*a0.x + a0.y*a0.y + a0.z*a0.z + a0.w*a0.w + a1.x*a1.x + a1.y*a1.y + a1.z*a1.z + a1.w*a1.w;
        s2 = b0.x + b0.y + b0.z + b0.w + b1.x + b1.y + b1.z + b1.w;
    }
    for (int off = 32; off; off >>= 1) {
        s1 += __shfl_xor(s1, off);
        s2 += __shfl_xor(s2, off);
    }
    __shared__ float r1[2], r2[2];
    if ((tid & 63) == 0) { r1[tid >> 6] = s1; r2[tid >> 6] = s2; }
    __syncthreads();
    if (tid == 0) { rmu2[n] = r1[0] + r1[1]; rsg[n] = r2[0] + r2[1]; }
}

__global__ __launch_bounds__(128) void rowstats_bf16_kernel(
    const u16* __restrict__ mu, const u16* __restrict__ sg,
    float* __restrict__ rmu2, float* __restrict__ rsg)
{
    const int n = blockIdx.x, tid = threadIdx.x;
    float s1 = 0.f, s2 = 0.f;
    if (tid < 96) {
        uint4 um = *(const uint4*)(mu + (size_t)n * E + tid * 8);
        uint4 us = *(const uint4*)(sg + (size_t)n * E + tid * 8);
        u32 ua[4] = {um.x, um.y, um.z, um.w};
        u32 ub[4] = {us.x, us.y, us.z, us.w};
#pragma unroll
        for (int j = 0; j < 4; ++j) {
            float a0 = bfl(ua[j]), a1 = bfh(ua[j]);
            s1 += a0 * a0 + a1 * a1;
            s2 += bfl(ub[j]) + bfh(ub[j]);
        }
    }
    for (int off = 32; off; off >>= 1) {
        s1 += __shfl_xor(s1, off);
        s2 += __shfl_xor(s2, off);
    }
    __shared__ float r1[2], r2[2];
    if ((tid & 63) == 0) { r1[tid >> 6] = s1; r2[tid >> 6] = s2; }
    __syncthreads();
    if (tid == 0) { rmu2[n] = r1[0] + r1[1]; rsg[n] = r2[0] + r2[1]; }
}

// -------------------------------------------- weight transpose + square ----
__global__ void transpose_w_kernel(const float* __restrict__ W,
                                   u16* __restrict__ Wt, u16* __restrict__ W2t)
{
    __shared__ float T[32][33];
    const int j0 = blockIdx.x * 32, k0 = blockIdx.y * 32;
    const int tid = threadIdx.x;
    const int r = tid >> 3, c = (tid & 7) * 4;
    float4 v = *(const float4*)(W + (size_t)(k0 + r) * E + j0 + c);
    T[r][c] = v.x; T[r][c + 1] = v.y; T[r][c + 2] = v.z; T[r][c + 3] = v.w;
    __syncthreads();
    const int j = tid >> 3, kc = (tid & 7) * 4;
    float w0 = T[kc][j], w1 = T[kc + 1][j], w2 = T[kc + 2][j], w3 = T[kc + 3][j];
    size_t o = (size_t)(j0 + j) * E + k0 + kc;
    *(uint2*)(Wt + o) = make_uint2(pk2(w0, w1), pk2(w2, w3));
    const float s = 1.f / 768.f;
    *(uint2*)(W2t + o) = make_uint2(pk2(w0 * w0 * s, w1 * w1 * s), pk2(w2 * w2 * s, w3 * w3 * s));
}

// --------------------------------------- linear (LDS-staged bf16 MFMA) ----
template<int MODE>
__global__ __launch_bounds__(256, 3) void linear_fused(
    const u16* __restrict__ Am, const u16* __restrict__ As,
    const u16* __restrict__ Wt, const u16* __restrict__ W2t,
    const float* __restrict__ spws, const float* __restrict__ rmu2, const float* __restrict__ rsg,
    float* __restrict__ mu_out, float* __restrict__ sg_out, u16* __restrict__ QKVB)
{
    __shared__ __align__(16) u16 L[24576];   // 48KB: Amu(16K) Asg(16K) Wt(8K) W2t(8K)

    const int wgid = blockIdx.x;
    const int NW = (MODE == 1) ? 144 : 48;
    const int NB = (MODE == 1) ? 36 : 12;
    const int swz = (wgid & 7) * NW + (wgid >> 3);
    const int m_blk = swz / NB, n_blk = swz % NB;
    const int m0 = m_blk * 128, col0 = n_blk * 64;
    const int tid = threadIdx.x, wv = tid >> 6, lane = tid & 63;
    const int g = lane >> 4, q15 = lane & 15;

    const u16* sp_[12];
#pragma unroll
    for (int j = 0; j < 12; ++j) {
        int ch = j * 256 + tid;
        int arr = (ch < 1024) ? 0 : (ch < 2048) ? 1 : (ch < 2560) ? 2 : 3;
        int local = ch - ((arr == 0) ? 0 : (arr == 1) ? 1024 : (arr == 2) ? 2048 : 2560);
        int r = local >> 3, c = local & 7;
        int cs = (c ^ (r & 7)) * 8;
        const u16* base = (arr == 0) ? (Am + (size_t)(m0 + r) * E) :
                          (arr == 1) ? (As + (size_t)(m0 + r) * E) :
                          (arr == 2) ? (Wt + (size_t)(col0 + r) * E) :
                                       (W2t + (size_t)(col0 + r) * E);
        sp_[j] = base + cs;
    }

    f32x4 acc1[2][4], acc2[2][4];
#pragma unroll
    for (int mt = 0; mt < 2; ++mt)
#pragma unroll
        for (int nt = 0; nt < 4; ++nt) {
            acc1[mt][nt] = (f32x4){0.f, 0.f, 0.f, 0.f};
            acc2[mt][nt] = (f32x4){0.f, 0.f, 0.f, 0.f};
        }

    for (int t = 0; t < 12; ++t) {
#pragma unroll
        for (int j = 0; j < 12; ++j)
            GLL16(sp_[j] + t * 64, (u16*)((char*)L + j * 4096 + wv * 1024));
        __syncthreads();
#pragma unroll
        for (int kk = 0; kk < 2; ++kk) {
            bf16x8 am[2], asg[2];
#pragma unroll
            for (int mt = 0; mt < 2; ++mt) {
                int r = wv * 32 + mt * 16 + q15;
                int c = ((kk * 4 + g) ^ (r & 7)) * 8;
                am[mt]  = *(const bf16x8*)&L[(r << 6) + c];
                asg[mt] = *(const bf16x8*)&L[8192 + (r << 6) + c];
            }
#pragma unroll
            for (int nt = 0; nt < 4; ++nt) {
                int rb = nt * 16 + q15;
                int cb = ((kk * 4 + g) ^ (rb & 7)) * 8;
                bf16x8 bw = *(const bf16x8*)&L[16384 + (rb << 6) + cb];
                bf16x8 b2 = *(const bf16x8*)&L[20480 + (rb << 6) + cb];
                acc1[0][nt] = __builtin_amdgcn_mfma_f32_16x16x32_bf16(am[0], bw, acc1[0][nt], 0, 0, 0);
                acc1[1][nt] = __builtin_amdgcn_mfma_f32_16x16x32_bf16(am[1], bw, acc1[1][nt], 0, 0, 0);
                acc2[0][nt] = __builtin_amdgcn_mfma_f32_16x16x32_bf16(asg[0], b2, acc2[0][nt], 0, 0, 0);
                acc2[1][nt] = __builtin_amdgcn_mfma_f32_16x16x32_bf16(asg[1], b2, acc2[1][nt], 0, 0, 0);
            }
        }
        __syncthreads();
    }

    const float inv2 = 1.f / (768.f * 768.f), invd = 1.f / 768.f;
    float rr[2][4];
#pragma unroll
    for (int mt = 0; mt < 2; ++mt)
#pragma unroll
        for (int r = 0; r < 4; ++r) {
            int row = m0 + wv * 32 + mt * 16 + g * 4 + r;
            rr[mt][r] = rmu2[row] * inv2 + rsg[row] * invd;
        }

    if (MODE == 0) {
#pragma unroll
        for (int mt = 0; mt < 2; ++mt)
#pragma unroll
            for (int nt = 0; nt < 4; ++nt)
#pragma unroll
                for (int r = 0; r < 4; ++r) {
                    int row = m0 + wv * 32 + mt * 16 + g * 4 + r;
                    int col = col0 + nt * 16 + q15;
                    float mu = acc1[mt][nt][r];
                    float sg = sp_f(sp_f(acc2[mt][nt][r] + rr[mt][r] * spws[col]));
                    mu_out[(size_t)row * E + col] = mu;
                    sg_out[(size_t)row * E + col] = sg;
                }
    } else {
        const int proj = n_blk / 12, h = n_blk % 12;
        if (proj < 2) {
            u16* b0 = QKVB + (size_t)(proj * 3 + 0) * BFN;
            u16* b1 = QKVB + (size_t)(proj * 3 + 1) * BFN;
            u16* b2 = QKVB + (size_t)(proj * 3 + 2) * BFN;
#pragma unroll
            for (int mt = 0; mt < 2; ++mt)
#pragma unroll
                for (int nt = 0; nt < 4; ++nt)
#pragma unroll
                    for (int r = 0; r < 4; ++r) {
                        int row = m0 + wv * 32 + mt * 16 + g * 4 + r;
                        int col = col0 + nt * 16 + q15;
                        float mu = acc1[mt][nt][r];
                        float sg = sp_f(acc2[mt][nt][r] + rr[mt][r] * spws[col]);
                        int bb = row >> 10, s = row & 1023, d = nt * 16 + q15;
                        size_t rb = ((size_t)(bb * 12 + h) << 16) + ((size_t)s << 6) + d;
                        b0[rb] = f2bf(mu);
                        b1[rb] = f2bf(sg);
                        b2[rb] = f2bf(proj == 0 ? (mu * mu + sg) * QSC : mu * mu * QSC);
                    }
        } else {
            float sgv[2][4][4];
#pragma unroll
            for (int mt = 0; mt < 2; ++mt)
#pragma unroll
                for (int nt = 0; nt < 4; ++nt)
#pragma unroll
                    for (int r = 0; r < 4; ++r) {
                        int col = col0 + nt * 16 + q15;
                        sgv[mt][nt][r] = sp_f(acc2[mt][nt][r] + rr[mt][r] * spws[col]);
                    }
            const int bb = m0 >> 10, s0 = m0 & 1023;
#pragma unroll
            for (int a = 0; a < 3; ++a) {
                __syncthreads();
#pragma unroll
                for (int mt = 0; mt < 2; ++mt)
#pragma unroll
                    for (int nt = 0; nt < 4; ++nt)
#pragma unroll
                        for (int r = 0; r < 4; ++r) {
                            float mu = acc1[mt][nt][r], sg = sgv[mt][nt][r];
                            float v = (a == 0) ? mu : (a == 1) ? sg * 0.0009765625f : mu * mu + sg;
                            L[(nt * 16 + q15) * 136 + wv * 32 + mt * 16 + g * 4 + r] = f2bf(v);
                        }
                __syncthreads();
                const int d = tid >> 2, sc = (tid & 3) * 32;
                u16* dst = QKVB + (size_t)(6 + a) * BFN;
                size_t ga = ((size_t)((bb * 12 + h) * 64 + d) << 10) + s0 + sc;
                *(uint4*)(dst + ga)      = *(const uint4*)&L[d * 136 + sc];
                *(uint4*)(dst + ga + 8)  = *(const uint4*)&L[d * 136 + sc + 8];
                *(uint4*)(dst + ga + 16) = *(const uint4*)&L[d * 136 + sc + 16];
                *(uint4*)(dst + ga + 24) = *(const uint4*)&L[d * 136 + sc + 24];
            }
        }
    }
}

// ------------------------------------------------------------- attention ---
// v5: cooperative LDS staging (global_load_lds, pre-swizzled source, linear
// dest) shared by all 4 waves; m97 2-barrier loop; 36KB LDS -> 4 blocks/CU.
// Pass 1: Kmu 64-k tiles. Pass 2: 32-k tiles, 6 arrays (24KB) per tile.
#define PLB 12288
__global__ __launch_bounds__(256, 4) void vdp_attn5(
    const u16* __restrict__ Kmu, const u16* __restrict__ Ksg, const u16* __restrict__ Asq,
    const u16* __restrict__ Qmu, const u16* __restrict__ Q1v, const u16* __restrict__ Q2v,
    const u16* __restrict__ Vmu, const u16* __restrict__ Vsg, const u16* __restrict__ Vw2,
    u16* __restrict__ om, u16* __restrict__ osg)
{
    __shared__ __align__(16) u16 L[18432];   // 24KB stage + 12KB P-tiles

    const int wgid = blockIdx.x;                  // 768 = 48bh x 16qt
    const int seq = (wgid & 7) * 96 + (wgid >> 3);
    const int bh = seq >> 4, qt = seq & 15;
    const int tid = threadIdx.x, wv = tid >> 6, lane = tid & 63;
    const int g = lane >> 4, q15 = lane & 15;
    const size_t hb = (size_t)bh << 16;

    const size_t qoff = hb + (size_t)((qt * 64 + wv * 16 + q15) << 6) + g * 8;
    bf16x8 bq0 = *(const bf16x8*)(Qmu + qoff), bq1 = *(const bf16x8*)(Qmu + qoff + 32);
    bf16x8 b10 = *(const bf16x8*)(Q1v + qoff), b11 = *(const bf16x8*)(Q1v + qoff + 32);
    bf16x8 b20 = *(const bf16x8*)(Q2v + qoff), b21 = *(const bf16x8*)(Q2v + qoff + 32);

    // staging source offsets (chunk = tid; source col-chunk pre-swizzled)
    const int sr = tid >> 3, sc8 = tid & 7;
    const size_t koffA = hb + (size_t)sr * 64 + ((sc8 ^ (sr & 7)) << 3);          // rows 0..31
    const size_t koffB = hb + (size_t)(sr + 32) * 64 + ((sc8 ^ ((sr + 32) & 7)) << 3); // rows 32..63
    const int vr = tid >> 2, vc = tid & 3;
    const size_t voff = hb + (size_t)vr * 1024 + ((vc ^ (vr & 3)) << 3);

    // ---- pass 1: softmax stats (Kmu staged, 64-k tiles)
    float m2 = -3.0e38f;
    float lacc[4] = {0.f, 0.f, 0.f, 0.f};
    for (int t = 0; t < 16; ++t) {
        GLL16(Kmu + koffA + ((size_t)t << 12), &L[wv * 512]);
        GLL16(Kmu + koffB + ((size_t)t << 12), &L[2048 + wv * 512]);
        __syncthreads();
        f32x4 sc[4];
#pragma unroll
        for (int kt = 0; kt < 4; ++kt) sc[kt] = (f32x4){0.f, 0.f, 0.f, 0.f};
        __builtin_amdgcn_s_setprio(1);
#pragma unroll
        for (int kt = 0; kt < 4; ++kt) {
            int row = kt * 16 + q15, ra = row << 6;
            bf16x8 k0 = *(const bf16x8*)&L[ra + ((g ^ (row & 7)) << 3)];
            bf16x8 k1 = *(const bf16x8*)&L[ra + (((g + 4) ^ (row & 7)) << 3)];
            sc[kt] = __builtin_amdgcn_mfma_f32_16x16x32_bf16(k0, bq0, sc[kt], 0, 0, 0);
            sc[kt] = __builtin_amdgcn_mfma_f32_16x16x32_bf16(k1, bq1, sc[kt], 0, 0, 0);
        }
        __builtin_amdgcn_s_setprio(0);
        float t0 = fmaxf(fmaxf(sc[0][0], sc[0][1]), fmaxf(sc[0][2], sc[0][3]));
        float t1 = fmaxf(fmaxf(sc[1][0], sc[1][1]), fmaxf(sc[1][2], sc[1][3]));
        float t2 = fmaxf(fmaxf(sc[2][0], sc[2][1]), fmaxf(sc[2][2], sc[2][3]));
        float t3 = fmaxf(fmaxf(sc[3][0], sc[3][1]), fmaxf(sc[3][2], sc[3][3]));
        float tm = fmaxf(fmaxf(t0, t1), fmaxf(t2, t3)) * C2E;
        if (tm > m2 + 8.f) {
            float f = ex2(m2 - tm);
            lacc[0] *= f; lacc[1] *= f; lacc[2] *= f; lacc[3] *= f;
            m2 = tm;
        }
#pragma unroll
        for (int kt = 0; kt < 4; ++kt)
#pragma unroll
            for (int r = 0; r < 4; ++r)
                lacc[kt] += ex2(fmaf(sc[kt][r], C2E, -m2));
        __syncthreads();
    }
    float l = (lacc[0] + lacc[1]) + (lacc[2] + lacc[3]);
#pragma unroll
    for (int off = 16; off <= 32; off <<= 1) {
        float mo = __shfl_xor(m2, off), lo = __shfl_xor(l, off);
        float nm = fmaxf(m2, mo);
        l = l * ex2(m2 - nm) + lo * ex2(mo - nm);
        m2 = nm;
    }
    const float M = m2 + lg2(l);

    // ---- pass 2: 32-k tiles, 6 staged arrays
    f32x4 accm[4], accd[4], acce[4];
#pragma unroll
    for (int nt = 0; nt < 4; ++nt) {
        accm[nt] = (f32x4){0.f, 0.f, 0.f, 0.f};
        accd[nt] = (f32x4){0.f, 0.f, 0.f, 0.f};
        acce[nt] = (f32x4){0.f, 0.f, 0.f, 0.f};
    }
    const int plw = PLB + wv * 1536;

    for (int t = 0; t < 32; ++t) {
        const size_t ka = (size_t)t << 11;   // t*32 rows * 64
        const size_t va = (size_t)t << 5;    // t*32 along s
        GLL16(Kmu + koffA + ka, &L[0     + wv * 512]);
        GLL16(Ksg + koffA + ka, &L[2048  + wv * 512]);
        GLL16(Asq + koffA + ka, &L[4096  + wv * 512]);
        GLL16(Vmu + voff + va,  &L[6144  + wv * 512]);
        GLL16(Vsg + voff + va,  &L[8192  + wv * 512]);
        GLL16(Vw2 + voff + va,  &L[10240 + wv * 512]);
        __syncthreads();

        f32x4 sc[2], sgc[2];
#pragma unroll
        for (int kt = 0; kt < 2; ++kt) { sc[kt] = (f32x4){0.f,0.f,0.f,0.f}; sgc[kt] = (f32x4){0.f,0.f,0.f,0.f}; }
        __builtin_amdgcn_s_setprio(1);
#pragma unroll
        for (int kt = 0; kt < 2; ++kt) {
            int row = kt * 16 + q15, ra = row << 6;
            int ca = ((g ^ (row & 7)) << 3), cb = (((g + 4) ^ (row & 7)) << 3);
            sc[kt]  = __builtin_amdgcn_mfma_f32_16x16x32_bf16(*(const bf16x8*)&L[ra + ca],        bq0, sc[kt],  0, 0, 0);
            sc[kt]  = __builtin_amdgcn_mfma_f32_16x16x32_bf16(*(const bf16x8*)&L[ra + cb],        bq1, sc[kt],  0, 0, 0);
            sgc[kt] = __builtin_amdgcn_mfma_f32_16x16x32_bf16(*(const bf16x8*)&L[2048 + ra + ca], b10, sgc[kt], 0, 0, 0);
            sgc[kt] = __builtin_amdgcn_mfma_f32_16x16x32_bf16(*(const bf16x8*)&L[2048 + ra + cb], b11, sgc[kt], 0, 0, 0);
            sgc[kt] = __builtin_amdgcn_mfma_f32_16x16x32_bf16(*(const bf16x8*)&L[4096 + ra + ca], b20, sgc[kt], 0, 0, 0);
            sgc[kt] = __builtin_amdgcn_mfma_f32_16x16x32_bf16(*(const bf16x8*)&L[4096 + ra + cb], b21, sgc[kt], 0, 0, 0);
        }
        __builtin_amdgcn_s_setprio(0);

#pragma unroll
        for (int kt = 0; kt < 2; ++kt) {
            float p[4], p2[4], sw[4];
#pragma unroll
            for (int r = 0; r < 4; ++r) {
                p[r] = ex2(fmaf(sc[kt][r], C2E, -M));
                p2[r] = p[r] * p[r];
                float gq = p[r] - p2[r];
                sw[r] = gq * gq * sgc[kt][r];
            }
            int ch = (kt << 1) + (g >> 1);
            int base = q15 * 32 + ((ch ^ (q15 & 3)) << 3) + ((g & 1) << 2);
#pragma unroll
            for (int rp = 0; rp < 4; rp += 2) {
                *(u32*)&L[plw + base + rp]        = cvtpk(p[rp],  p[rp + 1]);
                *(u32*)&L[plw + 512 + base + rp]  = cvtpk(p2[rp], p2[rp + 1]);
                *(u32*)&L[plw + 1024 + base + rp] = cvtpk(sw[rp], sw[rp + 1]);
            }
        }

        __builtin_amdgcn_s_setprio(1);
        {
            int pc = q15 * 32 + ((g ^ (q15 & 3)) << 3);
            bf16x8 pa  = *(const bf16x8*)&L[plw + pc];
            bf16x8 p2a = *(const bf16x8*)&L[plw + 512 + pc];
            bf16x8 swa = *(const bf16x8*)&L[plw + 1024 + pc];
#pragma unroll
            for (int nt = 0; nt < 4; ++nt) {
                int vi = (nt * 16 + q15) * 32 + ((g ^ (q15 & 3)) << 3);
                accm[nt] = __builtin_amdgcn_mfma_f32_16x16x32_bf16(pa,  *(const bf16x8*)&L[6144 + vi],  accm[nt], 0, 0, 0);
                accd[nt] = __builtin_amdgcn_mfma_f32_16x16x32_bf16(p2a, *(const bf16x8*)&L[8192 + vi],  accd[nt], 0, 0, 0);
                acce[nt] = __builtin_amdgcn_mfma_f32_16x16x32_bf16(swa, *(const bf16x8*)&L[10240 + vi], acce[nt], 0, 0, 0);
            }
        }
        __builtin_amdgcn_s_setprio(0);
        __syncthreads();
    }

    const int b_ = bh / 12, h_ = bh % 12;
#pragma unroll
    for (int nt = 0; nt < 4; ++nt)
#pragma unroll
        for (int r = 0; r < 4; ++r) {
            int srow = qt * 64 + wv * 16 + g * 4 + r;
            int d = nt * 16 + q15;
            size_t o = (size_t)(b_ * 1024 + srow) * E + h_ * 64 + d;
            om[o]  = f2bf(accm[nt][r]);
            osg[o] = f2bf(sp_f(accd[nt][r] + acce[nt][r]));
        }
}

// ------------------------------------------------------------------- kl ----
__global__ void kl_kernel(const float* __restrict__ w0, const float* __restrict__ w1,
                          const float* __restrict__ w2, const float* __restrict__ w3,
                          const float* __restrict__ s0, const float* __restrict__ s1,
                          const float* __restrict__ s2, const float* __restrict__ s3,
                          float* __restrict__ kl_out)
{
    const int gid = blockIdx.x * 256 + threadIdx.x;
    const int gsz = gridDim.x * 256;
    float acc = 0.f;
    const float cw = 100.f / ((float)E * (float)E);
#pragma unroll
    for (int mm = 0; mm < 4; ++mm) {
        const float* w = (mm == 0) ? w0 : (mm == 1) ? w1 : (mm == 2) ? w2 : w3;
        const float* sv = (mm == 0) ? s0 : (mm == 1) ? s1 : (mm == 2) ? s2 : s3;
        for (int i = gid; i < E * E; i += gsz) { float x = w[i]; acc += x * x * cw; }
        for (int i = gid; i < E; i += gsz) { float x = sv[i]; acc += (-x + sp_f(x) * 100.f) * (1.f / (float)E); }
    }
    for (int off = 32; off; off >>= 1) acc += __shfl_xor(acc, off);
    __shared__ float r[4];
    int tid = threadIdx.x, w_ = tid >> 6;
    if ((tid & 63) == 0) r[w_] = acc;
    __syncthreads();
    if (tid == 0) atomicAdd(kl_out, 0.5f * (r[0] + r[1] + r[2] + r[3]));
}

// --------------------------------------------------------------- launch ----
extern "C" void kernel_launch(void* const* d_in, const int* in_sizes, int n_in,
                              void* d_out, int out_size, void* d_ws, size_t ws_size,
                              hipStream_t stream)
{
    const float* mu_in = (const float*)d_in[0];
    const float* sg_in = (const float*)d_in[1];
    const float* wq  = (const float*)d_in[2];
    const float* wqs = (const float*)d_in[3];
    const float* wk  = (const float*)d_in[4];
    const float* wks = (const float*)d_in[5];
    const float* wvp = (const float*)d_in[6];
    const float* wvs = (const float*)d_in[7];
    const float* wo  = (const float*)d_in[8];
    const float* wos = (const float*)d_in[9];

    float* out_mu = (float*)d_out;
    float* out_sg = out_mu + (size_t)NTOK * E;
    float* kl_out = out_mu + 2 * (size_t)NTOK * E;

    float* ws = (float*)d_ws;
    size_t off = 0;
    auto allocf = [&](size_t n) { float* p = ws + off; off += n; return p; };
    float* rmu2  = allocf(NTOK);
    float* rsgs  = allocf(NTOK);
    float* armu2 = allocf(NTOK);
    float* arsg  = allocf(NTOK);
    float* spws  = allocf(4 * E);

    u16* ub = (u16*)(ws + off);
    size_t uoff = 0;
    auto allocu = [&](size_t n) { u16* p = ub + uoff; uoff += n; return p; };
    u16* Xmu    = allocu(BFN);
    u16* Xsg    = allocu(BFN);
    u16* WtQKV  = allocu(3 * WFN);
    u16* W2tQKV = allocu(3 * WFN);
    u16* Wt3    = allocu(WFN);
    u16* W2t3   = allocu(WFN);
    u16* QKVB   = allocu(9 * BFN);
    u16* amu_b  = allocu(BFN);
    u16* asg_b  = allocu(BFN);
    (void)ws_size; (void)in_sizes; (void)n_in; (void)out_size;

    prep_kernel<<<13, 256, 0, stream>>>(wqs, wks, wvs, wos, spws, kl_out);
    convstats_kernel<<<NTOK, 128, 0, stream>>>(mu_in, sg_in, Xmu, Xsg, rmu2, rsgs);
    dim3 tgrid(24, 24);
    transpose_w_kernel<<<tgrid, 256, 0, stream>>>(wq,  WtQKV,           W2tQKV);
    transpose_w_kernel<<<tgrid, 256, 0, stream>>>(wk,  WtQKV + WFN,     W2tQKV + WFN);
    transpose_w_kernel<<<tgrid, 256, 0, stream>>>(wvp, WtQKV + 2 * WFN, W2tQKV + 2 * WFN);
    transpose_w_kernel<<<tgrid, 256, 0, stream>>>(wo,  Wt3,             W2t3);

    linear_fused<1><<<1152, 256, 0, stream>>>(Xmu, Xsg, WtQKV, W2tQKV, spws, rmu2, rsgs,
                                              nullptr, nullptr, QKVB);

    vdp_attn5<<<768, 256, 0, stream>>>(QKVB + 3 * BFN, QKVB + 4 * BFN, QKVB + 1 * BFN,
                                       QKVB + 0 * BFN, QKVB + 2 * BFN, QKVB + 5 * BFN,
                                       QKVB + 6 * BFN, QKVB + 7 * BFN, QKVB + 8 * BFN,
                                       amu_b, asg_b);

    rowstats_bf16_kernel<<<NTOK, 128, 0, stream>>>(amu_b, asg_b, armu2, arsg);
    linear_fused<0><<<384, 256, 0, stream>>>(amu_b, asg_b, Wt3, W2t3, spws + 3 * E, armu2, arsg,
                                             out_mu, out_sg, nullptr);

    kl_kernel<<<512, 256, 0, stream>>>(wq, wk, wvp, wo, wqs, wks, wvs, wos, kl_out);
}

// Round 6
// 231.311 us; speedup vs baseline: 16.0917x; 1.0376x over previous
//
#include <hip/hip_runtime.h>
#include <math.h>

#define E 768
#define NTOK 4096  /* BATCH*S */

typedef __attribute__((ext_vector_type(8))) __bf16 bf16x8;
typedef __attribute__((ext_vector_type(4))) float f32x4;
typedef unsigned int u32;
typedef unsigned short u16;

#define BFN ((size_t)NTOK * E)
#define WFN ((size_t)E * E)
#define QSC 1.4901161193847656e-08f   /* 2^-26 */
#define C2E 0.18033688011112042f      /* 0.125 * log2(e) */

__device__ __forceinline__ float sp_f(float x) {
    return fmaxf(x, 0.f) + log1pf(__expf(-fabsf(x)));
}
__device__ __forceinline__ u16 f2bf(float f) {
    u32 u = __float_as_uint(f);
    u += 0x7fffu + ((u >> 16) & 1u);
    return (u16)(u >> 16);
}
__device__ __forceinline__ u32 pk2(float a, float b) {
    return (u32)f2bf(a) | ((u32)f2bf(b) << 16);
}
__device__ __forceinline__ u32 cvtpk(float a, float b) {
    u32 r; asm("v_cvt_pk_bf16_f32 %0, %1, %2" : "=v"(r) : "v"(a), "v"(b)); return r;
}
__device__ __forceinline__ float ex2(float x) {
    float r; asm("v_exp_f32 %0, %1" : "=v"(r) : "v"(x)); return r;
}
__device__ __forceinline__ float lg2(float x) {
    float r; asm("v_log_f32 %0, %1" : "=v"(r) : "v"(x)); return r;
}
__device__ __forceinline__ float bfl(u32 u) { return __uint_as_float(u << 16); }
__device__ __forceinline__ float bfh(u32 u) { return __uint_as_float(u & 0xffff0000u); }

#define GLL16(gp, lp) __builtin_amdgcn_global_load_lds( \
    (const __attribute__((address_space(1))) u32*)(gp), \
    (__attribute__((address_space(3))) u32*)(lp), 16, 0, 0)

// ---------------------------------------------------------------- prep ----
__global__ void prep_kernel(const float* __restrict__ wqs, const float* __restrict__ wks,
                            const float* __restrict__ wvs, const float* __restrict__ wos,
                            float* __restrict__ spws, float* __restrict__ kl_out)
{
    int i = blockIdx.x * 256 + threadIdx.x;
    if (i < 4 * E) {
        const float* src;
        int j;
        if (i < E)            { src = wqs; j = i; }
        else if (i < 2 * E)   { src = wks; j = i - E; }
        else if (i < 3 * E)   { src = wvs; j = i - 2 * E; }
        else                  { src = wos; j = i - 3 * E; }
        spws[i] = sp_f(src[j]);
    }
    if (i == 4 * E) *kl_out = 2.f * (logf(0.01f) - 1.f);
}

// ---------------------------------------- fused fp32->bf16 + row stats ----
__global__ __launch_bounds__(128) void convstats_kernel(
    const float* __restrict__ mu, const float* __restrict__ sg,
    u16* __restrict__ Xmu, u16* __restrict__ Xsg,
    float* __restrict__ rmu2, float* __restrict__ rsg)
{
    const int n = blockIdx.x, tid = threadIdx.x;
    float s1 = 0.f, s2 = 0.f;
    if (tid < 96) {
        size_t o = (size_t)n * E + tid * 8;
        float4 a0 = *(const float4*)(mu + o), a1 = *(const float4*)(mu + o + 4);
        float4 b0 = *(const float4*)(sg + o), b1 = *(const float4*)(sg + o + 4);
        *(uint4*)(Xmu + o) = make_uint4(pk2(a0.x, a0.y), pk2(a0.z, a0.w), pk2(a1.x, a1.y), pk2(a1.z, a1.w));
        *(uint4*)(Xsg + o) = make_uint4(pk2(b0.x, b0.y), pk2(b0.z, b0.w), pk2(b1.x, b1.y), pk2(b1.z, b1.w));
        s1 = a0.x*a0.x + a0.y*a0.y + a0.z*a0.z + a0.w*a0.w + a1.x*a1.x + a1.y*a1.y + a1.z*a1.z + a1.w*a1.w;
        s2 = b0.x + b0.y + b0.z + b0.w + b1.x + b1.y + b1.z + b1.w;
    }
    for (int off = 32; off; off >>= 1) {
        s1 += __shfl_xor(s1, off);
        s2 += __shfl_xor(s2, off);
    }
    __shared__ float r1[2], r2[2];
    if ((tid & 63) == 0) { r1[tid >> 6] = s1; r2[tid >> 6] = s2; }
    __syncthreads();
    if (tid == 0) { rmu2[n] = r1[0] + r1[1]; rsg[n] = r2[0] + r2[1]; }
}

__global__ __launch_bounds__(128) void rowstats_bf16_kernel(
    const u16* __restrict__ mu, const u16* __restrict__ sg,
    float* __restrict__ rmu2, float* __restrict__ rsg)
{
    const int n = blockIdx.x, tid = threadIdx.x;
    float s1 = 0.f, s2 = 0.f;
    if (tid < 96) {
        uint4 um = *(const uint4*)(mu + (size_t)n * E + tid * 8);
        uint4 us = *(const uint4*)(sg + (size_t)n * E + tid * 8);
        u32 ua[4] = {um.x, um.y, um.z, um.w};
        u32 ub[4] = {us.x, us.y, us.z, us.w};
#pragma unroll
        for (int j = 0; j < 4; ++j) {
            float a0 = bfl(ua[j]), a1 = bfh(ua[j]);
            s1 += a0 * a0 + a1 * a1;
            s2 += bfl(ub[j]) + bfh(ub[j]);
        }
    }
    for (int off = 32; off; off >>= 1) {
        s1 += __shfl_xor(s1, off);
        s2 += __shfl_xor(s2, off);
    }
    __shared__ float r1[2], r2[2];
    if ((tid & 63) == 0) { r1[tid >> 6] = s1; r2[tid >> 6] = s2; }
    __syncthreads();
    if (tid == 0) { rmu2[n] = r1[0] + r1[1]; rsg[n] = r2[0] + r2[1]; }
}

// -------------------------------------------- weight transpose + square ----
__global__ void transpose_w_kernel(const float* __restrict__ W,
                                   u16* __restrict__ Wt, u16* __restrict__ W2t)
{
    __shared__ float T[32][33];
    const int j0 = blockIdx.x * 32, k0 = blockIdx.y * 32;
    const int tid = threadIdx.x;
    const int r = tid >> 3, c = (tid & 7) * 4;
    float4 v = *(const float4*)(W + (size_t)(k0 + r) * E + j0 + c);
    T[r][c] = v.x; T[r][c + 1] = v.y; T[r][c + 2] = v.z; T[r][c + 3] = v.w;
    __syncthreads();
    const int j = tid >> 3, kc = (tid & 7) * 4;
    float w0 = T[kc][j], w1 = T[kc + 1][j], w2 = T[kc + 2][j], w3 = T[kc + 3][j];
    size_t o = (size_t)(j0 + j) * E + k0 + kc;
    *(uint2*)(Wt + o) = make_uint2(pk2(w0, w1), pk2(w2, w3));
    const float s = 1.f / 768.f;
    *(uint2*)(W2t + o) = make_uint2(pk2(w0 * w0 * s, w1 * w1 * s), pk2(w2 * w2 * s, w3 * w3 * s));
}

// --------------------------------------- linear (LDS-staged bf16 MFMA) ----
template<int MODE>
__global__ __launch_bounds__(256, 3) void linear_fused(
    const u16* __restrict__ Am, const u16* __restrict__ As,
    const u16* __restrict__ Wt, const u16* __restrict__ W2t,
    const float* __restrict__ spws, const float* __restrict__ rmu2, const float* __restrict__ rsg,
    float* __restrict__ mu_out, float* __restrict__ sg_out, u16* __restrict__ QKVB)
{
    __shared__ __align__(16) u16 L[24576];   // 48KB: Amu(16K) Asg(16K) Wt(8K) W2t(8K)

    const int wgid = blockIdx.x;
    const int NW = (MODE == 1) ? 144 : 48;
    const int NB = (MODE == 1) ? 36 : 12;
    const int swz = (wgid & 7) * NW + (wgid >> 3);
    const int m_blk = swz / NB, n_blk = swz % NB;
    const int m0 = m_blk * 128, col0 = n_blk * 64;
    const int tid = threadIdx.x, wv = tid >> 6, lane = tid & 63;
    const int g = lane >> 4, q15 = lane & 15;

    const u16* sp_[12];
#pragma unroll
    for (int j = 0; j < 12; ++j) {
        int ch = j * 256 + tid;
        int arr = (ch < 1024) ? 0 : (ch < 2048) ? 1 : (ch < 2560) ? 2 : 3;
        int local = ch - ((arr == 0) ? 0 : (arr == 1) ? 1024 : (arr == 2) ? 2048 : 2560);
        int r = local >> 3, c = local & 7;
        int cs = (c ^ (r & 7)) * 8;
        const u16* base = (arr == 0) ? (Am + (size_t)(m0 + r) * E) :
                          (arr == 1) ? (As + (size_t)(m0 + r) * E) :
                          (arr == 2) ? (Wt + (size_t)(col0 + r) * E) :
                                       (W2t + (size_t)(col0 + r) * E);
        sp_[j] = base + cs;
    }

    f32x4 acc1[2][4], acc2[2][4];
#pragma unroll
    for (int mt = 0; mt < 2; ++mt)
#pragma unroll
        for (int nt = 0; nt < 4; ++nt) {
            acc1[mt][nt] = (f32x4){0.f, 0.f, 0.f, 0.f};
            acc2[mt][nt] = (f32x4){0.f, 0.f, 0.f, 0.f};
        }

    for (int t = 0; t < 12; ++t) {
#pragma unroll
        for (int j = 0; j < 12; ++j)
            GLL16(sp_[j] + t * 64, (u16*)((char*)L + j * 4096 + wv * 1024));
        __syncthreads();
#pragma unroll
        for (int kk = 0; kk < 2; ++kk) {
            bf16x8 am[2], asg[2];
#pragma unroll
            for (int mt = 0; mt < 2; ++mt) {
                int r = wv * 32 + mt * 16 + q15;
                int c = ((kk * 4 + g) ^ (r & 7)) * 8;
                am[mt]  = *(const bf16x8*)&L[(r << 6) + c];
                asg[mt] = *(const bf16x8*)&L[8192 + (r << 6) + c];
            }
#pragma unroll
            for (int nt = 0; nt < 4; ++nt) {
                int rb = nt * 16 + q15;
                int cb = ((kk * 4 + g) ^ (rb & 7)) * 8;
                bf16x8 bw = *(const bf16x8*)&L[16384 + (rb << 6) + cb];
                bf16x8 b2 = *(const bf16x8*)&L[20480 + (rb << 6) + cb];
                acc1[0][nt] = __builtin_amdgcn_mfma_f32_16x16x32_bf16(am[0], bw, acc1[0][nt], 0, 0, 0);
                acc1[1][nt] = __builtin_amdgcn_mfma_f32_16x16x32_bf16(am[1], bw, acc1[1][nt], 0, 0, 0);
                acc2[0][nt] = __builtin_amdgcn_mfma_f32_16x16x32_bf16(asg[0], b2, acc2[0][nt], 0, 0, 0);
                acc2[1][nt] = __builtin_amdgcn_mfma_f32_16x16x32_bf16(asg[1], b2, acc2[1][nt], 0, 0, 0);
            }
        }
        __syncthreads();
    }

    const float inv2 = 1.f / (768.f * 768.f), invd = 1.f / 768.f;
    float rr[2][4];
#pragma unroll
    for (int mt = 0; mt < 2; ++mt)
#pragma unroll
        for (int r = 0; r < 4; ++r) {
            int row = m0 + wv * 32 + mt * 16 + g * 4 + r;
            rr[mt][r] = rmu2[row] * inv2 + rsg[row] * invd;
        }

    if (MODE == 0) {
#pragma unroll
        for (int mt = 0; mt < 2; ++mt)
#pragma unroll
            for (int nt = 0; nt < 4; ++nt)
#pragma unroll
                for (int r = 0; r < 4; ++r) {
                    int row = m0 + wv * 32 + mt * 16 + g * 4 + r;
                    int col = col0 + nt * 16 + q15;
                    float mu = acc1[mt][nt][r];
                    float sg = sp_f(sp_f(acc2[mt][nt][r] + rr[mt][r] * spws[col]));
                    mu_out[(size_t)row * E + col] = mu;
                    sg_out[(size_t)row * E + col] = sg;
                }
    } else {
        const int proj = n_blk / 12, h = n_blk % 12;
        if (proj < 2) {
            u16* b0 = QKVB + (size_t)(proj * 3 + 0) * BFN;
            u16* b1 = QKVB + (size_t)(proj * 3 + 1) * BFN;
            u16* b2 = QKVB + (size_t)(proj * 3 + 2) * BFN;
#pragma unroll
            for (int mt = 0; mt < 2; ++mt)
#pragma unroll
                for (int nt = 0; nt < 4; ++nt)
#pragma unroll
                    for (int r = 0; r < 4; ++r) {
                        int row = m0 + wv * 32 + mt * 16 + g * 4 + r;
                        int col = col0 + nt * 16 + q15;
                        float mu = acc1[mt][nt][r];
                        float sg = sp_f(acc2[mt][nt][r] + rr[mt][r] * spws[col]);
                        int bb = row >> 10, s = row & 1023, d = nt * 16 + q15;
                        size_t rb = ((size_t)(bb * 12 + h) << 16) + ((size_t)s << 6) + d;
                        b0[rb] = f2bf(mu);
                        b1[rb] = f2bf(sg);
                        b2[rb] = f2bf(proj == 0 ? (mu * mu + sg) * QSC : mu * mu * QSC);
                    }
        } else {
            float sgv[2][4][4];
#pragma unroll
            for (int mt = 0; mt < 2; ++mt)
#pragma unroll
                for (int nt = 0; nt < 4; ++nt)
#pragma unroll
                    for (int r = 0; r < 4; ++r) {
                        int col = col0 + nt * 16 + q15;
                        sgv[mt][nt][r] = sp_f(acc2[mt][nt][r] + rr[mt][r] * spws[col]);
                    }
            const int bb = m0 >> 10, s0 = m0 & 1023;
#pragma unroll
            for (int a = 0; a < 3; ++a) {
                __syncthreads();
#pragma unroll
                for (int mt = 0; mt < 2; ++mt)
#pragma unroll
                    for (int nt = 0; nt < 4; ++nt)
#pragma unroll
                        for (int r = 0; r < 4; ++r) {
                            float mu = acc1[mt][nt][r], sg = sgv[mt][nt][r];
                            float v = (a == 0) ? mu : (a == 1) ? sg * 0.0009765625f : mu * mu + sg;
                            L[(nt * 16 + q15) * 136 + wv * 32 + mt * 16 + g * 4 + r] = f2bf(v);
                        }
                __syncthreads();
                const int d = tid >> 2, sc = (tid & 3) * 32;
                u16* dst = QKVB + (size_t)(6 + a) * BFN;
                size_t ga = ((size_t)((bb * 12 + h) * 64 + d) << 10) + s0 + sc;
                *(uint4*)(dst + ga)      = *(const uint4*)&L[d * 136 + sc];
                *(uint4*)(dst + ga + 8)  = *(const uint4*)&L[d * 136 + sc + 8];
                *(uint4*)(dst + ga + 16) = *(const uint4*)&L[d * 136 + sc + 16];
                *(uint4*)(dst + ga + 24) = *(const uint4*)&L[d * 136 + sc + 24];
            }
        }
    }
}

// ------------------------------------------------------------- attention ---
// v6: T3 2-phase prefetch. K-side double-buffered (12KB x2), V single (12KB),
// P-tiles stride-40 (80B rows, 2-way banks). Per t-iter: issue V(t)+K(t+1)
// stages -> scores+softmax from K[cur] -> vmcnt(3) (V only) + raw s_barrier
// -> PV -> __syncthreads (drains K prefetch after full-iter hiding).
// LDS 51KB -> 3 blocks/CU (grid 768 = exactly 3/CU).
#define KB0 0
#define KB1 6144
#define VB  12288
#define PB  18432
__global__ __launch_bounds__(256, 3) void vdp_attn6(
    const u16* __restrict__ Kmu, const u16* __restrict__ Ksg, const u16* __restrict__ Asq,
    const u16* __restrict__ Qmu, const u16* __restrict__ Q1v, const u16* __restrict__ Q2v,
    const u16* __restrict__ Vmu, const u16* __restrict__ Vsg, const u16* __restrict__ Vw2,
    u16* __restrict__ om, u16* __restrict__ osg)
{
    __shared__ __align__(16) u16 L[26112];   // 51KB

    const int wgid = blockIdx.x;                  // 768 = 48bh x 16qt
    const int seq = (wgid & 7) * 96 + (wgid >> 3);
    const int bh = seq >> 4, qt = seq & 15;
    const int tid = threadIdx.x, wv = tid >> 6, lane = tid & 63;
    const int g = lane >> 4, q15 = lane & 15;
    const size_t hb = (size_t)bh << 16;

    const size_t qoff = hb + (size_t)((qt * 64 + wv * 16 + q15) << 6) + g * 8;
    bf16x8 bq0 = *(const bf16x8*)(Qmu + qoff), bq1 = *(const bf16x8*)(Qmu + qoff + 32);
    bf16x8 b10 = *(const bf16x8*)(Q1v + qoff), b11 = *(const bf16x8*)(Q1v + qoff + 32);
    bf16x8 b20 = *(const bf16x8*)(Q2v + qoff), b21 = *(const bf16x8*)(Q2v + qoff + 32);

    // staging source offsets (chunk = tid; source col-chunk pre-swizzled)
    const int sr = tid >> 3, sc8 = tid & 7;
    const size_t koffA = hb + (size_t)sr * 64 + ((sc8 ^ (sr & 7)) << 3);                // rows 0..31
    const size_t koffB = hb + (size_t)(sr + 32) * 64 + ((sc8 ^ (sr & 7)) << 3);         // rows 32..63
    const int vr = tid >> 2, vc = tid & 3;
    const size_t voff = hb + (size_t)vr * 1024 + ((vc ^ ((vr >> 1) & 3)) << 3);

    int cur = 0;

    // ---- pass 1: softmax stats (Kmu, 64-k tiles, double-buffered prefetch)
    float m2 = -3.0e38f;
    float lacc[4] = {0.f, 0.f, 0.f, 0.f};
    GLL16(Kmu + koffA, &L[KB0 + wv * 512]);
    GLL16(Kmu + koffB, &L[KB0 + 2048 + wv * 512]);
    __syncthreads();
    for (int t = 0; t < 16; ++t) {
        const int tn = (t < 15) ? t + 1 : 15;
        const int nb = cur ? KB0 : KB1;
        GLL16(Kmu + koffA + ((size_t)tn << 12), &L[nb + wv * 512]);
        GLL16(Kmu + koffB + ((size_t)tn << 12), &L[nb + 2048 + wv * 512]);
        const int kb = cur ? KB1 : KB0;
        f32x4 sc[4];
#pragma unroll
        for (int kt = 0; kt < 4; ++kt) sc[kt] = (f32x4){0.f, 0.f, 0.f, 0.f};
        __builtin_amdgcn_s_setprio(1);
#pragma unroll
        for (int kt = 0; kt < 4; ++kt) {
            int row = kt * 16 + q15, ra = kb + (row << 6);
            bf16x8 k0 = *(const bf16x8*)&L[ra + ((g ^ (row & 7)) << 3)];
            bf16x8 k1 = *(const bf16x8*)&L[ra + (((g + 4) ^ (row & 7)) << 3)];
            sc[kt] = __builtin_amdgcn_mfma_f32_16x16x32_bf16(k0, bq0, sc[kt], 0, 0, 0);
            sc[kt] = __builtin_amdgcn_mfma_f32_16x16x32_bf16(k1, bq1, sc[kt], 0, 0, 0);
        }
        __builtin_amdgcn_s_setprio(0);
        float t0 = fmaxf(fmaxf(sc[0][0], sc[0][1]), fmaxf(sc[0][2], sc[0][3]));
        float t1 = fmaxf(fmaxf(sc[1][0], sc[1][1]), fmaxf(sc[1][2], sc[1][3]));
        float t2 = fmaxf(fmaxf(sc[2][0], sc[2][1]), fmaxf(sc[2][2], sc[2][3]));
        float t3 = fmaxf(fmaxf(sc[3][0], sc[3][1]), fmaxf(sc[3][2], sc[3][3]));
        float tm = fmaxf(fmaxf(t0, t1), fmaxf(t2, t3)) * C2E;
        if (tm > m2 + 8.f) {
            float f = ex2(m2 - tm);
            lacc[0] *= f; lacc[1] *= f; lacc[2] *= f; lacc[3] *= f;
            m2 = tm;
        }
#pragma unroll
        for (int kt = 0; kt < 4; ++kt)
#pragma unroll
            for (int r = 0; r < 4; ++r)
                lacc[kt] += ex2(fmaf(sc[kt][r], C2E, -m2));
        __syncthreads();
        cur ^= 1;
    }
    float l = (lacc[0] + lacc[1]) + (lacc[2] + lacc[3]);
#pragma unroll
    for (int off = 16; off <= 32; off <<= 1) {
        float mo = __shfl_xor(m2, off), lo = __shfl_xor(l, off);
        float nm = fmaxf(m2, mo);
        l = l * ex2(m2 - nm) + lo * ex2(mo - nm);
        m2 = nm;
    }
    const float M = m2 + lg2(l);

    // ---- pass 2: 32-k tiles, K dbuf prefetch + V single-buffer
    f32x4 accm[4], accd[4], acce[4];
#pragma unroll
    for (int nt = 0; nt < 4; ++nt) {
        accm[nt] = (f32x4){0.f, 0.f, 0.f, 0.f};
        accd[nt] = (f32x4){0.f, 0.f, 0.f, 0.f};
        acce[nt] = (f32x4){0.f, 0.f, 0.f, 0.f};
    }
    const int plw = PB + wv * 1920;

    cur = 0;
    GLL16(Kmu + koffA, &L[KB0 + 0    + wv * 512]);
    GLL16(Ksg + koffA, &L[KB0 + 2048 + wv * 512]);
    GLL16(Asq + koffA, &L[KB0 + 4096 + wv * 512]);
    __syncthreads();

    for (int t = 0; t < 32; ++t) {
        // issue V(t) then K(t+1) (counted-vmcnt relies on this order)
        const size_t va = (size_t)t << 5;
        GLL16(Vmu + voff + va, &L[VB + 0    + wv * 512]);
        GLL16(Vsg + voff + va, &L[VB + 2048 + wv * 512]);
        GLL16(Vw2 + voff + va, &L[VB + 4096 + wv * 512]);
        const int tn = (t < 31) ? t + 1 : 31;
        const size_t ka = (size_t)tn << 11;
        const int nb = cur ? KB0 : KB1;
        GLL16(Kmu + koffA + ka, &L[nb + 0    + wv * 512]);
        GLL16(Ksg + koffA + ka, &L[nb + 2048 + wv * 512]);
        GLL16(Asq + koffA + ka, &L[nb + 4096 + wv * 512]);

        // scores from K[cur]
        const int kb = cur ? KB1 : KB0;
        f32x4 sc[2], sgc[2];
#pragma unroll
        for (int kt = 0; kt < 2; ++kt) { sc[kt] = (f32x4){0.f,0.f,0.f,0.f}; sgc[kt] = (f32x4){0.f,0.f,0.f,0.f}; }
        __builtin_amdgcn_s_setprio(1);
#pragma unroll
        for (int kt = 0; kt < 2; ++kt) {
            int row = kt * 16 + q15, ra = kb + (row << 6);
            int ca = ((g ^ (row & 7)) << 3), cb = (((g + 4) ^ (row & 7)) << 3);
            sc[kt]  = __builtin_amdgcn_mfma_f32_16x16x32_bf16(*(const bf16x8*)&L[ra + ca],        bq0, sc[kt],  0, 0, 0);
            sc[kt]  = __builtin_amdgcn_mfma_f32_16x16x32_bf16(*(const bf16x8*)&L[ra + cb],        bq1, sc[kt],  0, 0, 0);
            sgc[kt] = __builtin_amdgcn_mfma_f32_16x16x32_bf16(*(const bf16x8*)&L[2048 + ra + ca], b10, sgc[kt], 0, 0, 0);
            sgc[kt] = __builtin_amdgcn_mfma_f32_16x16x32_bf16(*(const bf16x8*)&L[2048 + ra + cb], b11, sgc[kt], 0, 0, 0);
            sgc[kt] = __builtin_amdgcn_mfma_f32_16x16x32_bf16(*(const bf16x8*)&L[4096 + ra + ca], b20, sgc[kt], 0, 0, 0);
            sgc[kt] = __builtin_amdgcn_mfma_f32_16x16x32_bf16(*(const bf16x8*)&L[4096 + ra + cb], b21, sgc[kt], 0, 0, 0);
        }
        __builtin_amdgcn_s_setprio(0);

        // softmax -> P tiles (stride-40 rows, uint2 writes)
#pragma unroll
        for (int kt = 0; kt < 2; ++kt) {
            float p[4], p2[4], sw[4];
#pragma unroll
            for (int r = 0; r < 4; ++r) {
                p[r] = ex2(fmaf(sc[kt][r], C2E, -M));
                p2[r] = p[r] * p[r];
                float gq = p[r] - p2[r];
                sw[r] = gq * gq * sgc[kt][r];
            }
            int ch = (kt << 1) | (g >> 1);
            int base = q15 * 40 + ((ch ^ ((q15 >> 1) & 3)) << 3) + ((g & 1) << 2);
            *(uint2*)&L[plw + base]        = make_uint2(cvtpk(p[0],  p[1]),  cvtpk(p[2],  p[3]));
            *(uint2*)&L[plw + 640 + base]  = make_uint2(cvtpk(p2[0], p2[1]), cvtpk(p2[2], p2[3]));
            *(uint2*)&L[plw + 1280 + base] = make_uint2(cvtpk(sw[0], sw[1]), cvtpk(sw[2], sw[3]));
        }

        // wait V only (3 K-loads stay in flight), all-waves barrier
        asm volatile("s_waitcnt vmcnt(3)" ::: "memory");
        __builtin_amdgcn_sched_barrier(0);
        __builtin_amdgcn_s_barrier();
        __builtin_amdgcn_sched_barrier(0);

        // PV
        __builtin_amdgcn_s_setprio(1);
        {
            int pc = q15 * 40 + ((g ^ ((q15 >> 1) & 3)) << 3);
            bf16x8 pa  = *(const bf16x8*)&L[plw + pc];
            bf16x8 p2a = *(const bf16x8*)&L[plw + 640 + pc];
            bf16x8 swa = *(const bf16x8*)&L[plw + 1280 + pc];
#pragma unroll
            for (int nt = 0; nt < 4; ++nt) {
                int row = nt * 16 + q15;
                int vi = (row << 5) + ((g ^ ((q15 >> 1) & 3)) << 3);
                accm[nt] = __builtin_amdgcn_mfma_f32_16x16x32_bf16(pa,  *(const bf16x8*)&L[VB + vi],        accm[nt], 0, 0, 0);
                accd[nt] = __builtin_amdgcn_mfma_f32_16x16x32_bf16(p2a, *(const bf16x8*)&L[VB + 2048 + vi], accd[nt], 0, 0, 0);
                acce[nt] = __builtin_amdgcn_mfma_f32_16x16x32_bf16(swa, *(const bf16x8*)&L[VB + 4096 + vi], acce[nt], 0, 0, 0);
            }
        }
        __builtin_amdgcn_s_setprio(0);
        __syncthreads();
        cur ^= 1;
    }

    const int b_ = bh / 12, h_ = bh % 12;
#pragma unroll
    for (int nt = 0; nt < 4; ++nt)
#pragma unroll
        for (int r = 0; r < 4; ++r) {
            int srow = qt * 64 + wv * 16 + g * 4 + r;
            int d = nt * 16 + q15;
            size_t o = (size_t)(b_ * 1024 + srow) * E + h_ * 64 + d;
            om[o]  = f2bf(accm[nt][r]);
            osg[o] = f2bf(sp_f(accd[nt][r] + acce[nt][r]));
        }
}

// ------------------------------------------------------------------- kl ----
__global__ void kl_kernel(const float* __restrict__ w0, const float* __restrict__ w1,
                          const float* __restrict__ w2, const float* __restrict__ w3,
                          const float* __restrict__ s0, const float* __restrict__ s1,
                          const float* __restrict__ s2, const float* __restrict__ s3,
                          float* __restrict__ kl_out)
{
    const int gid = blockIdx.x * 256 + threadIdx.x;
    const int gsz = gridDim.x * 256;
    float acc = 0.f;
    const float cw = 100.f / ((float)E * (float)E);
#pragma unroll
    for (int mm = 0; mm < 4; ++mm) {
        const float* w = (mm == 0) ? w0 : (mm == 1) ? w1 : (mm == 2) ? w2 : w3;
        const float* sv = (mm == 0) ? s0 : (mm == 1) ? s1 : (mm == 2) ? s2 : s3;
        for (int i = gid; i < E * E; i += gsz) { float x = w[i]; acc += x * x * cw; }
        for (int i = gid; i < E; i += gsz) { float x = sv[i]; acc += (-x + sp_f(x) * 100.f) * (1.f / (float)E); }
    }
    for (int off = 32; off; off >>= 1) acc += __shfl_xor(acc, off);
    __shared__ float r[4];
    int tid = threadIdx.x, w_ = tid >> 6;
    if ((tid & 63) == 0) r[w_] = acc;
    __syncthreads();
    if (tid == 0) atomicAdd(kl_out, 0.5f * (r[0] + r[1] + r[2] + r[3]));
}

// --------------------------------------------------------------- launch ----
extern "C" void kernel_launch(void* const* d_in, const int* in_sizes, int n_in,
                              void* d_out, int out_size, void* d_ws, size_t ws_size,
                              hipStream_t stream)
{
    const float* mu_in = (const float*)d_in[0];
    const float* sg_in = (const float*)d_in[1];
    const float* wq  = (const float*)d_in[2];
    const float* wqs = (const float*)d_in[3];
    const float* wk  = (const float*)d_in[4];
    const float* wks = (const float*)d_in[5];
    const float* wvp = (const float*)d_in[6];
    const float* wvs = (const float*)d_in[7];
    const float* wo  = (const float*)d_in[8];
    const float* wos = (const float*)d_in[9];

    float* out_mu = (float*)d_out;
    float* out_sg = out_mu + (size_t)NTOK * E;
    float* kl_out = out_mu + 2 * (size_t)NTOK * E;

    float* ws = (float*)d_ws;
    size_t off = 0;
    auto allocf = [&](size_t n) { float* p = ws + off; off += n; return p; };
    float* rmu2  = allocf(NTOK);
    float* rsgs  = allocf(NTOK);
    float* armu2 = allocf(NTOK);
    float* arsg  = allocf(NTOK);
    float* spws  = allocf(4 * E);

    u16* ub = (u16*)(ws + off);
    size_t uoff = 0;
    auto allocu = [&](size_t n) { u16* p = ub + uoff; uoff += n; return p; };
    u16* Xmu    = allocu(BFN);
    u16* Xsg    = allocu(BFN);
    u16* WtQKV  = allocu(3 * WFN);
    u16* W2tQKV = allocu(3 * WFN);
    u16* Wt3    = allocu(WFN);
    u16* W2t3   = allocu(WFN);
    u16* QKVB   = allocu(9 * BFN);
    u16* amu_b  = allocu(BFN);
    u16* asg_b  = allocu(BFN);
    (void)ws_size; (void)in_sizes; (void)n_in; (void)out_size;

    prep_kernel<<<13, 256, 0, stream>>>(wqs, wks, wvs, wos, spws, kl_out);
    convstats_kernel<<<NTOK, 128, 0, stream>>>(mu_in, sg_in, Xmu, Xsg, rmu2, rsgs);
    dim3 tgrid(24, 24);
    transpose_w_kernel<<<tgrid, 256, 0, stream>>>(wq,  WtQKV,           W2tQKV);
    transpose_w_kernel<<<tgrid, 256, 0, stream>>>(wk,  WtQKV + WFN,     W2tQKV + WFN);
    transpose_w_kernel<<<tgrid, 256, 0, stream>>>(wvp, WtQKV + 2 * WFN, W2tQKV + 2 * WFN);
    transpose_w_kernel<<<tgrid, 256, 0, stream>>>(wo,  Wt3,             W2t3);

    linear_fused<1><<<1152, 256, 0, stream>>>(Xmu, Xsg, WtQKV, W2tQKV, spws, rmu2, rsgs,
                                              nullptr, nullptr, QKVB);

    vdp_attn6<<<768, 256, 0, stream>>>(QKVB + 3 * BFN, QKVB + 4 * BFN, QKVB + 1 * BFN,
                                       QKVB + 0 * BFN, QKVB + 2 * BFN, QKVB + 5 * BFN,
                                       QKVB + 6 * BFN, QKVB + 7 * BFN, QKVB + 8 * BFN,
                                       amu_b, asg_b);

    rowstats_bf16_kernel<<<NTOK, 128, 0, stream>>>(amu_b, asg_b, armu2, arsg);
    linear_fused<0><<<384, 256, 0, stream>>>(amu_b, asg_b, Wt3, W2t3, spws + 3 * E, armu2, arsg,
                                             out_mu, out_sg, nullptr);

    kl_kernel<<<512, 256, 0, stream>>>(wq, wk, wvp, wo, wqs, wks, wvs, wos, kl_out);
}

// Round 7
// 226.012 us; speedup vs baseline: 16.4690x; 1.0234x over previous
//
#include <hip/hip_runtime.h>
#include <math.h>

#define E 768
#define NTOK 4096  /* BATCH*S */

typedef __attribute__((ext_vector_type(8))) __bf16 bf16x8;
typedef __attribute__((ext_vector_type(4))) float f32x4;
typedef unsigned int u32;
typedef unsigned short u16;
typedef __attribute__((ext_vector_type(4))) u32 u32x4;

#define BFN ((size_t)NTOK * E)
#define WFN ((size_t)E * E)
#define QSC 1.4901161193847656e-08f   /* 2^-26 */
#define C2E 0.18033688011112042f      /* 0.125 * log2(e) */

__device__ __forceinline__ float sp_f(float x) {
    return fmaxf(x, 0.f) + log1pf(__expf(-fabsf(x)));
}
__device__ __forceinline__ u16 f2bf(float f) {
    u32 u = __float_as_uint(f);
    u += 0x7fffu + ((u >> 16) & 1u);
    return (u16)(u >> 16);
}
__device__ __forceinline__ u32 pk2(float a, float b) {
    return (u32)f2bf(a) | ((u32)f2bf(b) << 16);
}
__device__ __forceinline__ u32 cvtpk(float a, float b) {
    u32 r; asm("v_cvt_pk_bf16_f32 %0, %1, %2" : "=v"(r) : "v"(a), "v"(b)); return r;
}
__device__ __forceinline__ float ex2(float x) {
    float r; asm("v_exp_f32 %0, %1" : "=v"(r) : "v"(x)); return r;
}
__device__ __forceinline__ float lg2(float x) {
    float r; asm("v_log_f32 %0, %1" : "=v"(r) : "v"(x)); return r;
}
__device__ __forceinline__ float bfl(u32 u) { return __uint_as_float(u << 16); }
__device__ __forceinline__ float bfh(u32 u) { return __uint_as_float(u & 0xffff0000u); }

#define GLL16(gp, lp) __builtin_amdgcn_global_load_lds( \
    (const __attribute__((address_space(1))) u32*)(gp), \
    (__attribute__((address_space(3))) u32*)(lp), 16, 0, 0)

#define SBAR() do { __builtin_amdgcn_sched_barrier(0); \
                    __builtin_amdgcn_s_barrier(); \
                    __builtin_amdgcn_sched_barrier(0); } while (0)
#define VMCNT(N) do { asm volatile("s_waitcnt vmcnt(" #N ")" ::: "memory"); \
                      __builtin_amdgcn_sched_barrier(0); } while (0)

// ----------------------------------------------------------- prep (fused) --
// blocks [0,2048): fp32->bf16 conv + row stats (2 rows/block)
// blocks [2048,4352): 4x weight transpose+square (z = (b-2048)/576)
// blocks [4352,4864): KL partial sums (atomicAdd)
// block 4864: softplus(w_sigma) table
__global__ __launch_bounds__(256) void prep_all(
    const float* __restrict__ mu_in, const float* __restrict__ sg_in,
    const float* __restrict__ wq, const float* __restrict__ wk,
    const float* __restrict__ wvp, const float* __restrict__ wo,
    const float* __restrict__ wqs, const float* __restrict__ wks,
    const float* __restrict__ wvs, const float* __restrict__ wos,
    u16* __restrict__ Xmu, u16* __restrict__ Xsg,
    float* __restrict__ rmu2, float* __restrict__ rsg,
    u16* __restrict__ WtAll, u16* __restrict__ W2tAll,
    float* __restrict__ spws, float* __restrict__ kl_out)
{
    __shared__ float T[32][33];
    __shared__ float r1[4], r2[4];
    const int b = blockIdx.x, tid = threadIdx.x;

    if (b < 2048) {
        const int half = tid >> 7;
        const int n = b * 2 + half;
        const int t2 = tid & 127;
        float s1 = 0.f, s2 = 0.f;
        if (t2 < 96) {
            size_t o = (size_t)n * E + t2 * 8;
            float4 a0 = *(const float4*)(mu_in + o), a1 = *(const float4*)(mu_in + o + 4);
            float4 b0 = *(const float4*)(sg_in + o), b1 = *(const float4*)(sg_in + o + 4);
            *(uint4*)(Xmu + o) = make_uint4(pk2(a0.x, a0.y), pk2(a0.z, a0.w), pk2(a1.x, a1.y), pk2(a1.z, a1.w));
            *(uint4*)(Xsg + o) = make_uint4(pk2(b0.x, b0.y), pk2(b0.z, b0.w), pk2(b1.x, b1.y), pk2(b1.z, b1.w));
            s1 = a0.x*a0.x + a0.y*a0.y + a0.z*a0.z + a0.w*a0.w + a1.x*a1.x + a1.y*a1.y + a1.z*a1.z + a1.w*a1.w;
            s2 = b0.x + b0.y + b0.z + b0.w + b1.x + b1.y + b1.z + b1.w;
        }
        for (int off = 32; off; off >>= 1) {
            s1 += __shfl_xor(s1, off);
            s2 += __shfl_xor(s2, off);
        }
        if ((tid & 63) == 0) { r1[tid >> 6] = s1; r2[tid >> 6] = s2; }
        __syncthreads();
        if (t2 == 0) {
            rmu2[n] = r1[half * 2] + r1[half * 2 + 1];
            rsg[n]  = r2[half * 2] + r2[half * 2 + 1];
        }
    } else if (b < 4352) {
        const int b2 = b - 2048;
        const int z = b2 / 576, rem = b2 - z * 576;
        const float* W = (z == 0) ? wq : (z == 1) ? wk : (z == 2) ? wvp : wo;
        u16* Wt  = WtAll  + (size_t)z * WFN;
        u16* W2t = W2tAll + (size_t)z * WFN;
        const int j0 = (rem % 24) * 32, k0 = (rem / 24) * 32;
        const int r = tid >> 3, c = (tid & 7) * 4;
        float4 v = *(const float4*)(W + (size_t)(k0 + r) * E + j0 + c);
        T[r][c] = v.x; T[r][c + 1] = v.y; T[r][c + 2] = v.z; T[r][c + 3] = v.w;
        __syncthreads();
        const int j = tid >> 3, kc = (tid & 7) * 4;
        float w0 = T[kc][j], w1 = T[kc + 1][j], w2 = T[kc + 2][j], w3 = T[kc + 3][j];
        size_t o = (size_t)(j0 + j) * E + k0 + kc;
        *(uint2*)(Wt + o) = make_uint2(pk2(w0, w1), pk2(w2, w3));
        const float s = 1.f / 768.f;
        *(uint2*)(W2t + o) = make_uint2(pk2(w0 * w0 * s, w1 * w1 * s), pk2(w2 * w2 * s, w3 * w3 * s));
    } else if (b < 4864) {
        const int gid = (b - 4352) * 256 + tid;
        const int gsz = 512 * 256;
        float acc = 0.f;
        const float cw = 100.f / ((float)E * (float)E);
#pragma unroll
        for (int mm = 0; mm < 4; ++mm) {
            const float* w  = (mm == 0) ? wq  : (mm == 1) ? wk  : (mm == 2) ? wvp : wo;
            const float* sv = (mm == 0) ? wqs : (mm == 1) ? wks : (mm == 2) ? wvs : wos;
            for (int i = gid; i < E * E; i += gsz) { float x = w[i]; acc += x * x * cw; }
            for (int i = gid; i < E; i += gsz) { float x = sv[i]; acc += (-x + sp_f(x) * 100.f) * (1.f / (float)E); }
        }
        if (b == 4352 && tid == 0) acc += 4.f * (logf(0.01f) - 1.f);
        for (int off = 32; off; off >>= 1) acc += __shfl_xor(acc, off);
        if ((tid & 63) == 0) r1[tid >> 6] = acc;
        __syncthreads();
        if (tid == 0) atomicAdd(kl_out, 0.5f * (r1[0] + r1[1] + r1[2] + r1[3]));
    } else {
        for (int i = tid; i < 4 * E; i += 256) {
            const float* src;
            int j;
            if (i < E)            { src = wqs; j = i; }
            else if (i < 2 * E)   { src = wks; j = i - E; }
            else if (i < 3 * E)   { src = wvs; j = i - 2 * E; }
            else                  { src = wos; j = i - 3 * E; }
            spws[i] = sp_f(src[j]);
        }
    }
}

__global__ __launch_bounds__(128) void rowstats_bf16_kernel(
    const u16* __restrict__ mu, const u16* __restrict__ sg,
    float* __restrict__ rmu2, float* __restrict__ rsg)
{
    const int n = blockIdx.x, tid = threadIdx.x;
    float s1 = 0.f, s2 = 0.f;
    if (tid < 96) {
        uint4 um = *(const uint4*)(mu + (size_t)n * E + tid * 8);
        uint4 us = *(const uint4*)(sg + (size_t)n * E + tid * 8);
        u32 ua[4] = {um.x, um.y, um.z, um.w};
        u32 ub[4] = {us.x, us.y, us.z, us.w};
#pragma unroll
        for (int j = 0; j < 4; ++j) {
            float a0 = bfl(ua[j]), a1 = bfh(ua[j]);
            s1 += a0 * a0 + a1 * a1;
            s2 += bfl(ub[j]) + bfh(ub[j]);
        }
    }
    for (int off = 32; off; off >>= 1) {
        s1 += __shfl_xor(s1, off);
        s2 += __shfl_xor(s2, off);
    }
    __shared__ float r1[2], r2[2];
    if ((tid & 63) == 0) { r1[tid >> 6] = s1; r2[tid >> 6] = s2; }
    __syncthreads();
    if (tid == 0) { rmu2[n] = r1[0] + r1[1]; rsg[n] = r2[0] + r2[1]; }
}

// --------------------------------- linear (BK=32 double-buffered bf16 MFMA)
// buffer layout (12288 u16 each, two buffers): Amu[128][32]@0, Asg@4096,
// Wt[64][32]@8192, W2t@10240. Swizzle c^((r>>1)&3) on both source and read.
// Per iter: {raw barrier; issue 6 GLL16 -> next buf; vmcnt(6); raw barrier;
// 16 MFMA from cur buf} — prefetch stays in flight across barriers.
template<int MODE>
__global__ __launch_bounds__(256, 3) void linear_fused(
    const u16* __restrict__ Am, const u16* __restrict__ As,
    const u16* __restrict__ Wt, const u16* __restrict__ W2t,
    const float* __restrict__ spws, const float* __restrict__ rmu2, const float* __restrict__ rsg,
    float* __restrict__ mu_out, float* __restrict__ sg_out, u16* __restrict__ QKVB)
{
    __shared__ __align__(16) u16 L[24576];   // 48KB = 2 x 12288

    const int wgid = blockIdx.x;
    const int NW = (MODE == 1) ? 144 : 48;
    const int NB = (MODE == 1) ? 36 : 12;
    const int swz = (wgid & 7) * NW + (wgid >> 3);
    const int m_blk = swz / NB, n_blk = swz % NB;
    const int m0 = m_blk * 128, col0 = n_blk * 64;
    const int tid = threadIdx.x, wv = tid >> 6, lane = tid & 63;
    const int g = lane >> 4, q15 = lane & 15;

    const u16* sp_[6];
    {
        const int rA = tid >> 2, cA = tid & 3;
        const int rB = 64 + rA;
        const int csA = (cA ^ ((rA >> 1) & 3)) << 3;
        const int csB = (cA ^ ((rB >> 1) & 3)) << 3;
        sp_[0] = Am  + (size_t)(m0 + rA) * E + csA;
        sp_[1] = Am  + (size_t)(m0 + rB) * E + csB;
        sp_[2] = As  + (size_t)(m0 + rA) * E + csA;
        sp_[3] = As  + (size_t)(m0 + rB) * E + csB;
        sp_[4] = Wt  + (size_t)(col0 + rA) * E + csA;
        sp_[5] = W2t + (size_t)(col0 + rA) * E + csA;
    }

    f32x4 acc1[2][4], acc2[2][4];
#pragma unroll
    for (int mt = 0; mt < 2; ++mt)
#pragma unroll
        for (int nt = 0; nt < 4; ++nt) {
            acc1[mt][nt] = (f32x4){0.f, 0.f, 0.f, 0.f};
            acc2[mt][nt] = (f32x4){0.f, 0.f, 0.f, 0.f};
        }

#pragma unroll
    for (int j = 0; j < 6; ++j)
        GLL16(sp_[j], &L[j * 2048 + tid * 8]);

    for (int t = 0; t < 24; ++t) {
        SBAR();
        const int tn = (t < 23) ? t + 1 : 23;
        const int nb = ((t & 1) ^ 1) * 12288;
#pragma unroll
        for (int j = 0; j < 6; ++j)
            GLL16(sp_[j] + tn * 32, &L[nb + j * 2048 + tid * 8]);
        VMCNT(6);
        SBAR();
        const int cb = (t & 1) * 12288;
        bf16x8 am[2], asg[2];
#pragma unroll
        for (int mt = 0; mt < 2; ++mt) {
            int r = wv * 32 + mt * 16 + q15;
            int c = (g ^ ((r >> 1) & 3)) << 3;
            am[mt]  = *(const bf16x8*)&L[cb + r * 32 + c];
            asg[mt] = *(const bf16x8*)&L[cb + 4096 + r * 32 + c];
        }
        __builtin_amdgcn_s_setprio(1);
#pragma unroll
        for (int nt = 0; nt < 4; ++nt) {
            int rb = nt * 16 + q15;
            int c = (g ^ ((rb >> 1) & 3)) << 3;
            bf16x8 bw = *(const bf16x8*)&L[cb + 8192 + rb * 32 + c];
            bf16x8 b2 = *(const bf16x8*)&L[cb + 10240 + rb * 32 + c];
            acc1[0][nt] = __builtin_amdgcn_mfma_f32_16x16x32_bf16(am[0], bw, acc1[0][nt], 0, 0, 0);
            acc1[1][nt] = __builtin_amdgcn_mfma_f32_16x16x32_bf16(am[1], bw, acc1[1][nt], 0, 0, 0);
            acc2[0][nt] = __builtin_amdgcn_mfma_f32_16x16x32_bf16(asg[0], b2, acc2[0][nt], 0, 0, 0);
            acc2[1][nt] = __builtin_amdgcn_mfma_f32_16x16x32_bf16(asg[1], b2, acc2[1][nt], 0, 0, 0);
        }
        __builtin_amdgcn_s_setprio(0);
    }
    __syncthreads();

    const float inv2 = 1.f / (768.f * 768.f), invd = 1.f / 768.f;
    float rr[2][4];
#pragma unroll
    for (int mt = 0; mt < 2; ++mt)
#pragma unroll
        for (int r = 0; r < 4; ++r) {
            int row = m0 + wv * 32 + mt * 16 + g * 4 + r;
            rr[mt][r] = rmu2[row] * inv2 + rsg[row] * invd;
        }

    if (MODE == 0) {
#pragma unroll
        for (int mt = 0; mt < 2; ++mt)
#pragma unroll
            for (int nt = 0; nt < 4; ++nt)
#pragma unroll
                for (int r = 0; r < 4; ++r) {
                    int row = m0 + wv * 32 + mt * 16 + g * 4 + r;
                    int col = col0 + nt * 16 + q15;
                    float mu = acc1[mt][nt][r];
                    float sg = sp_f(sp_f(acc2[mt][nt][r] + rr[mt][r] * spws[col]));
                    mu_out[(size_t)row * E + col] = mu;
                    sg_out[(size_t)row * E + col] = sg;
                }
    } else {
        const int proj = n_blk / 12, h = n_blk % 12;
        if (proj < 2) {
            u16* b0 = QKVB + (size_t)(proj * 3 + 0) * BFN;
            u16* b1 = QKVB + (size_t)(proj * 3 + 1) * BFN;
            u16* b2 = QKVB + (size_t)(proj * 3 + 2) * BFN;
#pragma unroll
            for (int mt = 0; mt < 2; ++mt)
#pragma unroll
                for (int nt = 0; nt < 4; ++nt)
#pragma unroll
                    for (int r = 0; r < 4; ++r) {
                        int row = m0 + wv * 32 + mt * 16 + g * 4 + r;
                        int col = col0 + nt * 16 + q15;
                        float mu = acc1[mt][nt][r];
                        float sg = sp_f(acc2[mt][nt][r] + rr[mt][r] * spws[col]);
                        int bb = row >> 10, s = row & 1023, d = nt * 16 + q15;
                        size_t rb = ((size_t)(bb * 12 + h) << 16) + ((size_t)s << 6) + d;
                        b0[rb] = f2bf(mu);
                        b1[rb] = f2bf(sg);
                        b2[rb] = f2bf(proj == 0 ? (mu * mu + sg) * QSC : mu * mu * QSC);
                    }
        } else {
            // V: transposed [bh][d][s] with s PERMUTED within 32-blocks
            // (slot = g*8 + mt*4 + r) so attn's P stays register-local.
            float sgv[2][4][4];
#pragma unroll
            for (int mt = 0; mt < 2; ++mt)
#pragma unroll
                for (int nt = 0; nt < 4; ++nt)
#pragma unroll
                    for (int r = 0; r < 4; ++r) {
                        int col = col0 + nt * 16 + q15;
                        sgv[mt][nt][r] = sp_f(acc2[mt][nt][r] + rr[mt][r] * spws[col]);
                    }
            const int bb = m0 >> 10, s0 = m0 & 1023;
#pragma unroll
            for (int a = 0; a < 3; ++a) {
                __syncthreads();
#pragma unroll
                for (int mt = 0; mt < 2; ++mt)
#pragma unroll
                    for (int nt = 0; nt < 4; ++nt)
#pragma unroll
                        for (int r = 0; r < 4; ++r) {
                            float mu = acc1[mt][nt][r], sg = sgv[mt][nt][r];
                            float v = (a == 0) ? mu : (a == 1) ? sg * 0.0009765625f : mu * mu + sg;
                            L[(nt * 16 + q15) * 136 + wv * 32 + g * 8 + mt * 4 + r] = f2bf(v);
                        }
                __syncthreads();
                const int d = tid >> 2, sc = (tid & 3) * 32;
                u16* dst = QKVB + (size_t)(6 + a) * BFN;
                size_t ga = ((size_t)((bb * 12 + h) * 64 + d) << 10) + s0 + sc;
                *(uint4*)(dst + ga)      = *(const uint4*)&L[d * 136 + sc];
                *(uint4*)(dst + ga + 8)  = *(const uint4*)&L[d * 136 + sc + 8];
                *(uint4*)(dst + ga + 16) = *(const uint4*)&L[d * 136 + sc + 16];
                *(uint4*)(dst + ga + 24) = *(const uint4*)&L[d * 136 + sc + 24];
            }
        }
    }
}

// ------------------------------------------------------------- attention ---
// v7: raw-barrier pipelines with counted vmcnt in both passes; P never
// touches LDS (permuted-V slot order makes producer lane == consumer lane).
// LDS 36KB: K dbuf 2x12KB + V 12KB.
#define KB0 0
#define KB1 6144
#define VB  12288
__global__ __launch_bounds__(256, 3) void vdp_attn7(
    const u16* __restrict__ Kmu, const u16* __restrict__ Ksg, const u16* __restrict__ Asq,
    const u16* __restrict__ Qmu, const u16* __restrict__ Q1v, const u16* __restrict__ Q2v,
    const u16* __restrict__ Vmu, const u16* __restrict__ Vsg, const u16* __restrict__ Vw2,
    u16* __restrict__ om, u16* __restrict__ osg)
{
    __shared__ __align__(16) u16 L[18432];   // 36KB

    const int wgid = blockIdx.x;                  // 768 = 48bh x 16qt
    const int seq = (wgid & 7) * 96 + (wgid >> 3);
    const int bh = seq >> 4, qt = seq & 15;
    const int tid = threadIdx.x, wv = tid >> 6, lane = tid & 63;
    const int g = lane >> 4, q15 = lane & 15;
    const size_t hb = (size_t)bh << 16;

    const size_t qoff = hb + (size_t)((qt * 64 + wv * 16 + q15) << 6) + g * 8;
    bf16x8 bq0 = *(const bf16x8*)(Qmu + qoff), bq1 = *(const bf16x8*)(Qmu + qoff + 32);
    bf16x8 b10 = *(const bf16x8*)(Q1v + qoff), b11 = *(const bf16x8*)(Q1v + qoff + 32);
    bf16x8 b20 = *(const bf16x8*)(Q2v + qoff), b21 = *(const bf16x8*)(Q2v + qoff + 32);

    const int sr = tid >> 3, sc8 = tid & 7;
    const size_t koffA = hb + (size_t)sr * 64 + ((sc8 ^ (sr & 7)) << 3);
    const size_t koffB = hb + (size_t)(sr + 32) * 64 + ((sc8 ^ (sr & 7)) << 3);
    const int vr = tid >> 2, vc = tid & 3;
    const size_t voff = hb + (size_t)vr * 1024 + ((vc ^ ((vr >> 1) & 3)) << 3);

    // ---- pass 1: softmax stats, raw-barrier dbuf (bufs @0 and @4096)
    float m2 = -3.0e38f;
    float lacc[4] = {0.f, 0.f, 0.f, 0.f};
    GLL16(Kmu + koffA, &L[0 + wv * 512]);
    GLL16(Kmu + koffB, &L[2048 + wv * 512]);
    __syncthreads();
    for (int t = 0; t < 16; ++t) {
        SBAR();
        const int tn = (t < 15) ? t + 1 : 15;
        const int nb = (t & 1) ? 0 : 4096;
        GLL16(Kmu + koffA + ((size_t)tn << 12), &L[nb + wv * 512]);
        GLL16(Kmu + koffB + ((size_t)tn << 12), &L[nb + 2048 + wv * 512]);
        VMCNT(2);
        SBAR();
        const int kb = (t & 1) ? 4096 : 0;
        f32x4 sc[4];
#pragma unroll
        for (int kt = 0; kt < 4; ++kt) sc[kt] = (f32x4){0.f, 0.f, 0.f, 0.f};
        __builtin_amdgcn_s_setprio(1);
#pragma unroll
        for (int kt = 0; kt < 4; ++kt) {
            int row = kt * 16 + q15, ra = kb + (row << 6);
            bf16x8 k0 = *(const bf16x8*)&L[ra + ((g ^ (row & 7)) << 3)];
            bf16x8 k1 = *(const bf16x8*)&L[ra + (((g + 4) ^ (row & 7)) << 3)];
            sc[kt] = __builtin_amdgcn_mfma_f32_16x16x32_bf16(k0, bq0, sc[kt], 0, 0, 0);
            sc[kt] = __builtin_amdgcn_mfma_f32_16x16x32_bf16(k1, bq1, sc[kt], 0, 0, 0);
        }
        __builtin_amdgcn_s_setprio(0);
        float t0 = fmaxf(fmaxf(sc[0][0], sc[0][1]), fmaxf(sc[0][2], sc[0][3]));
        float t1 = fmaxf(fmaxf(sc[1][0], sc[1][1]), fmaxf(sc[1][2], sc[1][3]));
        float t2 = fmaxf(fmaxf(sc[2][0], sc[2][1]), fmaxf(sc[2][2], sc[2][3]));
        float t3 = fmaxf(fmaxf(sc[3][0], sc[3][1]), fmaxf(sc[3][2], sc[3][3]));
        float tm = fmaxf(fmaxf(t0, t1), fmaxf(t2, t3)) * C2E;
        if (tm > m2 + 8.f) {
            float f = ex2(m2 - tm);
            lacc[0] *= f; lacc[1] *= f; lacc[2] *= f; lacc[3] *= f;
            m2 = tm;
        }
#pragma unroll
        for (int kt = 0; kt < 4; ++kt)
#pragma unroll
            for (int r = 0; r < 4; ++r)
                lacc[kt] += ex2(fmaf(sc[kt][r], C2E, -m2));
    }
    __syncthreads();   // drain stray prefetch before pass-2 region reuse
    float l = (lacc[0] + lacc[1]) + (lacc[2] + lacc[3]);
#pragma unroll
    for (int off = 16; off <= 32; off <<= 1) {
        float mo = __shfl_xor(m2, off), lo = __shfl_xor(l, off);
        float nm = fmaxf(m2, mo);
        l = l * ex2(m2 - nm) + lo * ex2(mo - nm);
        m2 = nm;
    }
    const float M = m2 + lg2(l);

    // ---- pass 2
    f32x4 accm[4], accd[4], acce[4];
#pragma unroll
    for (int nt = 0; nt < 4; ++nt) {
        accm[nt] = (f32x4){0.f, 0.f, 0.f, 0.f};
        accd[nt] = (f32x4){0.f, 0.f, 0.f, 0.f};
        acce[nt] = (f32x4){0.f, 0.f, 0.f, 0.f};
    }

    int cur = 0;
    GLL16(Kmu + koffA, &L[KB0 + 0    + wv * 512]);
    GLL16(Ksg + koffA, &L[KB0 + 2048 + wv * 512]);
    GLL16(Asq + koffA, &L[KB0 + 4096 + wv * 512]);
    __syncthreads();

    for (int t = 0; t < 32; ++t) {
        SBAR();                                   // everyone done with V & K[nb]
        const size_t va = (size_t)t << 5;
        GLL16(Vmu + voff + va, &L[VB + 0    + wv * 512]);
        GLL16(Vsg + voff + va, &L[VB + 2048 + wv * 512]);
        GLL16(Vw2 + voff + va, &L[VB + 4096 + wv * 512]);
        const int tn = (t < 31) ? t + 1 : 31;
        const size_t ka = (size_t)tn << 11;
        const int nb = cur ? KB0 : KB1;
        GLL16(Kmu + koffA + ka, &L[nb + 0    + wv * 512]);
        GLL16(Ksg + koffA + ka, &L[nb + 2048 + wv * 512]);
        GLL16(Asq + koffA + ka, &L[nb + 4096 + wv * 512]);
        VMCNT(6);                                 // K(t) landed (mine)
        SBAR();                                   // K(t) landed (everyone)

        const int kb = cur ? KB1 : KB0;
        f32x4 sc[2], sgc[2];
#pragma unroll
        for (int kt = 0; kt < 2; ++kt) { sc[kt] = (f32x4){0.f,0.f,0.f,0.f}; sgc[kt] = (f32x4){0.f,0.f,0.f,0.f}; }
        __builtin_amdgcn_s_setprio(1);
#pragma unroll
        for (int kt = 0; kt < 2; ++kt) {
            int row = kt * 16 + q15, ra = kb + (row << 6);
            int ca = ((g ^ (row & 7)) << 3), cb = (((g + 4) ^ (row & 7)) << 3);
            sc[kt]  = __builtin_amdgcn_mfma_f32_16x16x32_bf16(*(const bf16x8*)&L[ra + ca],        bq0, sc[kt],  0, 0, 0);
            sc[kt]  = __builtin_amdgcn_mfma_f32_16x16x32_bf16(*(const bf16x8*)&L[ra + cb],        bq1, sc[kt],  0, 0, 0);
            sgc[kt] = __builtin_amdgcn_mfma_f32_16x16x32_bf16(*(const bf16x8*)&L[2048 + ra + ca], b10, sgc[kt], 0, 0, 0);
            sgc[kt] = __builtin_amdgcn_mfma_f32_16x16x32_bf16(*(const bf16x8*)&L[2048 + ra + cb], b11, sgc[kt], 0, 0, 0);
            sgc[kt] = __builtin_amdgcn_mfma_f32_16x16x32_bf16(*(const bf16x8*)&L[4096 + ra + ca], b20, sgc[kt], 0, 0, 0);
            sgc[kt] = __builtin_amdgcn_mfma_f32_16x16x32_bf16(*(const bf16x8*)&L[4096 + ra + cb], b21, sgc[kt], 0, 0, 0);
        }
        __builtin_amdgcn_s_setprio(0);

        // softmax -> REGISTER A-fragments (slot j = kt*4+r matches permuted V)
        float p[8], p2v[8], swv[8];
#pragma unroll
        for (int kt = 0; kt < 2; ++kt)
#pragma unroll
            for (int r = 0; r < 4; ++r) {
                int j = kt * 4 + r;
                float pv = ex2(fmaf(sc[kt][r], C2E, -M));
                float pp = pv * pv;
                float gq = pv - pp;
                p[j] = pv; p2v[j] = pp; swv[j] = gq * gq * sgc[kt][r];
            }
        u32x4 ua = {cvtpk(p[0], p[1]),   cvtpk(p[2], p[3]),   cvtpk(p[4], p[5]),   cvtpk(p[6], p[7])};
        u32x4 ub = {cvtpk(p2v[0], p2v[1]), cvtpk(p2v[2], p2v[3]), cvtpk(p2v[4], p2v[5]), cvtpk(p2v[6], p2v[7])};
        u32x4 uc = {cvtpk(swv[0], swv[1]), cvtpk(swv[2], swv[3]), cvtpk(swv[4], swv[5]), cvtpk(swv[6], swv[7])};
        bf16x8 pa  = *(const bf16x8*)&ua;
        bf16x8 p2a = *(const bf16x8*)&ub;
        bf16x8 swa = *(const bf16x8*)&uc;

        VMCNT(3);                                 // V(t) landed (mine)
        SBAR();                                   // V(t) landed (everyone)

        __builtin_amdgcn_s_setprio(1);
#pragma unroll
        for (int nt = 0; nt < 4; ++nt) {
            int row = nt * 16 + q15;
            int vi = (row << 5) + ((g ^ ((q15 >> 1) & 3)) << 3);
            accm[nt] = __builtin_amdgcn_mfma_f32_16x16x32_bf16(pa,  *(const bf16x8*)&L[VB + vi],        accm[nt], 0, 0, 0);
            accd[nt] = __builtin_amdgcn_mfma_f32_16x16x32_bf16(p2a, *(const bf16x8*)&L[VB + 2048 + vi], accd[nt], 0, 0, 0);
            acce[nt] = __builtin_amdgcn_mfma_f32_16x16x32_bf16(swa, *(const bf16x8*)&L[VB + 4096 + vi], acce[nt], 0, 0, 0);
        }
        __builtin_amdgcn_s_setprio(0);
        cur ^= 1;
    }

    const int b_ = bh / 12, h_ = bh % 12;
#pragma unroll
    for (int nt = 0; nt < 4; ++nt)
#pragma unroll
        for (int r = 0; r < 4; ++r) {
            int srow = qt * 64 + wv * 16 + g * 4 + r;
            int d = nt * 16 + q15;
            size_t o = (size_t)(b_ * 1024 + srow) * E + h_ * 64 + d;
            om[o]  = f2bf(accm[nt][r]);
            osg[o] = f2bf(sp_f(accd[nt][r] + acce[nt][r]));
        }
}

// --------------------------------------------------------------- launch ----
extern "C" void kernel_launch(void* const* d_in, const int* in_sizes, int n_in,
                              void* d_out, int out_size, void* d_ws, size_t ws_size,
                              hipStream_t stream)
{
    const float* mu_in = (const float*)d_in[0];
    const float* sg_in = (const float*)d_in[1];
    const float* wq  = (const float*)d_in[2];
    const float* wqs = (const float*)d_in[3];
    const float* wk  = (const float*)d_in[4];
    const float* wks = (const float*)d_in[5];
    const float* wvp = (const float*)d_in[6];
    const float* wvs = (const float*)d_in[7];
    const float* wo  = (const float*)d_in[8];
    const float* wos = (const float*)d_in[9];

    float* out_mu = (float*)d_out;
    float* out_sg = out_mu + (size_t)NTOK * E;
    float* kl_out = out_mu + 2 * (size_t)NTOK * E;

    float* ws = (float*)d_ws;
    size_t off = 0;
    auto allocf = [&](size_t n) { float* p = ws + off; off += n; return p; };
    float* rmu2  = allocf(NTOK);
    float* rsgs  = allocf(NTOK);
    float* armu2 = allocf(NTOK);
    float* arsg  = allocf(NTOK);
    float* spws  = allocf(4 * E);

    u16* ub = (u16*)(ws + off);
    size_t uoff = 0;
    auto allocu = [&](size_t n) { u16* p = ub + uoff; uoff += n; return p; };
    u16* Xmu    = allocu(BFN);
    u16* Xsg    = allocu(BFN);
    u16* WtAll  = allocu(4 * WFN);   // Q,K,V,O stacked
    u16* W2tAll = allocu(4 * WFN);
    u16* QKVB   = allocu(9 * BFN);
    u16* amu_b  = allocu(BFN);
    u16* asg_b  = allocu(BFN);
    (void)ws_size; (void)in_sizes; (void)n_in; (void)out_size;

    hipMemsetAsync(kl_out, 0, 4, stream);
    prep_all<<<4865, 256, 0, stream>>>(mu_in, sg_in, wq, wk, wvp, wo,
                                       wqs, wks, wvs, wos,
                                       Xmu, Xsg, rmu2, rsgs, WtAll, W2tAll,
                                       spws, kl_out);

    linear_fused<1><<<1152, 256, 0, stream>>>(Xmu, Xsg, WtAll, W2tAll, spws, rmu2, rsgs,
                                              nullptr, nullptr, QKVB);

    vdp_attn7<<<768, 256, 0, stream>>>(QKVB + 3 * BFN, QKVB + 4 * BFN, QKVB + 1 * BFN,
                                       QKVB + 0 * BFN, QKVB + 2 * BFN, QKVB + 5 * BFN,
                                       QKVB + 6 * BFN, QKVB + 7 * BFN, QKVB + 8 * BFN,
                                       amu_b, asg_b);

    rowstats_bf16_kernel<<<NTOK, 128, 0, stream>>>(amu_b, asg_b, armu2, arsg);
    linear_fused<0><<<384, 256, 0, stream>>>(amu_b, asg_b, WtAll + 3 * WFN, W2tAll + 3 * WFN,
                                             spws + 3 * E, armu2, arsg,
                                             out_mu, out_sg, nullptr);
}

// Round 9
// 223.307 us; speedup vs baseline: 16.6685x; 1.0121x over previous
//
#include <hip/hip_runtime.h>
#include <math.h>

#define E 768
#define NTOK 4096  /* BATCH*S */

typedef __attribute__((ext_vector_type(8))) __bf16 bf16x8;
typedef __attribute__((ext_vector_type(4))) float f32x4;
typedef unsigned int u32;
typedef unsigned short u16;
typedef __attribute__((ext_vector_type(4))) u32 u32x4;

#define BFN ((size_t)NTOK * E)
#define WFN ((size_t)E * E)
#define QSC 1.4901161193847656e-08f   /* 2^-26 */
#define C2E 0.18033688011112042f      /* 0.125 * log2(e) */

__device__ __forceinline__ float sp_f(float x) {
    return fmaxf(x, 0.f) + log1pf(__expf(-fabsf(x)));
}
__device__ __forceinline__ u16 f2bf(float f) {
    u32 u = __float_as_uint(f);
    u += 0x7fffu + ((u >> 16) & 1u);
    return (u16)(u >> 16);
}
__device__ __forceinline__ u32 pk2(float a, float b) {
    return (u32)f2bf(a) | ((u32)f2bf(b) << 16);
}
__device__ __forceinline__ u32 cvtpk(float a, float b) {
    u32 r; asm("v_cvt_pk_bf16_f32 %0, %1, %2" : "=v"(r) : "v"(a), "v"(b)); return r;
}
__device__ __forceinline__ float ex2(float x) {
    float r; asm("v_exp_f32 %0, %1" : "=v"(r) : "v"(x)); return r;
}
__device__ __forceinline__ float lg2(float x) {
    float r; asm("v_log_f32 %0, %1" : "=v"(r) : "v"(x)); return r;
}
__device__ __forceinline__ float bfl(u32 u) { return __uint_as_float(u << 16); }
__device__ __forceinline__ float bfh(u32 u) { return __uint_as_float(u & 0xffff0000u); }

#define GLL16(gp, lp) __builtin_amdgcn_global_load_lds( \
    (const __attribute__((address_space(1))) u32*)(gp), \
    (__attribute__((address_space(3))) u32*)(lp), 16, 0, 0)

#define SBAR() do { __builtin_amdgcn_sched_barrier(0); \
                    __builtin_amdgcn_s_barrier(); \
                    __builtin_amdgcn_sched_barrier(0); } while (0)
#define VMCNT(N) do { asm volatile("s_waitcnt vmcnt(" #N ")" ::: "memory"); \
                      __builtin_amdgcn_sched_barrier(0); } while (0)

// ----------------------------------------------------------- prep (fused) --
__global__ __launch_bounds__(256) void prep_all(
    const float* __restrict__ mu_in, const float* __restrict__ sg_in,
    const float* __restrict__ wq, const float* __restrict__ wk,
    const float* __restrict__ wvp, const float* __restrict__ wo,
    const float* __restrict__ wqs, const float* __restrict__ wks,
    const float* __restrict__ wvs, const float* __restrict__ wos,
    u16* __restrict__ Xmu, u16* __restrict__ Xsg,
    float* __restrict__ rmu2, float* __restrict__ rsg,
    u16* __restrict__ WtAll, u16* __restrict__ W2tAll,
    float* __restrict__ spws, float* __restrict__ kl_out)
{
    __shared__ float T[32][33];
    __shared__ float r1[4], r2[4];
    const int b = blockIdx.x, tid = threadIdx.x;

    if (b < 2048) {
        const int half = tid >> 7;
        const int n = b * 2 + half;
        const int t2 = tid & 127;
        float s1 = 0.f, s2 = 0.f;
        if (t2 < 96) {
            size_t o = (size_t)n * E + t2 * 8;
            float4 a0 = *(const float4*)(mu_in + o), a1 = *(const float4*)(mu_in + o + 4);
            float4 b0 = *(const float4*)(sg_in + o), b1 = *(const float4*)(sg_in + o + 4);
            *(uint4*)(Xmu + o) = make_uint4(pk2(a0.x, a0.y), pk2(a0.z, a0.w), pk2(a1.x, a1.y), pk2(a1.z, a1.w));
            *(uint4*)(Xsg + o) = make_uint4(pk2(b0.x, b0.y), pk2(b0.z, b0.w), pk2(b1.x, b1.y), pk2(b1.z, b1.w));
            s1 = a0.x*a0.x + a0.y*a0.y + a0.z*a0.z + a0.w*a0.w + a1.x*a1.x + a1.y*a1.y + a1.z*a1.z + a1.w*a1.w;
            s2 = b0.x + b0.y + b0.z + b0.w + b1.x + b1.y + b1.z + b1.w;
        }
        for (int off = 32; off; off >>= 1) {
            s1 += __shfl_xor(s1, off);
            s2 += __shfl_xor(s2, off);
        }
        if ((tid & 63) == 0) { r1[tid >> 6] = s1; r2[tid >> 6] = s2; }
        __syncthreads();
        if (t2 == 0) {
            rmu2[n] = r1[half * 2] + r1[half * 2 + 1];
            rsg[n]  = r2[half * 2] + r2[half * 2 + 1];
        }
    } else if (b < 4352) {
        const int b2 = b - 2048;
        const int z = b2 / 576, rem = b2 - z * 576;
        const float* W = (z == 0) ? wq : (z == 1) ? wk : (z == 2) ? wvp : wo;
        u16* Wt  = WtAll  + (size_t)z * WFN;
        u16* W2t = W2tAll + (size_t)z * WFN;
        const int j0 = (rem % 24) * 32, k0 = (rem / 24) * 32;
        const int r = tid >> 3, c = (tid & 7) * 4;
        float4 v = *(const float4*)(W + (size_t)(k0 + r) * E + j0 + c);
        T[r][c] = v.x; T[r][c + 1] = v.y; T[r][c + 2] = v.z; T[r][c + 3] = v.w;
        __syncthreads();
        const int j = tid >> 3, kc = (tid & 7) * 4;
        float w0 = T[kc][j], w1 = T[kc + 1][j], w2 = T[kc + 2][j], w3 = T[kc + 3][j];
        size_t o = (size_t)(j0 + j) * E + k0 + kc;
        *(uint2*)(Wt + o) = make_uint2(pk2(w0, w1), pk2(w2, w3));
        const float s = 1.f / 768.f;
        *(uint2*)(W2t + o) = make_uint2(pk2(w0 * w0 * s, w1 * w1 * s), pk2(w2 * w2 * s, w3 * w3 * s));
    } else if (b < 4864) {
        const int gid = (b - 4352) * 256 + tid;
        const int gsz = 512 * 256;
        float acc = 0.f;
        const float cw = 100.f / ((float)E * (float)E);
#pragma unroll
        for (int mm = 0; mm < 4; ++mm) {
            const float* w  = (mm == 0) ? wq  : (mm == 1) ? wk  : (mm == 2) ? wvp : wo;
            const float* sv = (mm == 0) ? wqs : (mm == 1) ? wks : (mm == 2) ? wvs : wos;
            for (int i = gid; i < E * E; i += gsz) { float x = w[i]; acc += x * x * cw; }
            for (int i = gid; i < E; i += gsz) { float x = sv[i]; acc += (-x + sp_f(x) * 100.f) * (1.f / (float)E); }
        }
        if (b == 4352 && tid == 0) acc += 4.f * (logf(0.01f) - 1.f);
        for (int off = 32; off; off >>= 1) acc += __shfl_xor(acc, off);
        if ((tid & 63) == 0) r1[tid >> 6] = acc;
        __syncthreads();
        if (tid == 0) atomicAdd(kl_out, 0.5f * (r1[0] + r1[1] + r1[2] + r1[3]));
    } else {
        for (int i = tid; i < 4 * E; i += 256) {
            const float* src;
            int j;
            if (i < E)            { src = wqs; j = i; }
            else if (i < 2 * E)   { src = wks; j = i - E; }
            else if (i < 3 * E)   { src = wvs; j = i - 2 * E; }
            else                  { src = wos; j = i - 3 * E; }
            spws[i] = sp_f(src[j]);
        }
    }
}

__global__ __launch_bounds__(128) void rowstats_bf16_kernel(
    const u16* __restrict__ mu, const u16* __restrict__ sg,
    float* __restrict__ rmu2, float* __restrict__ rsg)
{
    const int n = blockIdx.x, tid = threadIdx.x;
    float s1 = 0.f, s2 = 0.f;
    if (tid < 96) {
        uint4 um = *(const uint4*)(mu + (size_t)n * E + tid * 8);
        uint4 us = *(const uint4*)(sg + (size_t)n * E + tid * 8);
        u32 ua[4] = {um.x, um.y, um.z, um.w};
        u32 ub[4] = {us.x, us.y, us.z, us.w};
#pragma unroll
        for (int j = 0; j < 4; ++j) {
            float a0 = bfl(ua[j]), a1 = bfh(ua[j]);
            s1 += a0 * a0 + a1 * a1;
            s2 += bfl(ub[j]) + bfh(ub[j]);
        }
    }
    for (int off = 32; off; off >>= 1) {
        s1 += __shfl_xor(s1, off);
        s2 += __shfl_xor(s2, off);
    }
    __shared__ float r1[2], r2[2];
    if ((tid & 63) == 0) { r1[tid >> 6] = s1; r2[tid >> 6] = s2; }
    __syncthreads();
    if (tid == 0) { rmu2[n] = r1[0] + r1[1]; rsg[n] = r2[0] + r2[1]; }
}

// --------------------------------- linear (BK=32 double-buffered bf16 MFMA)
// XCD-chunked, m-FASTEST ordering: the 4 blocks sharing one W-panel are
// consecutive on an XCD (panel streamed once into L2), and the XCD's 1.6MB
// A-slice stays L2-resident across the whole n-sweep.
template<int MODE>
__global__ __launch_bounds__(256, 3) void linear_fused(
    const u16* __restrict__ Am, const u16* __restrict__ As,
    const u16* __restrict__ Wt, const u16* __restrict__ W2t,
    const float* __restrict__ spws, const float* __restrict__ rmu2, const float* __restrict__ rsg,
    float* __restrict__ mu_out, float* __restrict__ sg_out, u16* __restrict__ QKVB)
{
    __shared__ __align__(16) u16 L[24576];   // 48KB = 2 x 12288

    const int wgid = blockIdx.x;
    const int xcd = wgid & 7, local = wgid >> 3;
    const int m_blk = xcd * 4 + (local & 3);        // m fastest within chunk
    const int n_blk = local >> 2;
    const int m0 = m_blk * 128, col0 = n_blk * 64;
    const int tid = threadIdx.x, wv = tid >> 6, lane = tid & 63;
    const int g = lane >> 4, q15 = lane & 15;

    const u16* sp_[6];
    {
        const int rA = tid >> 2, cA = tid & 3;
        const int rB = 64 + rA;
        const int csA = (cA ^ ((rA >> 1) & 3)) << 3;
        const int csB = (cA ^ ((rB >> 1) & 3)) << 3;
        sp_[0] = Am  + (size_t)(m0 + rA) * E + csA;
        sp_[1] = Am  + (size_t)(m0 + rB) * E + csB;
        sp_[2] = As  + (size_t)(m0 + rA) * E + csA;
        sp_[3] = As  + (size_t)(m0 + rB) * E + csB;
        sp_[4] = Wt  + (size_t)(col0 + rA) * E + csA;
        sp_[5] = W2t + (size_t)(col0 + rA) * E + csA;
    }

    f32x4 acc1[2][4], acc2[2][4];
#pragma unroll
    for (int mt = 0; mt < 2; ++mt)
#pragma unroll
        for (int nt = 0; nt < 4; ++nt) {
            acc1[mt][nt] = (f32x4){0.f, 0.f, 0.f, 0.f};
            acc2[mt][nt] = (f32x4){0.f, 0.f, 0.f, 0.f};
        }

#pragma unroll
    for (int j = 0; j < 6; ++j)
        GLL16(sp_[j], &L[j * 2048 + tid * 8]);

    for (int t = 0; t < 24; ++t) {
        SBAR();
        const int tn = (t < 23) ? t + 1 : 23;
        const int nb = ((t & 1) ^ 1) * 12288;
#pragma unroll
        for (int j = 0; j < 6; ++j)
            GLL16(sp_[j] + tn * 32, &L[nb + j * 2048 + tid * 8]);
        VMCNT(6);
        SBAR();
        const int cb = (t & 1) * 12288;
        bf16x8 am[2], asg[2];
#pragma unroll
        for (int mt = 0; mt < 2; ++mt) {
            int r = wv * 32 + mt * 16 + q15;
            int c = (g ^ ((r >> 1) & 3)) << 3;
            am[mt]  = *(const bf16x8*)&L[cb + r * 32 + c];
            asg[mt] = *(const bf16x8*)&L[cb + 4096 + r * 32 + c];
        }
        __builtin_amdgcn_s_setprio(1);
#pragma unroll
        for (int nt = 0; nt < 4; ++nt) {
            int rb = nt * 16 + q15;
            int c = (g ^ ((rb >> 1) & 3)) << 3;
            bf16x8 bw = *(const bf16x8*)&L[cb + 8192 + rb * 32 + c];
            bf16x8 b2 = *(const bf16x8*)&L[cb + 10240 + rb * 32 + c];
            acc1[0][nt] = __builtin_amdgcn_mfma_f32_16x16x32_bf16(am[0], bw, acc1[0][nt], 0, 0, 0);
            acc1[1][nt] = __builtin_amdgcn_mfma_f32_16x16x32_bf16(am[1], bw, acc1[1][nt], 0, 0, 0);
            acc2[0][nt] = __builtin_amdgcn_mfma_f32_16x16x32_bf16(asg[0], b2, acc2[0][nt], 0, 0, 0);
            acc2[1][nt] = __builtin_amdgcn_mfma_f32_16x16x32_bf16(asg[1], b2, acc2[1][nt], 0, 0, 0);
        }
        __builtin_amdgcn_s_setprio(0);
    }
    __syncthreads();

    const float inv2 = 1.f / (768.f * 768.f), invd = 1.f / 768.f;
    float rr[2][4];
#pragma unroll
    for (int mt = 0; mt < 2; ++mt)
#pragma unroll
        for (int r = 0; r < 4; ++r) {
            int row = m0 + wv * 32 + mt * 16 + g * 4 + r;
            rr[mt][r] = rmu2[row] * inv2 + rsg[row] * invd;
        }

    if (MODE == 0) {
#pragma unroll
        for (int mt = 0; mt < 2; ++mt)
#pragma unroll
            for (int nt = 0; nt < 4; ++nt)
#pragma unroll
                for (int r = 0; r < 4; ++r) {
                    int row = m0 + wv * 32 + mt * 16 + g * 4 + r;
                    int col = col0 + nt * 16 + q15;
                    float mu = acc1[mt][nt][r];
                    float sg = sp_f(sp_f(acc2[mt][nt][r] + rr[mt][r] * spws[col]));
                    mu_out[(size_t)row * E + col] = mu;
                    sg_out[(size_t)row * E + col] = sg;
                }
    } else {
        const int proj = n_blk / 12, h = n_blk % 12;
        float sgv[2][4][4];
#pragma unroll
        for (int mt = 0; mt < 2; ++mt)
#pragma unroll
            for (int nt = 0; nt < 4; ++nt)
#pragma unroll
                for (int r = 0; r < 4; ++r) {
                    int col = col0 + nt * 16 + q15;
                    sgv[mt][nt][r] = sp_f(acc2[mt][nt][r] + rr[mt][r] * spws[col]);
                }
        const int bb = m0 >> 10;
        if (proj < 2) {
            // coalesced [bh][s][d] store via LDS transpose (pad 72):
            // each thread owns a contiguous 32-u16 run (4 x uint4, matching
            // offsets on both sides) -> full 128x64 tile coverage.
            const int s0 = (m0 & 1023);
            const int sl = tid >> 1, hh = tid & 1;
            size_t gbase = ((size_t)(bb * 12 + h) << 16) + ((size_t)(s0 + sl) << 6) + hh * 32;
#pragma unroll
            for (int a = 0; a < 3; ++a) {
                __syncthreads();
#pragma unroll
                for (int mt = 0; mt < 2; ++mt)
#pragma unroll
                    for (int nt = 0; nt < 4; ++nt)
#pragma unroll
                        for (int r = 0; r < 4; ++r) {
                            float mu = acc1[mt][nt][r], sg = sgv[mt][nt][r];
                            float v = (a == 0) ? mu : (a == 1) ? sg :
                                      (proj == 0 ? (mu * mu + sg) * QSC : mu * mu * QSC);
                            L[(wv * 32 + mt * 16 + g * 4 + r) * 72 + nt * 16 + q15] = f2bf(v);
                        }
                __syncthreads();
                u16* dst = QKVB + (size_t)(proj * 3 + a) * BFN;
#pragma unroll
                for (int j = 0; j < 4; ++j)
                    *(uint4*)(dst + gbase + j * 8) = *(const uint4*)&L[sl * 72 + hh * 32 + j * 8];
            }
        } else {
            // V: transposed [bh][d][s], s permuted in 32-blocks (slot g*8+mt*4+r)
            const int s0 = m0 & 1023;
#pragma unroll
            for (int a = 0; a < 3; ++a) {
                __syncthreads();
#pragma unroll
                for (int mt = 0; mt < 2; ++mt)
#pragma unroll
                    for (int nt = 0; nt < 4; ++nt)
#pragma unroll
                        for (int r = 0; r < 4; ++r) {
                            float mu = acc1[mt][nt][r], sg = sgv[mt][nt][r];
                            float v = (a == 0) ? mu : (a == 1) ? sg * 0.0009765625f : mu * mu + sg;
                            L[(nt * 16 + q15) * 136 + wv * 32 + g * 8 + mt * 4 + r] = f2bf(v);
                        }
                __syncthreads();
                const int d = tid >> 2, sc = (tid & 3) * 32;
                u16* dst = QKVB + (size_t)(6 + a) * BFN;
                size_t ga = ((size_t)((bb * 12 + h) * 64 + d) << 10) + s0 + sc;
                *(uint4*)(dst + ga)      = *(const uint4*)&L[d * 136 + sc];
                *(uint4*)(dst + ga + 8)  = *(const uint4*)&L[d * 136 + sc + 8];
                *(uint4*)(dst + ga + 16) = *(const uint4*)&L[d * 136 + sc + 16];
                *(uint4*)(dst + ga + 24) = *(const uint4*)&L[d * 136 + sc + 24];
            }
        }
    }
}

// ------------------------------------------------------------- attention ---
// v8: K AND V double-buffered; one counted wait (vmcnt(6)) + two barriers per
// iter. P stays in registers (permuted-V slot order). LDS 48KB -> 3 blocks/CU.
#define KB0 0
#define KB1 6144
#define VB0 12288
#define VB1 18432
__global__ __launch_bounds__(256, 3) void vdp_attn8(
    const u16* __restrict__ Kmu, const u16* __restrict__ Ksg, const u16* __restrict__ Asq,
    const u16* __restrict__ Qmu, const u16* __restrict__ Q1v, const u16* __restrict__ Q2v,
    const u16* __restrict__ Vmu, const u16* __restrict__ Vsg, const u16* __restrict__ Vw2,
    u16* __restrict__ om, u16* __restrict__ osg)
{
    __shared__ __align__(16) u16 L[24576];   // 48KB

    const int wgid = blockIdx.x;                  // 768 = 48bh x 16qt
    const int seq = (wgid & 7) * 96 + (wgid >> 3);
    const int bh = seq >> 4, qt = seq & 15;
    const int tid = threadIdx.x, wv = tid >> 6, lane = tid & 63;
    const int g = lane >> 4, q15 = lane & 15;
    const size_t hb = (size_t)bh << 16;

    const size_t qoff = hb + (size_t)((qt * 64 + wv * 16 + q15) << 6) + g * 8;
    bf16x8 bq0 = *(const bf16x8*)(Qmu + qoff), bq1 = *(const bf16x8*)(Qmu + qoff + 32);
    bf16x8 b10 = *(const bf16x8*)(Q1v + qoff), b11 = *(const bf16x8*)(Q1v + qoff + 32);
    bf16x8 b20 = *(const bf16x8*)(Q2v + qoff), b21 = *(const bf16x8*)(Q2v + qoff + 32);

    const int sr = tid >> 3, sc8 = tid & 7;
    const size_t koffA = hb + (size_t)sr * 64 + ((sc8 ^ (sr & 7)) << 3);
    const size_t koffB = hb + (size_t)(sr + 32) * 64 + ((sc8 ^ (sr & 7)) << 3);
    const int vr = tid >> 2, vc = tid & 3;
    const size_t voff = hb + (size_t)vr * 1024 + ((vc ^ ((vr >> 1) & 3)) << 3);

    // ---- pass 1: softmax stats, raw-barrier dbuf (bufs @0 and @4096)
    float m2 = -3.0e38f;
    float lacc[4] = {0.f, 0.f, 0.f, 0.f};
    GLL16(Kmu + koffA, &L[0 + wv * 512]);
    GLL16(Kmu + koffB, &L[2048 + wv * 512]);
    __syncthreads();
    for (int t = 0; t < 16; ++t) {
        SBAR();
        const int tn = (t < 15) ? t + 1 : 15;
        const int nb = (t & 1) ? 0 : 4096;
        GLL16(Kmu + koffA + ((size_t)tn << 12), &L[nb + wv * 512]);
        GLL16(Kmu + koffB + ((size_t)tn << 12), &L[nb + 2048 + wv * 512]);
        VMCNT(2);
        SBAR();
        const int kb = (t & 1) ? 4096 : 0;
        f32x4 sc[4];
#pragma unroll
        for (int kt = 0; kt < 4; ++kt) sc[kt] = (f32x4){0.f, 0.f, 0.f, 0.f};
        __builtin_amdgcn_s_setprio(1);
#pragma unroll
        for (int kt = 0; kt < 4; ++kt) {
            int row = kt * 16 + q15, ra = kb + (row << 6);
            bf16x8 k0 = *(const bf16x8*)&L[ra + ((g ^ (row & 7)) << 3)];
            bf16x8 k1 = *(const bf16x8*)&L[ra + (((g + 4) ^ (row & 7)) << 3)];
            sc[kt] = __builtin_amdgcn_mfma_f32_16x16x32_bf16(k0, bq0, sc[kt], 0, 0, 0);
            sc[kt] = __builtin_amdgcn_mfma_f32_16x16x32_bf16(k1, bq1, sc[kt], 0, 0, 0);
        }
        __builtin_amdgcn_s_setprio(0);
        float t0 = fmaxf(fmaxf(sc[0][0], sc[0][1]), fmaxf(sc[0][2], sc[0][3]));
        float t1 = fmaxf(fmaxf(sc[1][0], sc[1][1]), fmaxf(sc[1][2], sc[1][3]));
        float t2 = fmaxf(fmaxf(sc[2][0], sc[2][1]), fmaxf(sc[2][2], sc[2][3]));
        float t3 = fmaxf(fmaxf(sc[3][0], sc[3][1]), fmaxf(sc[3][2], sc[3][3]));
        float tm = fmaxf(fmaxf(t0, t1), fmaxf(t2, t3)) * C2E;
        if (tm > m2 + 8.f) {
            float f = ex2(m2 - tm);
            lacc[0] *= f; lacc[1] *= f; lacc[2] *= f; lacc[3] *= f;
            m2 = tm;
        }
#pragma unroll
        for (int kt = 0; kt < 4; ++kt)
#pragma unroll
            for (int r = 0; r < 4; ++r)
                lacc[kt] += ex2(fmaf(sc[kt][r], C2E, -m2));
    }
    __syncthreads();
    float l = (lacc[0] + lacc[1]) + (lacc[2] + lacc[3]);
#pragma unroll
    for (int off = 16; off <= 32; off <<= 1) {
        float mo = __shfl_xor(m2, off), lo = __shfl_xor(l, off);
        float nm = fmaxf(m2, mo);
        l = l * ex2(m2 - nm) + lo * ex2(mo - nm);
        m2 = nm;
    }
    const float M = m2 + lg2(l);

    // ---- pass 2: K and V both double-buffered
    f32x4 accm[4], accd[4], acce[4];
#pragma unroll
    for (int nt = 0; nt < 4; ++nt) {
        accm[nt] = (f32x4){0.f, 0.f, 0.f, 0.f};
        accd[nt] = (f32x4){0.f, 0.f, 0.f, 0.f};
        acce[nt] = (f32x4){0.f, 0.f, 0.f, 0.f};
    }

    GLL16(Kmu + koffA, &L[KB0 + 0    + wv * 512]);
    GLL16(Ksg + koffA, &L[KB0 + 2048 + wv * 512]);
    GLL16(Asq + koffA, &L[KB0 + 4096 + wv * 512]);
    GLL16(Vmu + voff, &L[VB0 + 0    + wv * 512]);
    GLL16(Vsg + voff, &L[VB0 + 2048 + wv * 512]);
    GLL16(Vw2 + voff, &L[VB0 + 4096 + wv * 512]);
    __syncthreads();

    for (int t = 0; t < 32; ++t) {
        SBAR();                                   // buf[cur^1] free to overwrite
        const int tn = (t < 31) ? t + 1 : 31;
        const size_t ka = (size_t)tn << 11;
        const size_t va = (size_t)tn << 5;
        const int nbK = (t & 1) ? KB0 : KB1;
        const int nbV = (t & 1) ? VB0 : VB1;
        GLL16(Kmu + koffA + ka, &L[nbK + 0    + wv * 512]);
        GLL16(Ksg + koffA + ka, &L[nbK + 2048 + wv * 512]);
        GLL16(Asq + koffA + ka, &L[nbK + 4096 + wv * 512]);
        GLL16(Vmu + voff + va,  &L[nbV + 0    + wv * 512]);
        GLL16(Vsg + voff + va,  &L[nbV + 2048 + wv * 512]);
        GLL16(Vw2 + voff + va,  &L[nbV + 4096 + wv * 512]);
        VMCNT(6);                                 // K(t),V(t) landed (mine)
        SBAR();                                   // ... for everyone

        const int kb = (t & 1) ? KB1 : KB0;
        const int vb = (t & 1) ? VB1 : VB0;
        f32x4 sc[2], sgc[2];
#pragma unroll
        for (int kt = 0; kt < 2; ++kt) { sc[kt] = (f32x4){0.f,0.f,0.f,0.f}; sgc[kt] = (f32x4){0.f,0.f,0.f,0.f}; }
        __builtin_amdgcn_s_setprio(1);
#pragma unroll
        for (int kt = 0; kt < 2; ++kt) {
            int row = kt * 16 + q15, ra = kb + (row << 6);
            int ca = ((g ^ (row & 7)) << 3), cb = (((g + 4) ^ (row & 7)) << 3);
            sc[kt]  = __builtin_amdgcn_mfma_f32_16x16x32_bf16(*(const bf16x8*)&L[ra + ca],        bq0, sc[kt],  0, 0, 0);
            sc[kt]  = __builtin_amdgcn_mfma_f32_16x16x32_bf16(*(const bf16x8*)&L[ra + cb],        bq1, sc[kt],  0, 0, 0);
            sgc[kt] = __builtin_amdgcn_mfma_f32_16x16x32_bf16(*(const bf16x8*)&L[2048 + ra + ca], b10, sgc[kt], 0, 0, 0);
            sgc[kt] = __builtin_amdgcn_mfma_f32_16x16x32_bf16(*(const bf16x8*)&L[2048 + ra + cb], b11, sgc[kt], 0, 0, 0);
            sgc[kt] = __builtin_amdgcn_mfma_f32_16x16x32_bf16(*(const bf16x8*)&L[4096 + ra + ca], b20, sgc[kt], 0, 0, 0);
            sgc[kt] = __builtin_amdgcn_mfma_f32_16x16x32_bf16(*(const bf16x8*)&L[4096 + ra + cb], b21, sgc[kt], 0, 0, 0);
        }
        __builtin_amdgcn_s_setprio(0);

        float p[8], p2v[8], swv[8];
#pragma unroll
        for (int kt = 0; kt < 2; ++kt)
#pragma unroll
            for (int r = 0; r < 4; ++r) {
                int j = kt * 4 + r;
                float pv = ex2(fmaf(sc[kt][r], C2E, -M));
                float pp = pv * pv;
                float gq = pv - pp;
                p[j] = pv; p2v[j] = pp; swv[j] = gq * gq * sgc[kt][r];
            }
        u32x4 ua  = {cvtpk(p[0], p[1]),     cvtpk(p[2], p[3]),     cvtpk(p[4], p[5]),     cvtpk(p[6], p[7])};
        u32x4 ubv = {cvtpk(p2v[0], p2v[1]), cvtpk(p2v[2], p2v[3]), cvtpk(p2v[4], p2v[5]), cvtpk(p2v[6], p2v[7])};
        u32x4 ucv = {cvtpk(swv[0], swv[1]), cvtpk(swv[2], swv[3]), cvtpk(swv[4], swv[5]), cvtpk(swv[6], swv[7])};
        bf16x8 pa  = *(const bf16x8*)&ua;
        bf16x8 p2a = *(const bf16x8*)&ubv;
        bf16x8 swa = *(const bf16x8*)&ucv;

        __builtin_amdgcn_s_setprio(1);
#pragma unroll
        for (int nt = 0; nt < 4; ++nt) {
            int row = nt * 16 + q15;
            int vi = vb + (row << 5) + ((g ^ ((q15 >> 1) & 3)) << 3);
            accm[nt] = __builtin_amdgcn_mfma_f32_16x16x32_bf16(pa,  *(const bf16x8*)&L[vi],        accm[nt], 0, 0, 0);
            accd[nt] = __builtin_amdgcn_mfma_f32_16x16x32_bf16(p2a, *(const bf16x8*)&L[vi + 2048], accd[nt], 0, 0, 0);
            acce[nt] = __builtin_amdgcn_mfma_f32_16x16x32_bf16(swa, *(const bf16x8*)&L[vi + 4096], acce[nt], 0, 0, 0);
        }
        __builtin_amdgcn_s_setprio(0);
    }

    const int b_ = bh / 12, h_ = bh % 12;
#pragma unroll
    for (int nt = 0; nt < 4; ++nt)
#pragma unroll
        for (int r = 0; r < 4; ++r) {
            int srow = qt * 64 + wv * 16 + g * 4 + r;
            int d = nt * 16 + q15;
            size_t o = (size_t)(b_ * 1024 + srow) * E + h_ * 64 + d;
            om[o]  = f2bf(accm[nt][r]);
            osg[o] = f2bf(sp_f(accd[nt][r] + acce[nt][r]));
        }
}

// --------------------------------------------------------------- launch ----
extern "C" void kernel_launch(void* const* d_in, const int* in_sizes, int n_in,
                              void* d_out, int out_size, void* d_ws, size_t ws_size,
                              hipStream_t stream)
{
    const float* mu_in = (const float*)d_in[0];
    const float* sg_in = (const float*)d_in[1];
    const float* wq  = (const float*)d_in[2];
    const float* wqs = (const float*)d_in[3];
    const float* wk  = (const float*)d_in[4];
    const float* wks = (const float*)d_in[5];
    const float* wvp = (const float*)d_in[6];
    const float* wvs = (const float*)d_in[7];
    const float* wo  = (const float*)d_in[8];
    const float* wos = (const float*)d_in[9];

    float* out_mu = (float*)d_out;
    float* out_sg = out_mu + (size_t)NTOK * E;
    float* kl_out = out_mu + 2 * (size_t)NTOK * E;

    float* ws = (float*)d_ws;
    size_t off = 0;
    auto allocf = [&](size_t n) { float* p = ws + off; off += n; return p; };
    float* rmu2  = allocf(NTOK);
    float* rsgs  = allocf(NTOK);
    float* armu2 = allocf(NTOK);
    float* arsg  = allocf(NTOK);
    float* spws  = allocf(4 * E);

    u16* ub = (u16*)(ws + off);
    size_t uoff = 0;
    auto allocu = [&](size_t n) { u16* p = ub + uoff; uoff += n; return p; };
    u16* Xmu    = allocu(BFN);
    u16* Xsg    = allocu(BFN);
    u16* WtAll  = allocu(4 * WFN);
    u16* W2tAll = allocu(4 * WFN);
    u16* QKVB   = allocu(9 * BFN);
    u16* amu_b  = allocu(BFN);
    u16* asg_b  = allocu(BFN);
    (void)ws_size; (void)in_sizes; (void)n_in; (void)out_size;

    hipMemsetAsync(kl_out, 0, 4, stream);
    prep_all<<<4865, 256, 0, stream>>>(mu_in, sg_in, wq, wk, wvp, wo,
                                       wqs, wks, wvs, wos,
                                       Xmu, Xsg, rmu2, rsgs, WtAll, W2tAll,
                                       spws, kl_out);

    linear_fused<1><<<1152, 256, 0, stream>>>(Xmu, Xsg, WtAll, W2tAll, spws, rmu2, rsgs,
                                              nullptr, nullptr, QKVB);

    vdp_attn8<<<768, 256, 0, stream>>>(QKVB + 3 * BFN, QKVB + 4 * BFN, QKVB + 1 * BFN,
                                       QKVB + 0 * BFN, QKVB + 2 * BFN, QKVB + 5 * BFN,
                                       QKVB + 6 * BFN, QKVB + 7 * BFN, QKVB + 8 * BFN,
                                       amu_b, asg_b);

    rowstats_bf16_kernel<<<NTOK, 128, 0, stream>>>(amu_b, asg_b, armu2, arsg);
    linear_fused<0><<<384, 256, 0, stream>>>(amu_b, asg_b, WtAll + 3 * WFN, W2tAll + 3 * WFN,
                                             spws + 3 * E, armu2, arsg,
                                             out_mu, out_sg, nullptr);
}